// Round 13
// baseline (414.696 us; speedup 1.0000x reference)
//
#include <hip/hip_runtime.h>
#include <math.h>
#include <stdint.h>

// Problem constants (B,V,D,H,DE,DFF fixed by the reference)
#define B_   2
#define V_   2048
#define D_   1024
#define H_   16
#define DK_  64
#define DE_  256
#define DFF_ 4096
#define M_   (B_*V_)     // 4096 tokens
#define D2_  (2*D_)      // 2048
#define D3_  (3*D_)      // 3072 (fused QKV width)

typedef unsigned short u16;
typedef unsigned int   u32;
typedef __bf16 bf16x8 __attribute__((ext_vector_type(8)));
typedef u16    u16x8  __attribute__((ext_vector_type(8)));
typedef u16    u16x4  __attribute__((ext_vector_type(4)));
typedef float  f32x4  __attribute__((ext_vector_type(4)));
typedef u32    u32x2  __attribute__((ext_vector_type(2)));
typedef u32    u32x4  __attribute__((ext_vector_type(4)));

__device__ __forceinline__ float bf2f(u16 u) {
    union { unsigned int i; float f; } z; z.i = ((unsigned int)u) << 16; return z.f;
}
__device__ __forceinline__ u16 f2bf(float f) {
    union { float f; unsigned int i; } z; z.f = f;
    unsigned int x = z.i;
    return (u16)((x + 0x7fffu + ((x >> 16) & 1u)) >> 16);  // RNE
}
__device__ __forceinline__ float gelu_erf(float v) {
    return 0.5f * v * (1.0f + erff(v * 0.70710678118654752f));
}

// async global->LDS, 16B per lane; LDS dest = wave-uniform base + lane*16
__device__ __forceinline__ void gload16(const u16* g, u16* lds)
{
    __builtin_amdgcn_global_load_lds(
        (const __attribute__((address_space(1))) void*)g,
        (__attribute__((address_space(3))) void*)(uintptr_t)lds,
        16, 0, 0);
}

// raw workgroup barrier WITHOUT the compiler's implicit vmcnt(0) drain,
// wrapped in compiler memory fences so LDS reads/writes can't be hoisted across.
__device__ __forceinline__ void barrier_raw()
{
    asm volatile("" ::: "memory");
    __builtin_amdgcn_s_barrier();
    asm volatile("" ::: "memory");
}

// ---------------------------------------------------------------------------
// Weight convert+transpose: Wt[N][K] bf16 <- W[K][N] f32 (32x32 LDS tiles)
// ---------------------------------------------------------------------------
__global__ void convT_k(const float* __restrict__ W, u16* __restrict__ Wt, int K, int N)
{
    __shared__ float tile[32][33];
    const int n0 = blockIdx.x * 32, k0 = blockIdx.y * 32;
    const int tx = threadIdx.x, ty = threadIdx.y;   // 32 x 8
    #pragma unroll
    for (int j = 0; j < 4; ++j)
        tile[ty * 4 + j][tx] = W[(size_t)(k0 + ty * 4 + j) * N + n0 + tx];
    __syncthreads();
    #pragma unroll
    for (int j = 0; j < 4; ++j)
        Wt[(size_t)(n0 + ty * 4 + j) * K + k0 + tx] = f2bf(tile[tx][ty * 4 + j]);
}

// elementwise f32 -> bf16 (n divisible by 4*256)
__global__ void conv_k(const float* __restrict__ X, u16* __restrict__ Y)
{
    const int i = (blockIdx.x * 256 + threadIdx.x) * 4;
    f32x4 v = *reinterpret_cast<const f32x4*>(X + i);
    u16x4 o;
    #pragma unroll
    for (int j = 0; j < 4; ++j) o[j] = f2bf(v[j]);
    *reinterpret_cast<u16x4*>(Y + i) = o;
}

// log2-mask precompute: Lm = bf16(log2(clip(conn,0,1)+1e-6)), 8 elems/thread
__global__ void lmask_k(const float* __restrict__ conn, u16* __restrict__ Lm)
{
    const size_t i = ((size_t)blockIdx.x * 256 + threadIdx.x) * 8;
    f32x4 a = *reinterpret_cast<const f32x4*>(conn + i);
    f32x4 b = *reinterpret_cast<const f32x4*>(conn + i + 4);
    u16x8 o;
    #pragma unroll
    for (int j = 0; j < 4; ++j) {
        o[j]     = f2bf(__log2f(fminf(fmaxf(a[j], 0.f), 1.f) + 1e-6f));
        o[j + 4] = f2bf(__log2f(fminf(fmaxf(b[j], 0.f), 1.f) + 1e-6f));
    }
    *reinterpret_cast<u16x8*>(Lm + i) = o;
}

// concat q/k/v biases into one 3072-wide f32 vector
__global__ void qkvbias_k(const float* __restrict__ bq, const float* __restrict__ bk,
                          const float* __restrict__ bv, float* __restrict__ o)
{
    int i = blockIdx.x * 256 + threadIdx.x;
    o[i] = i < 1024 ? bq[i] : (i < 2048 ? bk[i - 1024] : bv[i - 2048]);
}

// combine split-K attention partials: O = (O1+O2)/(l1+l2+1e-8)
// Op: [2][M_][D_] bf16 (unnormalized), Lp: [2][M_][H_] f32. O may alias Op[0].
__global__ void combine_k(const u16* __restrict__ Op, const float* __restrict__ Lp,
                          u16* __restrict__ O)
{
    const size_t c = ((size_t)blockIdx.x * 256 + threadIdx.x) * 8;
    const int row = (int)(c >> 10);          // D_ = 1024
    const int hh  = (int)((c & 1023) >> 6);
    u16x8 a  = *reinterpret_cast<const u16x8*>(Op + c);
    u16x8 b2 = *reinterpret_cast<const u16x8*>(Op + (size_t)M_ * D_ + c);
    float l = Lp[(size_t)row * H_ + hh] + Lp[((size_t)M_ + row) * H_ + hh];
    float rcp = 1.0f / (l + 1e-8f);
    u16x8 o;
    #pragma unroll
    for (int j = 0; j < 8; ++j) o[j] = f2bf((bf2f(a[j]) + bf2f(b2[j])) * rcp);
    *reinterpret_cast<u16x8*>(O + c) = o;
}

// ---------------------------------------------------------------------------
// bf16 MFMA GEMM, counted-vmcnt pipelined: C = epi(A @ Wt^T + bias (+res))
// BM=128, BN in {128,64}; 4 waves; double-buffered LDS.
// Epilogue: C tile bounced through LDS (bank-swizzled) -> coalesced 16B stores.
// EPI: 0 = none, 1 = exact-erf GELU, 2 = add residual
// ---------------------------------------------------------------------------
template<int EPI, int BN, typename TC, typename TRES>
__launch_bounds__(256)
__global__ void gemm_k(const u16* __restrict__ A, const u16* __restrict__ Wt,
                       const float* __restrict__ bias, const TRES* __restrict__ res,
                       TC* __restrict__ C, int M, int N, int K)
{
    constexpr int NB = BN / 32;        // B frags per wave (4 or 2)
    constexpr int IB = BN / 32;        // B staging issues per wave
    __shared__ u16 As[2][128 * 64];
    __shared__ u16 Bs[2][BN * 64];

    const int tid  = threadIdx.x;
    const int lane = tid & 63;
    const int w    = tid >> 6;
    const int wm   = (w >> 1) * 64, wn = (w & 1) * (BN / 2);
    const int m0   = blockIdx.y * 128, n0 = blockIdx.x * BN;
    const int l15  = lane & 15, l4 = lane >> 4;
    const int rStage = lane >> 3;

    int rrA[4], ccA[4];
    #pragma unroll
    for (int i = 0; i < 4; ++i) {
        rrA[i] = w * 32 + i * 8 + rStage;
        ccA[i] = (lane & 7) ^ (rrA[i] & 7);
    }
    int rrB[IB], ccB[IB];
    #pragma unroll
    for (int i = 0; i < IB; ++i) {
        rrB[i] = w * (BN / 4) + i * 8 + rStage;
        ccB[i] = (lane & 7) ^ (rrB[i] & 7);
    }

    auto stage = [&](int kt, int dd) {
        const int k0 = kt * 64;
        #pragma unroll
        for (int i = 0; i < 4; ++i)
            gload16(A + (size_t)(m0 + rrA[i]) * K + k0 + ccA[i] * 8, &As[dd][w * 2048 + i * 512]);
        #pragma unroll
        for (int i = 0; i < IB; ++i)
            gload16(Wt + (size_t)(n0 + rrB[i]) * K + k0 + ccB[i] * 8, &Bs[dd][w * (BN * 16) + i * 512]);
    };

    f32x4 acc[4][NB] = {};
    const int NT = K / 64;

    stage(0, 0);   // prologue

    for (int t = 0; t < NT; ++t) {
        const int d = t & 1;
        barrier_raw();                 // (1) all waves done reading buf d^1
        if (t + 1 < NT) {
            stage(t + 1, d ^ 1);
            if constexpr (BN == 128) asm volatile("s_waitcnt vmcnt(8)" ::: "memory");
            else                     asm volatile("s_waitcnt vmcnt(6)" ::: "memory");
        } else {
            asm volatile("s_waitcnt vmcnt(0)" ::: "memory");
        }
        barrier_raw();                 // (2) tile t visible to all waves
        __builtin_amdgcn_sched_barrier(0);

        #pragma unroll
        for (int kk = 0; kk < 2; ++kk) {
            bf16x8 a[4], b[NB];
            #pragma unroll
            for (int mb = 0; mb < 4; ++mb) {
                int r  = wm + mb * 16 + l15;
                int ph = (kk * 4 + l4) ^ (r & 7);
                a[mb] = *reinterpret_cast<const bf16x8*>(&As[d][r * 64 + ph * 8]);
            }
            #pragma unroll
            for (int nb = 0; nb < NB; ++nb) {
                int r  = wn + nb * 16 + l15;
                int ph = (kk * 4 + l4) ^ (r & 7);
                b[nb] = *reinterpret_cast<const bf16x8*>(&Bs[d][r * 64 + ph * 8]);
            }
            #pragma unroll
            for (int mb = 0; mb < 4; ++mb)
                #pragma unroll
                for (int nb = 0; nb < NB; ++nb)
                    acc[mb][nb] = __builtin_amdgcn_mfma_f32_16x16x32_bf16(a[mb], b[nb], acc[mb][nb], 0, 0, 0);
        }
    }

    // ---- epilogue: bounce C tile through LDS for coalesced 16B stores ----
    barrier_raw();                       // all waves done with main-loop LDS
    u16* Cs = (u16*)&As[0][0];           // 128*BN u16 <= 32 KB (reuse A buffers)
    #pragma unroll
    for (int nb = 0; nb < NB; ++nb) {
        int col  = wn + nb * 16 + l15;
        int colx = col ^ (l4 << 4);      // bank swizzle; (row>>2)&3 == l4 here
        float bv = bias[n0 + col];
        #pragma unroll
        for (int mb = 0; mb < 4; ++mb) {
            #pragma unroll
            for (int i = 0; i < 4; ++i) {
                float v = acc[mb][nb][i] + bv;
                if (EPI == 1) v = gelu_erf(v);
                Cs[(wm + mb * 16 + l4 * 4 + i) * BN + colx] = f2bf(v);
            }
        }
    }
    asm volatile("s_waitcnt lgkmcnt(0)" ::: "memory");
    barrier_raw();
    constexpr int CPR = BN / 8;          // 16B chunks per row
    #pragma unroll
    for (int p = 0; p < (128 * CPR) / 256; ++p) {
        int c   = p * 256 + tid;
        int row = c / CPR;
        int cl  = (c % CPR) * 8;                        // logical col base
        int cp  = cl ^ (((row >> 2) & 3) << 4);         // physical col in Cs
        u16x8 vv = *reinterpret_cast<const u16x8*>(&Cs[row * BN + cp]);
        size_t gidx = (size_t)(m0 + row) * N + n0 + cl;
        if constexpr (sizeof(TC) == 2) {
            if (EPI == 2) {
                if constexpr (sizeof(TRES) == 2) {
                    u16x8 rr = *reinterpret_cast<const u16x8*>((const u16*)res + gidx);
                    #pragma unroll
                    for (int j = 0; j < 8; ++j) vv[j] = f2bf(bf2f(vv[j]) + bf2f(rr[j]));
                } else {
                    f32x4 r0 = *reinterpret_cast<const f32x4*>((const float*)res + gidx);
                    f32x4 r1 = *reinterpret_cast<const f32x4*>((const float*)res + gidx + 4);
                    #pragma unroll
                    for (int j = 0; j < 4; ++j) {
                        vv[j]     = f2bf(bf2f(vv[j])     + r0[j]);
                        vv[j + 4] = f2bf(bf2f(vv[j + 4]) + r1[j]);
                    }
                }
            }
            *reinterpret_cast<u16x8*>((u16*)C + gidx) = vv;
        } else {
            f32x4 o0, o1;
            #pragma unroll
            for (int j = 0; j < 4; ++j) { o0[j] = bf2f(vv[j]); o1[j] = bf2f(vv[j + 4]); }
            if (EPI == 2) {
                if constexpr (sizeof(TRES) == 2) {
                    u16x8 rr = *reinterpret_cast<const u16x8*>((const u16*)res + gidx);
                    #pragma unroll
                    for (int j = 0; j < 4; ++j) { o0[j] += bf2f(rr[j]); o1[j] += bf2f(rr[j + 4]); }
                } else {
                    f32x4 r0 = *reinterpret_cast<const f32x4*>((const float*)res + gidx);
                    f32x4 r1 = *reinterpret_cast<const f32x4*>((const float*)res + gidx + 4);
                    #pragma unroll
                    for (int j = 0; j < 4; ++j) { o0[j] += r0[j]; o1[j] += r1[j]; }
                }
            }
            *reinterpret_cast<f32x4*>((float*)C + gidx)     = o0;
            *reinterpret_cast<f32x4*>((float*)C + gidx + 4) = o1;
        }
    }
}

// ---------------------------------------------------------------------------
// Fused LayerNorm + FiLM (vectorized: 4 contiguous elems/thread)
// ---------------------------------------------------------------------------
template<typename TX>
__launch_bounds__(256)
__global__ void lnfilm_k(const TX* __restrict__ X, const u16* __restrict__ GB,
                         const float* __restrict__ g, const float* __restrict__ bb,
                         u16* __restrict__ Y)
{
    const int row = blockIdx.x;
    const int tid = threadIdx.x;
    const int d0  = tid * 4;
    const TX* xr = X + (size_t)row * D_ + d0;
    float xs[4], s = 0.f, sq = 0.f;
    if constexpr (sizeof(TX) == 4) {
        f32x4 v4 = *reinterpret_cast<const f32x4*>(xr);
        #pragma unroll
        for (int j = 0; j < 4; ++j) { xs[j] = v4[j]; s += xs[j]; sq += xs[j] * xs[j]; }
    } else {
        u16x4 v4 = *reinterpret_cast<const u16x4*>(xr);
        #pragma unroll
        for (int j = 0; j < 4; ++j) { xs[j] = bf2f(v4[j]); s += xs[j]; sq += xs[j] * xs[j]; }
    }
    #pragma unroll
    for (int off = 32; off; off >>= 1) {
        s  += __shfl_xor(s, off);
        sq += __shfl_xor(sq, off);
    }
    __shared__ float rs[4], rq[4];
    const int w = tid >> 6;
    if ((tid & 63) == 0) { rs[w] = s; rq[w] = sq; }
    __syncthreads();
    s  = rs[0] + rs[1] + rs[2] + rs[3];
    sq = rq[0] + rq[1] + rq[2] + rq[3];
    const float mean = s * (1.0f / D_);
    const float var  = sq * (1.0f / D_) - mean * mean;
    const float rstd = rsqrtf(fmaxf(var, 0.f) + 1e-5f);
    const u16* gbr = GB + (size_t)row * D2_ + d0;
    u16x4 g4 = *reinterpret_cast<const u16x4*>(gbr);
    u16x4 b4 = *reinterpret_cast<const u16x4*>(gbr + D_);
    f32x4 gg = *reinterpret_cast<const f32x4*>(g + d0);
    f32x4 bv = *reinterpret_cast<const f32x4*>(bb + d0);
    u16x4 o;
    #pragma unroll
    for (int j = 0; j < 4; ++j) {
        float v = (xs[j] - mean) * rstd * gg[j] + bv[j];
        v = v * (1.0f + bf2f(g4[j])) + bf2f(b4[j]);
        o[j] = f2bf(v);
    }
    *reinterpret_cast<u16x4*>(Y + (size_t)row * D_ + d0) = o;
}

// ---------------------------------------------------------------------------
// Flash attention, split-K over k-tiles (2 halves, grid x2 for occupancy).
// Swapped QK^T (S^T fragment: lane owns one q column). QBLK=128: 4 waves x
// 32 q-rows (2 groups of 16); V frags tr-read once, reused by both groups.
// Writes UNNORMALIZED partial O (bf16) + per-(q,h) row sums l (f32).
// ---------------------------------------------------------------------------
__launch_bounds__(256)
__global__ void attn_k(const u16* __restrict__ Q, const u16* __restrict__ K,
                       const u16* __restrict__ Vv, const u16* __restrict__ Lm,
                       u16* __restrict__ Op, float* __restrict__ Lp, int ld)
{
    __shared__ u16 Ks[64 * 64];     // [k][dk], 16B-chunk XOR-swizzled by (k&7)
    __shared__ u16 Vs[64 * 64];     // tr-subtiled for ds_read_b64_tr_b16
    __shared__ u16 Lms[128 * 64];   // [q][k], 16B-chunk XOR-swizzled by (q&7)
    __shared__ u16 Ps[128 * 72];

    const int blk  = blockIdx.x;
    const int half = blk >> 9;         // k-range half
    const int qt   = blk & 15;         // V/128 = 16 q-tiles
    const int h    = (blk >> 4) & 15;
    const int b    = (blk >> 8) & 1;
    const int q0   = qt * 128;
    const int tid = threadIdx.x, lane = tid & 63, w = tid >> 6;
    const int l15 = lane & 15, l4 = lane >> 4;
    const size_t bV = (size_t)b * V_;

    // Q frags (B-operand), two 16-row groups, pre-scaled by 1/8 (exact)
    bf16x8 qa[2][2];
    #pragma unroll
    for (int g = 0; g < 2; ++g) {
        const u16* qp = Q + (bV + q0 + w * 32 + g * 16 + l15) * ld + h * 64;
        u16x8 r0 = *reinterpret_cast<const u16x8*>(qp + l4 * 8);
        u16x8 r1 = *reinterpret_cast<const u16x8*>(qp + 32 + l4 * 8);
        u16x8 s0, s1;
        #pragma unroll
        for (int j = 0; j < 8; ++j) {
            s0[j] = f2bf(bf2f(r0[j]) * 0.125f);
            s1[j] = f2bf(bf2f(r1[j]) * 0.125f);
        }
        union { u16x8 u; bf16x8 h; } c0, c1;
        c0.u = s0; c1.u = s1;
        qa[g][0] = c0.h; qa[g][1] = c1.h;
    }

    // staging source offsets (per-lane, constant over k-tiles)
    const int rStage = (lane >> 3);                                // 0..7
    const int cSw    = ((lane & 7) ^ rStage) * 8;                  // K/Lm pre-swizzled chunk
    const int vK     = ((lane >> 5) << 2) + ((lane & 7) >> 1);     // V: source k row
    const int vDk    = ((lane >> 3) & 3) * 16 + (lane & 1) * 8;    // V: source dk
    const u32 vaddr  = (u32)(uintptr_t)&Vs[0] + (l4 << 10) + (l15 << 3);

    // Lm read geometry (slot XOR uses row&7 == l15&7, same for both groups)
    int lmOff[4];
    #pragma unroll
    for (int kb = 0; kb < 4; ++kb)
        lmOff[kb] = ((((kb << 1) | (l4 >> 1)) ^ (l15 & 7)) << 3);

    const float LOG2E = 1.44269504088896f;
    float lrp[2] = {0.f, 0.f};
    f32x4 o4[2][4] = {};

    const int kt0 = half * 16, kt1 = kt0 + 16;
    for (int kt = kt0; kt < kt1; ++kt) {
        const int k0 = kt * 64;
        if (kt > kt0) __syncthreads();
        #pragma unroll
        for (int i = 0; i < 2; ++i) {
            int r  = i * 32 + w * 8 + rStage;
            int kv = i * 32 + w * 8 + vK;
            gload16(K  + (bV + k0 + r)  * ld + h * 64 + cSw, &Ks[i * 2048 + w * 512]);
            gload16(Vv + (bV + k0 + kv) * ld + h * 64 + vDk, &Vs[i * 2048 + w * 512]);
        }
        #pragma unroll
        for (int i = 0; i < 4; ++i) {
            int r = i * 32 + w * 8 + rStage;
            gload16(Lm + (bV + q0 + r) * (size_t)V_ + k0 + cSw, &Lms[i * 2048 + w * 512]);
        }
        __syncthreads();   // drains vmcnt(0): tiles resident

        // per group: S^T = K (Q/8)^T, then P = exp2(S*log2e + lm), write Ps
        #pragma unroll
        for (int g = 0; g < 2; ++g) {
            f32x4 s[4];
            #pragma unroll
            for (int kb = 0; kb < 4; ++kb) {
                int row = (kb * 16 + l15) * 64;
                bf16x8 k0f = *reinterpret_cast<const bf16x8*>(&Ks[row + ((l4 ^ (l15 & 7)) * 8)]);
                bf16x8 k1f = *reinterpret_cast<const bf16x8*>(&Ks[row + (((l4 + 4) ^ (l15 & 7)) * 8)]);
                f32x4 z = {};
                z = __builtin_amdgcn_mfma_f32_16x16x32_bf16(k0f, qa[g][0], z, 0, 0, 0);
                z = __builtin_amdgcn_mfma_f32_16x16x32_bf16(k1f, qa[g][1], z, 0, 0, 0);
                s[kb] = z;
            }
            const int lmRow = w * 32 + g * 16 + l15;
            const u16* lmBase = &Lms[lmRow * 64 + (l4 & 1) * 4];
            u16* psW = &Ps[lmRow * 72 + l4 * 4];
            #pragma unroll
            for (int kb = 0; kb < 4; ++kb) {
                u16x4 lm4 = *reinterpret_cast<const u16x4*>(lmBase + lmOff[kb]);
                float p0, p1, p2, p3;
                float t0 = fmaf(s[kb][0], LOG2E, bf2f(lm4[0]));
                float t1 = fmaf(s[kb][1], LOG2E, bf2f(lm4[1]));
                float t2 = fmaf(s[kb][2], LOG2E, bf2f(lm4[2]));
                float t3 = fmaf(s[kb][3], LOG2E, bf2f(lm4[3]));
                asm("v_exp_f32 %0, %1" : "=v"(p0) : "v"(t0));
                asm("v_exp_f32 %0, %1" : "=v"(p1) : "v"(t1));
                asm("v_exp_f32 %0, %1" : "=v"(p2) : "v"(t2));
                asm("v_exp_f32 %0, %1" : "=v"(p3) : "v"(t3));
                lrp[g] += (p0 + p1) + (p2 + p3);
                u32 d0, d1;
                asm("v_cvt_pk_bf16_f32 %0, %1, %2" : "=v"(d0) : "v"(p0), "v"(p1));
                asm("v_cvt_pk_bf16_f32 %0, %1, %2" : "=v"(d1) : "v"(p2), "v"(p3));
                u32x2 dd = {d0, d1};
                *reinterpret_cast<u32x2*>(psW + kb * 16) = dd;
            }
        }

        // V B-fragments: tr-read ONCE into registers, reuse for both groups
        union VU { u32x4 u; bf16x8 h; };
        VU vb[2][4];
        #pragma unroll
        for (int c2 = 0; c2 < 2; ++c2) {
            u32 a0 = vaddr + c2 * 4096;
            u32x2 t0, t1, t2, t3, t4, t5, t6, t7;
            asm volatile("ds_read_b64_tr_b16 %0, %1"            : "=v"(t0) : "v"(a0));
            asm volatile("ds_read_b64_tr_b16 %0, %1 offset:512" : "=v"(t1) : "v"(a0));
            asm volatile("ds_read_b64_tr_b16 %0, %1 offset:128" : "=v"(t2) : "v"(a0));
            asm volatile("ds_read_b64_tr_b16 %0, %1 offset:640" : "=v"(t3) : "v"(a0));
            asm volatile("ds_read_b64_tr_b16 %0, %1 offset:256" : "=v"(t4) : "v"(a0));
            asm volatile("ds_read_b64_tr_b16 %0, %1 offset:768" : "=v"(t5) : "v"(a0));
            asm volatile("ds_read_b64_tr_b16 %0, %1 offset:384" : "=v"(t6) : "v"(a0));
            asm volatile("ds_read_b64_tr_b16 %0, %1 offset:896" : "=v"(t7) : "v"(a0));
            asm volatile("s_waitcnt lgkmcnt(0)" ::: "memory");
            __builtin_amdgcn_sched_barrier(0);
            vb[c2][0].u = (u32x4){t0.x, t0.y, t1.x, t1.y};
            vb[c2][1].u = (u32x4){t2.x, t2.y, t3.x, t3.y};
            vb[c2][2].u = (u32x4){t4.x, t4.y, t5.x, t5.y};
            vb[c2][3].u = (u32x4){t6.x, t6.y, t7.x, t7.y};
        }
        // O += P @ V for both groups (vb reused from registers)
        #pragma unroll
        for (int g = 0; g < 2; ++g) {
            const u16* pr = &Ps[(w * 32 + g * 16 + l15) * 72];
            bf16x8 pa0 = *reinterpret_cast<const bf16x8*>(pr + l4 * 8);
            bf16x8 pa1 = *reinterpret_cast<const bf16x8*>(pr + 32 + l4 * 8);
            #pragma unroll
            for (int nb = 0; nb < 4; ++nb) {
                o4[g][nb] = __builtin_amdgcn_mfma_f32_16x16x32_bf16(pa0, vb[0][nb].h, o4[g][nb], 0, 0, 0);
                o4[g][nb] = __builtin_amdgcn_mfma_f32_16x16x32_bf16(pa1, vb[1][nb].h, o4[g][nb], 0, 0, 0);
            }
        }
    }

    // write partial row-sums (one lane group) and unnormalized partial O
    u16* Ob = Op + (size_t)half * M_ * D_;
    #pragma unroll
    for (int g = 0; g < 2; ++g) {
        float v = lrp[g];
        v += __shfl_xor(v, 16);
        v += __shfl_xor(v, 32);
        if ((lane >> 4) == 0)
            Lp[((size_t)half * M_ + bV + q0 + w * 32 + g * 16 + l15) * H_ + h] = v;
        #pragma unroll
        for (int i = 0; i < 4; ++i) {
            int q = q0 + w * 32 + g * 16 + l4 * 4 + i;
            u16* op = Ob + (bV + q) * D_ + h * 64;
            #pragma unroll
            for (int nb = 0; nb < 4; ++nb)
                op[nb * 16 + l15] = f2bf(o4[g][nb][i]);
        }
    }
}

// ---------------------------------------------------------------------------
extern "C" void kernel_launch(void* const* d_in, const int* in_sizes, int n_in,
                              void* d_out, int out_size, void* d_ws, size_t ws_size,
                              hipStream_t stream)
{
    (void)in_sizes; (void)n_in; (void)out_size; (void)ws_size;
    const float* x    = (const float*)d_in[0];
    const float* e    = (const float*)d_in[1];
    const float* conn = (const float*)d_in[2];
    const float* ln1g = (const float*)d_in[3];
    const float* ln1b = (const float*)d_in[4];
    const float* f1w1 = (const float*)d_in[5];
    const float* f1b1 = (const float*)d_in[6];
    const float* f1w2 = (const float*)d_in[7];
    const float* f1b2 = (const float*)d_in[8];
    const float* wq   = (const float*)d_in[9];
    const float* bq   = (const float*)d_in[10];
    const float* wk   = (const float*)d_in[11];
    const float* bk   = (const float*)d_in[12];
    const float* wv   = (const float*)d_in[13];
    const float* bv   = (const float*)d_in[14];
    const float* wp   = (const float*)d_in[15];
    const float* bp   = (const float*)d_in[16];
    const float* ln2g = (const float*)d_in[17];
    const float* ln2b = (const float*)d_in[18];
    const float* f2w1 = (const float*)d_in[19];
    const float* f2b1 = (const float*)d_in[20];
    const float* f2w2 = (const float*)d_in[21];
    const float* f2b2 = (const float*)d_in[22];
    const float* ffw1 = (const float*)d_in[23];
    const float* ffb1 = (const float*)d_in[24];
    const float* ffw2 = (const float*)d_in[25];
    const float* ffb2 = (const float*)d_in[26];
    float* out = (float*)d_out;

    // workspace schedule (MB offsets, peak 72 MB == proven-safe)
    char* ws = (char*)d_ws;
    const size_t MB = 1u << 20;
    u16*   Lm    = (u16*)(ws + 0);        // 0-16   log2-mask (live -> attn)
    u16*   e_bf  = (u16*)(ws + 16 * MB);  // 16-18  (live -> film2 gemm1)
    u16*   h     = (u16*)(ws + 18 * MB);  // 18-34
    u16*   wt2   = (u16*)(ws + 34 * MB);  // 34-36  small weight slot
    u16*   wt8   = (u16*)(ws + 36 * MB);  // 36-44  f1w2t / f2w2t
    u16*   gb    = (u16*)(ws + 44 * MB);  // 44-60
    u16*   y     = (u16*)(ws + 60 * MB);  // 60-68
    u16*   wqkvt = (u16*)(ws + 18 * MB);  // 18-24  (h dead)
    u16*   qkv   = (u16*)(ws + 24 * MB);  // 24-48  fused QKV [4096][3072]
    float* qkvb  = (float*)(ws + 71 * MB);// 71-72  outside all live ranges here
    u16*   o     = (u16*)(ws + 48 * MB);  // 48-56  (= attn partial O half0)
    float* Lp    = (float*)(ws + 64 * MB);// 64-64.5 attn partial row sums (512 KB)
    u16*   xnew  = (u16*)(ws + 64 * MB);  // 64-72  (Lp dead after combine)
    u16*   h2    = (u16*)(ws + 18 * MB);  // 18-34
    u16*   gb2   = (u16*)(ws + 44 * MB);  // 44-60
    u16*   y2    = (u16*)(ws + 0);        // 0-8    (Lm dead)
    u16*   ffw1t = (u16*)(ws + 8 * MB);   // 8-16
    u16*   t     = (u16*)(ws + 16 * MB);  // 16-48
    u16*   ffw2t = (u16*)(ws + 48 * MB);  // 48-56

    dim3 blk(256), tblk(32, 8);
    #define CONVT(W, WT, K, N) convT_k<<<dim3((N)/32, (K)/32), tblk, 0, stream>>>(W, WT, K, N)

    conv_k <<<(M_*DE_)/1024, blk, 0, stream>>>(e, e_bf);
    lmask_k<<<(B_*(size_t)V_*V_)/2048, blk, 0, stream>>>(conn, Lm);

    // FiLM 1  (thin-N: BN=64 pipelined variants)
    CONVT(f1w1, wt2, DE_, D2_);
    gemm_k<1, 64, u16, u16><<<dim3(D2_/64, M_/128), blk, 0, stream>>>(e_bf, wt2, f1b1, (const u16*)nullptr, h, M_, D2_, DE_);
    CONVT(f1w2, wt8, D2_, D2_);
    gemm_k<0, 64, u16, u16><<<dim3(D2_/64, M_/128), blk, 0, stream>>>(h, wt8, f1b2, (const u16*)nullptr, gb, M_, D2_, D2_);
    lnfilm_k<float><<<M_, blk, 0, stream>>>(x, gb, ln1g, ln1b, y);
    // fused QKV (wide: BN=128 pipelined)
    CONVT(wq, wqkvt,                 D_, D_);
    CONVT(wk, wqkvt + 1024 * 1024,   D_, D_);
    CONVT(wv, wqkvt + 2048 * 1024,   D_, D_);
    qkvbias_k<<<D3_/256, blk, 0, stream>>>(bq, bk, bv, qkvb);
    gemm_k<0, 128, u16, u16><<<dim3(D3_/128, M_/128), blk, 0, stream>>>(y, wqkvt, qkvb, (const u16*)nullptr, qkv, M_, D3_, D_);
    // attention, split-K over k-tiles (partials: O half0 @o, half1 @o+8MB, Lp)
    attn_k<<<2*B_*H_*(V_/128), blk, 0, stream>>>(qkv, qkv + 1024, qkv + 2048, Lm, o, Lp, D3_);
    combine_k<<<(M_*(size_t)D_)/2048, blk, 0, stream>>>(o, Lp, o);
    // projection + residual (res = x, f32; thin-N: BN=64)
    CONVT(wp, wt2, D_, D_);
    gemm_k<2, 64, u16, float><<<dim3(D_/64, M_/128), blk, 0, stream>>>(o, wt2, bp, x, xnew, M_, D_, D_);
    // FiLM 2  (thin-N: BN=64)
    CONVT(f2w1, wt2, DE_, D2_);
    gemm_k<1, 64, u16, u16><<<dim3(D2_/64, M_/128), blk, 0, stream>>>(e_bf, wt2, f2b1, (const u16*)nullptr, h2, M_, D2_, DE_);
    CONVT(f2w2, wt8, D2_, D2_);
    gemm_k<0, 64, u16, u16><<<dim3(D2_/64, M_/128), blk, 0, stream>>>(h2, wt8, f2b2, (const u16*)nullptr, gb2, M_, D2_, D2_);
    lnfilm_k<u16><<<M_, blk, 0, stream>>>(xnew, gb2, ln2g, ln2b, y2);
    // FFN + residual -> out (f32)
    CONVT(ffw1, ffw1t, D_, DFF_);
    gemm_k<1, 128, u16, u16><<<dim3(DFF_/128, M_/128), blk, 0, stream>>>(y2, ffw1t, ffb1, (const u16*)nullptr, t, M_, DFF_, D_);
    CONVT(ffw2, ffw2t, DFF_, D_);
    gemm_k<2, 64, float, u16><<<dim3(D_/64, M_/128), blk, 0, stream>>>(t, ffw2t, ffb2, xnew, out, M_, D_, DFF_);
    #undef CONVT
}

// Round 14
// 382.411 us; speedup vs baseline: 1.0844x; 1.0844x over previous
//
#include <hip/hip_runtime.h>
#include <math.h>
#include <stdint.h>

// Problem constants (B,V,D,H,DE,DFF fixed by the reference)
#define B_   2
#define V_   2048
#define D_   1024
#define H_   16
#define DK_  64
#define DE_  256
#define DFF_ 4096
#define M_   (B_*V_)     // 4096 tokens
#define D2_  (2*D_)      // 2048
#define D3_  (3*D_)      // 3072 (fused QKV width)

typedef unsigned short u16;
typedef unsigned int   u32;
typedef __bf16 bf16x8 __attribute__((ext_vector_type(8)));
typedef u16    u16x8  __attribute__((ext_vector_type(8)));
typedef u16    u16x4  __attribute__((ext_vector_type(4)));
typedef float  f32x4  __attribute__((ext_vector_type(4)));
typedef u32    u32x2  __attribute__((ext_vector_type(2)));
typedef u32    u32x4  __attribute__((ext_vector_type(4)));

__device__ __forceinline__ float bf2f(u16 u) {
    union { unsigned int i; float f; } z; z.i = ((unsigned int)u) << 16; return z.f;
}
__device__ __forceinline__ u16 f2bf(float f) {
    union { float f; unsigned int i; } z; z.f = f;
    unsigned int x = z.i;
    return (u16)((x + 0x7fffu + ((x >> 16) & 1u)) >> 16);  // RNE
}
__device__ __forceinline__ float gelu_erf(float v) {
    return 0.5f * v * (1.0f + erff(v * 0.70710678118654752f));
}
__device__ __forceinline__ float ldv(const float* p) { return *p; }
__device__ __forceinline__ float ldv(const u16* p)   { return bf2f(*p); }
__device__ __forceinline__ void  stv(float* p, float v) { *p = v; }
__device__ __forceinline__ void  stv(u16* p,   float v) { *p = f2bf(v); }

// async global->LDS, 16B per lane; LDS dest = wave-uniform base + lane*16
__device__ __forceinline__ void gload16(const u16* g, u16* lds)
{
    __builtin_amdgcn_global_load_lds(
        (const __attribute__((address_space(1))) void*)g,
        (__attribute__((address_space(3))) void*)(uintptr_t)lds,
        16, 0, 0);
}

// raw workgroup barrier WITHOUT the compiler's implicit vmcnt(0) drain.
__device__ __forceinline__ void barrier_raw()
{
    asm volatile("" ::: "memory");
    __builtin_amdgcn_s_barrier();
    asm volatile("" ::: "memory");
}

// ---------------------------------------------------------------------------
// Weight convert+transpose: Wt[N][K] bf16 <- W[K][N] f32 (32x32 LDS tiles)
// ---------------------------------------------------------------------------
__global__ void convT_k(const float* __restrict__ W, u16* __restrict__ Wt, int K, int N)
{
    __shared__ float tile[32][33];
    const int n0 = blockIdx.x * 32, k0 = blockIdx.y * 32;
    const int tx = threadIdx.x, ty = threadIdx.y;   // 32 x 8
    #pragma unroll
    for (int j = 0; j < 4; ++j)
        tile[ty * 4 + j][tx] = W[(size_t)(k0 + ty * 4 + j) * N + n0 + tx];
    __syncthreads();
    #pragma unroll
    for (int j = 0; j < 4; ++j)
        Wt[(size_t)(n0 + ty * 4 + j) * K + k0 + tx] = f2bf(tile[tx][ty * 4 + j]);
}

// batched 1024x1024 transposes (wq,wk,wv) selected by blockIdx.z
__global__ void convT3_k(const float* __restrict__ W0, const float* __restrict__ W1,
                         const float* __restrict__ W2, u16* __restrict__ Wt)
{
    __shared__ float tile[32][33];
    const float* W = blockIdx.z == 0 ? W0 : (blockIdx.z == 1 ? W1 : W2);
    u16* dst = Wt + (size_t)blockIdx.z * D_ * D_;
    const int n0 = blockIdx.x * 32, k0 = blockIdx.y * 32;
    const int tx = threadIdx.x, ty = threadIdx.y;
    #pragma unroll
    for (int j = 0; j < 4; ++j)
        tile[ty * 4 + j][tx] = W[(size_t)(k0 + ty * 4 + j) * D_ + n0 + tx];
    __syncthreads();
    #pragma unroll
    for (int j = 0; j < 4; ++j)
        dst[(size_t)(n0 + ty * 4 + j) * D_ + k0 + tx] = f2bf(tile[tx][ty * 4 + j]);
}

// elementwise f32 -> bf16 (n divisible by 4*256)
__global__ void conv_k(const float* __restrict__ X, u16* __restrict__ Y)
{
    const int i = (blockIdx.x * 256 + threadIdx.x) * 4;
    f32x4 v = *reinterpret_cast<const f32x4*>(X + i);
    u16x4 o;
    #pragma unroll
    for (int j = 0; j < 4; ++j) o[j] = f2bf(v[j]);
    *reinterpret_cast<u16x4*>(Y + i) = o;
}

// log2-mask precompute: Lm = bf16(log2(clip(conn,0,1)+1e-6)), 8 elems/thread
__global__ void lmask_k(const float* __restrict__ conn, u16* __restrict__ Lm)
{
    const size_t i = ((size_t)blockIdx.x * 256 + threadIdx.x) * 8;
    f32x4 a = *reinterpret_cast<const f32x4*>(conn + i);
    f32x4 b = *reinterpret_cast<const f32x4*>(conn + i + 4);
    u16x8 o;
    #pragma unroll
    for (int j = 0; j < 4; ++j) {
        o[j]     = f2bf(__log2f(fminf(fmaxf(a[j], 0.f), 1.f) + 1e-6f));
        o[j + 4] = f2bf(__log2f(fminf(fmaxf(b[j], 0.f), 1.f) + 1e-6f));
    }
    *reinterpret_cast<u16x8*>(Lm + i) = o;
}

// concat q/k/v biases into one 3072-wide f32 vector
__global__ void qkvbias_k(const float* __restrict__ bq, const float* __restrict__ bk,
                          const float* __restrict__ bv, float* __restrict__ o)
{
    int i = blockIdx.x * 256 + threadIdx.x;
    o[i] = i < 1024 ? bq[i] : (i < 2048 ? bk[i - 1024] : bv[i - 2048]);
}

// per-row LayerNorm stats: stats[row*2] = mean, stats[row*2+1] = rstd
template<typename TX>
__launch_bounds__(256)
__global__ void xstats_k(const TX* __restrict__ X, float* __restrict__ stats)
{
    const int row = blockIdx.x;
    const int tid = threadIdx.x;
    const TX* xr = X + (size_t)row * D_ + tid * 4;
    float s = 0.f, sq = 0.f;
    if constexpr (sizeof(TX) == 4) {
        f32x4 v4 = *reinterpret_cast<const f32x4*>(xr);
        #pragma unroll
        for (int j = 0; j < 4; ++j) { s += v4[j]; sq += v4[j] * v4[j]; }
    } else {
        u16x4 v4 = *reinterpret_cast<const u16x4*>(xr);
        #pragma unroll
        for (int j = 0; j < 4; ++j) { float v = bf2f(v4[j]); s += v; sq += v * v; }
    }
    #pragma unroll
    for (int off = 32; off; off >>= 1) {
        s  += __shfl_xor(s, off);
        sq += __shfl_xor(sq, off);
    }
    __shared__ float rs[4], rq[4];
    const int w = tid >> 6;
    if ((tid & 63) == 0) { rs[w] = s; rq[w] = sq; }
    __syncthreads();
    if (tid == 0) {
        s  = rs[0] + rs[1] + rs[2] + rs[3];
        sq = rq[0] + rq[1] + rq[2] + rq[3];
        float mean = s * (1.0f / D_);
        float var  = sq * (1.0f / D_) - mean * mean;
        stats[row * 2]     = mean;
        stats[row * 2 + 1] = rsqrtf(fmaxf(var, 0.f) + 1e-5f);
    }
}

// ---------------------------------------------------------------------------
// bf16 MFMA GEMM, counted-vmcnt pipelined: C = epi(A @ Wt^T + bias (+res))
// BM=128, BN in {128,64}; 4 waves; double-buffered LDS. (r12 version)
// EPI: 0 = none, 1 = exact-erf GELU, 2 = add residual
// ---------------------------------------------------------------------------
template<int EPI, int BN, typename TC, typename TRES>
__launch_bounds__(256)
__global__ void gemm_k(const u16* __restrict__ A, const u16* __restrict__ Wt,
                       const float* __restrict__ bias, const TRES* __restrict__ res,
                       TC* __restrict__ C, int M, int N, int K)
{
    constexpr int NB = BN / 32;
    constexpr int IB = BN / 32;
    __shared__ u16 As[2][128 * 64];
    __shared__ u16 Bs[2][BN * 64];

    const int tid  = threadIdx.x;
    const int lane = tid & 63;
    const int w    = tid >> 6;
    const int wm   = (w >> 1) * 64, wn = (w & 1) * (BN / 2);
    const int m0   = blockIdx.y * 128, n0 = blockIdx.x * BN;
    const int l15  = lane & 15, l4 = lane >> 4;
    const int rStage = lane >> 3;

    int rrA[4], ccA[4];
    #pragma unroll
    for (int i = 0; i < 4; ++i) {
        rrA[i] = w * 32 + i * 8 + rStage;
        ccA[i] = (lane & 7) ^ (rrA[i] & 7);
    }
    int rrB[IB], ccB[IB];
    #pragma unroll
    for (int i = 0; i < IB; ++i) {
        rrB[i] = w * (BN / 4) + i * 8 + rStage;
        ccB[i] = (lane & 7) ^ (rrB[i] & 7);
    }

    auto stage = [&](int kt, int dd) {
        const int k0 = kt * 64;
        #pragma unroll
        for (int i = 0; i < 4; ++i)
            gload16(A + (size_t)(m0 + rrA[i]) * K + k0 + ccA[i] * 8, &As[dd][w * 2048 + i * 512]);
        #pragma unroll
        for (int i = 0; i < IB; ++i)
            gload16(Wt + (size_t)(n0 + rrB[i]) * K + k0 + ccB[i] * 8, &Bs[dd][w * (BN * 16) + i * 512]);
    };

    f32x4 acc[4][NB] = {};
    const int NT = K / 64;

    stage(0, 0);

    for (int t = 0; t < NT; ++t) {
        const int d = t & 1;
        barrier_raw();
        if (t + 1 < NT) {
            stage(t + 1, d ^ 1);
            if constexpr (BN == 128) asm volatile("s_waitcnt vmcnt(8)" ::: "memory");
            else                     asm volatile("s_waitcnt vmcnt(6)" ::: "memory");
        } else {
            asm volatile("s_waitcnt vmcnt(0)" ::: "memory");
        }
        barrier_raw();
        __builtin_amdgcn_sched_barrier(0);

        #pragma unroll
        for (int kk = 0; kk < 2; ++kk) {
            bf16x8 a[4], b[NB];
            #pragma unroll
            for (int mb = 0; mb < 4; ++mb) {
                int r  = wm + mb * 16 + l15;
                int ph = (kk * 4 + l4) ^ (r & 7);
                a[mb] = *reinterpret_cast<const bf16x8*>(&As[d][r * 64 + ph * 8]);
            }
            #pragma unroll
            for (int nb = 0; nb < NB; ++nb) {
                int r  = wn + nb * 16 + l15;
                int ph = (kk * 4 + l4) ^ (r & 7);
                b[nb] = *reinterpret_cast<const bf16x8*>(&Bs[d][r * 64 + ph * 8]);
            }
            #pragma unroll
            for (int mb = 0; mb < 4; ++mb)
                #pragma unroll
                for (int nb = 0; nb < NB; ++nb)
                    acc[mb][nb] = __builtin_amdgcn_mfma_f32_16x16x32_bf16(a[mb], b[nb], acc[mb][nb], 0, 0, 0);
        }
    }

    #pragma unroll
    for (int nb = 0; nb < NB; ++nb) {
        int col = n0 + wn + nb * 16 + l15;
        float bv = bias[col];
        #pragma unroll
        for (int mb = 0; mb < 4; ++mb) {
            #pragma unroll
            for (int i = 0; i < 4; ++i) {
                int row = m0 + wm + mb * 16 + l4 * 4 + i;
                float v = acc[mb][nb][i] + bv;
                if (EPI == 1) v = gelu_erf(v);
                if (EPI == 2) v += ldv(res + (size_t)row * N + col);
                stv(C + (size_t)row * N + col, v);
            }
        }
    }
}

// ---------------------------------------------------------------------------
// Fused film-g2 + LayerNorm + FiLM:
//   gb = A @ Wt^T + b2 (two panels: gamma = cols [0,1024), beta = cols [1024,2048))
//   Y[row][col] = ((X[row][col]-mean)*rstd*lng[col] + lnb[col]) * (1+gamma) + beta
// A: h (bf16 [M][2048]); Wt: f1w2t (bf16 [2048][2048]); logical N = 1024.
// BM=128, BNlog=64 (two 64-row B panels staged). Grid (1024/64, M/128).
// ---------------------------------------------------------------------------
template<typename TX>
__launch_bounds__(256)
__global__ void gemmfilm_k(const u16* __restrict__ A, const u16* __restrict__ Wt,
                           const float* __restrict__ b2, const TX* __restrict__ X,
                           const float* __restrict__ stats,
                           const float* __restrict__ lng, const float* __restrict__ lnb,
                           u16* __restrict__ Y)
{
    constexpr int Kc = D2_;            // 2048
    __shared__ u16 As[2][128 * 64];
    __shared__ u16 Bs[2][128 * 64];    // rows 0-63: gamma panel, 64-127: beta panel

    const int tid  = threadIdx.x;
    const int lane = tid & 63;
    const int w    = tid >> 6;
    const int wm   = (w >> 1) * 64, wn = (w & 1) * 32;
    const int m0   = blockIdx.y * 128, n0 = blockIdx.x * 64;
    const int l15  = lane & 15, l4 = lane >> 4;
    const int rStage = lane >> 3;

    int rrA[4], ccA[4];
    #pragma unroll
    for (int i = 0; i < 4; ++i) {
        rrA[i] = w * 32 + i * 8 + rStage;
        ccA[i] = (lane & 7) ^ (rrA[i] & 7);
    }
    // B: 4 issues/wave; i<2 -> gamma panel, i>=2 -> beta panel; 16 rows/wave/panel
    int rowB[4], ccB[4], grB[4];
    #pragma unroll
    for (int i = 0; i < 4; ++i) {
        int lr = w * 16 + (i & 1) * 8 + rStage;            // row within panel (0-63)
        rowB[i] = (i < 2 ? 0 : 64) + lr;                   // row in Bs
        grB[i]  = (i < 2 ? n0 : D_ + n0) + lr;             // row in Wt
        ccB[i]  = (lane & 7) ^ (lr & 7);
    }

    auto stage = [&](int kt, int dd) {
        const int k0 = kt * 64;
        #pragma unroll
        for (int i = 0; i < 4; ++i)
            gload16(A + (size_t)(m0 + rrA[i]) * Kc + k0 + ccA[i] * 8, &As[dd][w * 2048 + i * 512]);
        #pragma unroll
        for (int i = 0; i < 4; ++i)
            gload16(Wt + (size_t)grB[i] * Kc + k0 + ccB[i] * 8,
                    &Bs[dd][((i < 2 ? 0 : 64) + w * 16 + (i & 1) * 8) * 64]);
    };

    f32x4 accG[4][2] = {}, accB2[4][2] = {};
    const int NT = Kc / 64;

    stage(0, 0);

    for (int t = 0; t < NT; ++t) {
        const int d = t & 1;
        barrier_raw();
        if (t + 1 < NT) {
            stage(t + 1, d ^ 1);
            asm volatile("s_waitcnt vmcnt(8)" ::: "memory");
        } else {
            asm volatile("s_waitcnt vmcnt(0)" ::: "memory");
        }
        barrier_raw();
        __builtin_amdgcn_sched_barrier(0);

        #pragma unroll
        for (int kk = 0; kk < 2; ++kk) {
            bf16x8 a[4], bg[2], bb[2];
            #pragma unroll
            for (int mb = 0; mb < 4; ++mb) {
                int r  = wm + mb * 16 + l15;
                int ph = (kk * 4 + l4) ^ (r & 7);
                a[mb] = *reinterpret_cast<const bf16x8*>(&As[d][r * 64 + ph * 8]);
            }
            #pragma unroll
            for (int nb = 0; nb < 2; ++nb) {
                int r  = wn + nb * 16 + l15;                 // panel-local row
                int ph = (kk * 4 + l4) ^ (r & 7);
                bg[nb] = *reinterpret_cast<const bf16x8*>(&Bs[d][r * 64 + ph * 8]);
                bb[nb] = *reinterpret_cast<const bf16x8*>(&Bs[d][(64 + r) * 64 + ph * 8]);
            }
            #pragma unroll
            for (int mb = 0; mb < 4; ++mb)
                #pragma unroll
                for (int nb = 0; nb < 2; ++nb) {
                    accG[mb][nb]  = __builtin_amdgcn_mfma_f32_16x16x32_bf16(a[mb], bg[nb], accG[mb][nb], 0, 0, 0);
                    accB2[mb][nb] = __builtin_amdgcn_mfma_f32_16x16x32_bf16(a[mb], bb[nb], accB2[mb][nb], 0, 0, 0);
                }
        }
    }

    // epilogue: apply LN + FiLM, write y
    #pragma unroll
    for (int nb = 0; nb < 2; ++nb) {
        int col = n0 + wn + nb * 16 + l15;
        float gb_ = b2[col], bb_ = b2[D_ + col];
        float lg = lng[col], lb = lnb[col];
        #pragma unroll
        for (int mb = 0; mb < 4; ++mb) {
            #pragma unroll
            for (int i = 0; i < 4; ++i) {
                int row = m0 + wm + mb * 16 + l4 * 4 + i;
                float mean = stats[row * 2], rstd = stats[row * 2 + 1];
                float xv = ldv(X + (size_t)row * D_ + col);
                float gamma = accG[mb][nb][i] + gb_;
                float beta  = accB2[mb][nb][i] + bb_;
                float v = ((xv - mean) * rstd * lg + lb) * (1.0f + gamma) + beta;
                Y[(size_t)row * D_ + col] = f2bf(v);
            }
        }
    }
}

// ---------------------------------------------------------------------------
// Flash attention (r12 version, verbatim).
// ---------------------------------------------------------------------------
__launch_bounds__(256)
__global__ void attn_k(const u16* __restrict__ Q, const u16* __restrict__ K,
                       const u16* __restrict__ Vv, const u16* __restrict__ Lm,
                       u16* __restrict__ O, int ld)
{
    __shared__ u16 Ks[64 * 64];
    __shared__ u16 Vs[64 * 64];
    __shared__ u16 Lms[128 * 64];
    __shared__ u16 Ps[128 * 72];

    const int blk = blockIdx.x;
    const int qt  = blk & 15;
    const int h   = (blk >> 4) & 15;
    const int b   = blk >> 8;
    const int q0  = qt * 128;
    const int tid = threadIdx.x, lane = tid & 63, w = tid >> 6;
    const int l15 = lane & 15, l4 = lane >> 4;
    const size_t bV = (size_t)b * V_;

    bf16x8 qa[2][2];
    #pragma unroll
    for (int g = 0; g < 2; ++g) {
        const u16* qp = Q + (bV + q0 + w * 32 + g * 16 + l15) * ld + h * 64;
        u16x8 r0 = *reinterpret_cast<const u16x8*>(qp + l4 * 8);
        u16x8 r1 = *reinterpret_cast<const u16x8*>(qp + 32 + l4 * 8);
        u16x8 s0, s1;
        #pragma unroll
        for (int j = 0; j < 8; ++j) {
            s0[j] = f2bf(bf2f(r0[j]) * 0.125f);
            s1[j] = f2bf(bf2f(r1[j]) * 0.125f);
        }
        union { u16x8 u; bf16x8 h; } c0, c1;
        c0.u = s0; c1.u = s1;
        qa[g][0] = c0.h; qa[g][1] = c1.h;
    }

    const int rStage = (lane >> 3);
    const int cSw    = ((lane & 7) ^ rStage) * 8;
    const int vK     = ((lane >> 5) << 2) + ((lane & 7) >> 1);
    const int vDk    = ((lane >> 3) & 3) * 16 + (lane & 1) * 8;
    const u32 vaddr  = (u32)(uintptr_t)&Vs[0] + (l4 << 10) + (l15 << 3);

    int lmOff[4];
    #pragma unroll
    for (int kb = 0; kb < 4; ++kb)
        lmOff[kb] = ((((kb << 1) | (l4 >> 1)) ^ (l15 & 7)) << 3);

    const float LOG2E = 1.44269504088896f;
    float lrp[2] = {0.f, 0.f};
    f32x4 o4[2][4] = {};

    for (int kt = 0; kt < V_ / 64; ++kt) {
        const int k0 = kt * 64;
        if (kt) __syncthreads();
        #pragma unroll
        for (int i = 0; i < 2; ++i) {
            int r  = i * 32 + w * 8 + rStage;
            int kv = i * 32 + w * 8 + vK;
            gload16(K  + (bV + k0 + r)  * ld + h * 64 + cSw, &Ks[i * 2048 + w * 512]);
            gload16(Vv + (bV + k0 + kv) * ld + h * 64 + vDk, &Vs[i * 2048 + w * 512]);
        }
        #pragma unroll
        for (int i = 0; i < 4; ++i) {
            int r = i * 32 + w * 8 + rStage;
            gload16(Lm + (bV + q0 + r) * (size_t)V_ + k0 + cSw, &Lms[i * 2048 + w * 512]);
        }
        __syncthreads();

        #pragma unroll
        for (int g = 0; g < 2; ++g) {
            f32x4 s[4];
            #pragma unroll
            for (int kb = 0; kb < 4; ++kb) {
                int row = (kb * 16 + l15) * 64;
                bf16x8 k0f = *reinterpret_cast<const bf16x8*>(&Ks[row + ((l4 ^ (l15 & 7)) * 8)]);
                bf16x8 k1f = *reinterpret_cast<const bf16x8*>(&Ks[row + (((l4 + 4) ^ (l15 & 7)) * 8)]);
                f32x4 z = {};
                z = __builtin_amdgcn_mfma_f32_16x16x32_bf16(k0f, qa[g][0], z, 0, 0, 0);
                z = __builtin_amdgcn_mfma_f32_16x16x32_bf16(k1f, qa[g][1], z, 0, 0, 0);
                s[kb] = z;
            }
            const int lmRow = w * 32 + g * 16 + l15;
            const u16* lmBase = &Lms[lmRow * 64 + (l4 & 1) * 4];
            u16* psW = &Ps[lmRow * 72 + l4 * 4];
            #pragma unroll
            for (int kb = 0; kb < 4; ++kb) {
                u16x4 lm4 = *reinterpret_cast<const u16x4*>(lmBase + lmOff[kb]);
                float p0, p1, p2, p3;
                float t0 = fmaf(s[kb][0], LOG2E, bf2f(lm4[0]));
                float t1 = fmaf(s[kb][1], LOG2E, bf2f(lm4[1]));
                float t2 = fmaf(s[kb][2], LOG2E, bf2f(lm4[2]));
                float t3 = fmaf(s[kb][3], LOG2E, bf2f(lm4[3]));
                asm("v_exp_f32 %0, %1" : "=v"(p0) : "v"(t0));
                asm("v_exp_f32 %0, %1" : "=v"(p1) : "v"(t1));
                asm("v_exp_f32 %0, %1" : "=v"(p2) : "v"(t2));
                asm("v_exp_f32 %0, %1" : "=v"(p3) : "v"(t3));
                lrp[g] += (p0 + p1) + (p2 + p3);
                u32 d0, d1;
                asm("v_cvt_pk_bf16_f32 %0, %1, %2" : "=v"(d0) : "v"(p0), "v"(p1));
                asm("v_cvt_pk_bf16_f32 %0, %1, %2" : "=v"(d1) : "v"(p2), "v"(p3));
                u32x2 dd = {d0, d1};
                *reinterpret_cast<u32x2*>(psW + kb * 16) = dd;
            }
        }

        union VU { u32x4 u; bf16x8 h; };
        VU vb[2][4];
        #pragma unroll
        for (int c2 = 0; c2 < 2; ++c2) {
            u32 a0 = vaddr + c2 * 4096;
            u32x2 t0, t1, t2, t3, t4, t5, t6, t7;
            asm volatile("ds_read_b64_tr_b16 %0, %1"            : "=v"(t0) : "v"(a0));
            asm volatile("ds_read_b64_tr_b16 %0, %1 offset:512" : "=v"(t1) : "v"(a0));
            asm volatile("ds_read_b64_tr_b16 %0, %1 offset:128" : "=v"(t2) : "v"(a0));
            asm volatile("ds_read_b64_tr_b16 %0, %1 offset:640" : "=v"(t3) : "v"(a0));
            asm volatile("ds_read_b64_tr_b16 %0, %1 offset:256" : "=v"(t4) : "v"(a0));
            asm volatile("ds_read_b64_tr_b16 %0, %1 offset:768" : "=v"(t5) : "v"(a0));
            asm volatile("ds_read_b64_tr_b16 %0, %1 offset:384" : "=v"(t6) : "v"(a0));
            asm volatile("ds_read_b64_tr_b16 %0, %1 offset:896" : "=v"(t7) : "v"(a0));
            asm volatile("s_waitcnt lgkmcnt(0)" ::: "memory");
            __builtin_amdgcn_sched_barrier(0);
            vb[c2][0].u = (u32x4){t0.x, t0.y, t1.x, t1.y};
            vb[c2][1].u = (u32x4){t2.x, t2.y, t3.x, t3.y};
            vb[c2][2].u = (u32x4){t4.x, t4.y, t5.x, t5.y};
            vb[c2][3].u = (u32x4){t6.x, t6.y, t7.x, t7.y};
        }
        #pragma unroll
        for (int g = 0; g < 2; ++g) {
            const u16* pr = &Ps[(w * 32 + g * 16 + l15) * 72];
            bf16x8 pa0 = *reinterpret_cast<const bf16x8*>(pr + l4 * 8);
            bf16x8 pa1 = *reinterpret_cast<const bf16x8*>(pr + 32 + l4 * 8);
            #pragma unroll
            for (int nb = 0; nb < 4; ++nb) {
                o4[g][nb] = __builtin_amdgcn_mfma_f32_16x16x32_bf16(pa0, vb[0][nb].h, o4[g][nb], 0, 0, 0);
                o4[g][nb] = __builtin_amdgcn_mfma_f32_16x16x32_bf16(pa1, vb[1][nb].h, o4[g][nb], 0, 0, 0);
            }
        }
    }

    #pragma unroll
    for (int g = 0; g < 2; ++g) {
        float v = lrp[g];
        v += __shfl_xor(v, 16);
        v += __shfl_xor(v, 32);
        #pragma unroll
        for (int i = 0; i < 4; ++i) {
            float lw = __shfl(v, (lane & 48) | ((l4 << 2) + i));
            float rcp = 1.0f / (lw + 1e-8f);
            int q = q0 + w * 32 + g * 16 + l4 * 4 + i;
            u16* op = O + (bV + q) * D_ + h * 64;
            #pragma unroll
            for (int nb = 0; nb < 4; ++nb)
                op[nb * 16 + l15] = f2bf(o4[g][nb][i] * rcp);
        }
    }
}

// ---------------------------------------------------------------------------
extern "C" void kernel_launch(void* const* d_in, const int* in_sizes, int n_in,
                              void* d_out, int out_size, void* d_ws, size_t ws_size,
                              hipStream_t stream)
{
    (void)in_sizes; (void)n_in; (void)out_size; (void)ws_size;
    const float* x    = (const float*)d_in[0];
    const float* e    = (const float*)d_in[1];
    const float* conn = (const float*)d_in[2];
    const float* ln1g = (const float*)d_in[3];
    const float* ln1b = (const float*)d_in[4];
    const float* f1w1 = (const float*)d_in[5];
    const float* f1b1 = (const float*)d_in[6];
    const float* f1w2 = (const float*)d_in[7];
    const float* f1b2 = (const float*)d_in[8];
    const float* wq   = (const float*)d_in[9];
    const float* bq   = (const float*)d_in[10];
    const float* wk   = (const float*)d_in[11];
    const float* bk   = (const float*)d_in[12];
    const float* wv   = (const float*)d_in[13];
    const float* bv   = (const float*)d_in[14];
    const float* wp   = (const float*)d_in[15];
    const float* bp   = (const float*)d_in[16];
    const float* ln2g = (const float*)d_in[17];
    const float* ln2b = (const float*)d_in[18];
    const float* f2w1 = (const float*)d_in[19];
    const float* f2b1 = (const float*)d_in[20];
    const float* f2w2 = (const float*)d_in[21];
    const float* f2b2 = (const float*)d_in[22];
    const float* ffw1 = (const float*)d_in[23];
    const float* ffb1 = (const float*)d_in[24];
    const float* ffw2 = (const float*)d_in[25];
    const float* ffb2 = (const float*)d_in[26];
    float* out = (float*)d_out;

    // workspace schedule (MB offsets, peak 72 MB == proven-safe, r12 layout + stats)
    char* ws = (char*)d_ws;
    const size_t MB = 1u << 20;
    u16*   Lm    = (u16*)(ws + 0);        // 0-16   log2-mask (live -> attn)
    u16*   e_bf  = (u16*)(ws + 16 * MB);  // 16-18  (live -> film2 gemm1)
    u16*   h     = (u16*)(ws + 18 * MB);  // 18-34
    u16*   wt2   = (u16*)(ws + 34 * MB);  // 34-36  small weight slot (f1w1t/wpt/f2w1t 1-2MB)
    float* stats = (float*)(ws + 35 * MB);// 35-36  LN row stats (32 KB; disjoint from 1MB wt2 users)
    u16*   wt8   = (u16*)(ws + 36 * MB);  // 36-44  f1w2t / f2w2t
    u16*   y     = (u16*)(ws + 60 * MB);  // 60-68
    u16*   wqkvt = (u16*)(ws + 18 * MB);  // 18-24  (h dead)
    u16*   qkv   = (u16*)(ws + 24 * MB);  // 24-48  fused QKV [4096][3072]
    float* qkvb  = (float*)(ws + 71 * MB);// 71-72
    u16*   o     = (u16*)(ws + 48 * MB);  // 48-56
    u16*   xnew  = (u16*)(ws + 64 * MB);  // 64-72  (y dead by then)
    u16*   h2    = (u16*)(ws + 18 * MB);  // 18-34
    u16*   y2    = (u16*)(ws + 0);        // 0-8    (Lm dead)
    u16*   ffw1t = (u16*)(ws + 8 * MB);   // 8-16
    u16*   t     = (u16*)(ws + 16 * MB);  // 16-48
    u16*   ffw2t = (u16*)(ws + 48 * MB);  // 48-56

    dim3 blk(256), tblk(32, 8);
    #define CONVT(W, WT, K, N) convT_k<<<dim3((N)/32, (K)/32), tblk, 0, stream>>>(W, WT, K, N)

    conv_k <<<(M_*DE_)/1024, blk, 0, stream>>>(e, e_bf);
    lmask_k<<<(B_*(size_t)V_*V_)/2048, blk, 0, stream>>>(conn, Lm);

    // FiLM 1: g1 GEMM, then fused g2+LN+FiLM
    CONVT(f1w1, wt2, DE_, D2_);
    gemm_k<1, 64, u16, u16><<<dim3(D2_/64, M_/128), blk, 0, stream>>>(e_bf, wt2, f1b1, (const u16*)nullptr, h, M_, D2_, DE_);
    xstats_k<float><<<M_, blk, 0, stream>>>(x, stats);
    CONVT(f1w2, wt8, D2_, D2_);
    gemmfilm_k<float><<<dim3(D_/64, M_/128), blk, 0, stream>>>(h, wt8, f1b2, x, stats, ln1g, ln1b, y);
    // fused QKV (batched transposes + BN=128 pipelined GEMM)
    convT3_k<<<dim3(D_/32, D_/32, 3), tblk, 0, stream>>>(wq, wk, wv, wqkvt);
    qkvbias_k<<<D3_/256, blk, 0, stream>>>(bq, bk, bv, qkvb);
    gemm_k<0, 128, u16, u16><<<dim3(D3_/128, M_/128), blk, 0, stream>>>(y, wqkvt, qkvb, (const u16*)nullptr, qkv, M_, D3_, D_);
    // attention (QBLK=128)
    attn_k<<<B_*H_*(V_/128), blk, 0, stream>>>(qkv, qkv + 1024, qkv + 2048, Lm, o, D3_);
    // projection + residual (res = x, f32)
    CONVT(wp, wt2, D_, D_);
    gemm_k<2, 64, u16, float><<<dim3(D_/64, M_/128), blk, 0, stream>>>(o, wt2, bp, x, xnew, M_, D_, D_);
    // FiLM 2: g1 GEMM, then fused g2+LN+FiLM (stats from xnew)
    CONVT(f2w1, wt2, DE_, D2_);
    gemm_k<1, 64, u16, u16><<<dim3(D2_/64, M_/128), blk, 0, stream>>>(e_bf, wt2, f2b1, (const u16*)nullptr, h2, M_, D2_, DE_);
    xstats_k<u16><<<M_, blk, 0, stream>>>(xnew, stats);
    CONVT(f2w2, wt8, D2_, D2_);
    gemmfilm_k<u16><<<dim3(D_/64, M_/128), blk, 0, stream>>>(h2, wt8, f2b2, xnew, stats, ln2g, ln2b, y2);
    // FFN + residual -> out (f32)
    CONVT(ffw1, ffw1t, D_, DFF_);
    gemm_k<1, 128, u16, u16><<<dim3(DFF_/128, M_/128), blk, 0, stream>>>(y2, ffw1t, ffb1, (const u16*)nullptr, t, M_, DFF_, D_);
    CONVT(ffw2, ffw2t, DFF_, D_);
    gemm_k<2, 64, float, u16><<<dim3(D_/64, M_/128), blk, 0, stream>>>(t, ffw2t, ffb2, xnew, out, M_, D_, DFF_);
    #undef CONVT
}

// Round 15
// 378.524 us; speedup vs baseline: 1.0956x; 1.0103x over previous
//
#include <hip/hip_runtime.h>
#include <math.h>
#include <stdint.h>

// Problem constants (B,V,D,H,DE,DFF fixed by the reference)
#define B_   2
#define V_   2048
#define D_   1024
#define H_   16
#define DK_  64
#define DE_  256
#define DFF_ 4096
#define M_   (B_*V_)     // 4096 tokens
#define D2_  (2*D_)      // 2048
#define D3_  (3*D_)      // 3072 (fused QKV width)

typedef unsigned short u16;
typedef unsigned int   u32;
typedef __bf16 bf16x8 __attribute__((ext_vector_type(8)));
typedef u16    u16x8  __attribute__((ext_vector_type(8)));
typedef u16    u16x4  __attribute__((ext_vector_type(4)));
typedef float  f32x4  __attribute__((ext_vector_type(4)));
typedef u32    u32x2  __attribute__((ext_vector_type(2)));
typedef u32    u32x4  __attribute__((ext_vector_type(4)));

__device__ __forceinline__ float bf2f(u16 u) {
    union { unsigned int i; float f; } z; z.i = ((unsigned int)u) << 16; return z.f;
}
__device__ __forceinline__ u16 f2bf(float f) {
    union { float f; unsigned int i; } z; z.f = f;
    unsigned int x = z.i;
    return (u16)((x + 0x7fffu + ((x >> 16) & 1u)) >> 16);  // RNE
}
__device__ __forceinline__ float gelu_erf(float v) {
    return 0.5f * v * (1.0f + erff(v * 0.70710678118654752f));
}
__device__ __forceinline__ float ldv(const float* p) { return *p; }
__device__ __forceinline__ float ldv(const u16* p)   { return bf2f(*p); }
__device__ __forceinline__ void  stv(float* p, float v) { *p = v; }
__device__ __forceinline__ void  stv(u16* p,   float v) { *p = f2bf(v); }

// async global->LDS, 16B per lane; LDS dest = wave-uniform base + lane*16
__device__ __forceinline__ void gload16(const u16* g, u16* lds)
{
    __builtin_amdgcn_global_load_lds(
        (const __attribute__((address_space(1))) void*)g,
        (__attribute__((address_space(3))) void*)(uintptr_t)lds,
        16, 0, 0);
}

// raw workgroup barrier WITHOUT the compiler's implicit vmcnt(0) drain.
__device__ __forceinline__ void barrier_raw()
{
    asm volatile("" ::: "memory");
    __builtin_amdgcn_s_barrier();
    asm volatile("" ::: "memory");
}

// ---------------------------------------------------------------------------
// Weight convert+transpose: Wt[N][K] bf16 <- W[K][N] f32 (32x32 LDS tiles)
// ---------------------------------------------------------------------------
__global__ void convT_k(const float* __restrict__ W, u16* __restrict__ Wt, int K, int N)
{
    __shared__ float tile[32][33];
    const int n0 = blockIdx.x * 32, k0 = blockIdx.y * 32;
    const int tx = threadIdx.x, ty = threadIdx.y;   // 32 x 8
    #pragma unroll
    for (int j = 0; j < 4; ++j)
        tile[ty * 4 + j][tx] = W[(size_t)(k0 + ty * 4 + j) * N + n0 + tx];
    __syncthreads();
    #pragma unroll
    for (int j = 0; j < 4; ++j)
        Wt[(size_t)(n0 + ty * 4 + j) * K + k0 + tx] = f2bf(tile[tx][ty * 4 + j]);
}

// batched 1024x1024 transposes (wq,wk,wv) selected by blockIdx.z
__global__ void convT3_k(const float* __restrict__ W0, const float* __restrict__ W1,
                         const float* __restrict__ W2, u16* __restrict__ Wt)
{
    __shared__ float tile[32][33];
    const float* W = blockIdx.z == 0 ? W0 : (blockIdx.z == 1 ? W1 : W2);
    u16* dst = Wt + (size_t)blockIdx.z * D_ * D_;
    const int n0 = blockIdx.x * 32, k0 = blockIdx.y * 32;
    const int tx = threadIdx.x, ty = threadIdx.y;
    #pragma unroll
    for (int j = 0; j < 4; ++j)
        tile[ty * 4 + j][tx] = W[(size_t)(k0 + ty * 4 + j) * D_ + n0 + tx];
    __syncthreads();
    #pragma unroll
    for (int j = 0; j < 4; ++j)
        dst[(size_t)(n0 + ty * 4 + j) * D_ + k0 + tx] = f2bf(tile[tx][ty * 4 + j]);
}

// ---------------------------------------------------------------------------
// prep: fused prologue (lmask + e->bf16 + LN stats of x + qkv bias concat),
// dispatched by blockIdx range. Saves 3 launches and overlaps the streams.
// ---------------------------------------------------------------------------
#define NL_ 4096   // lmask blocks:  B*V*V/2048
#define NC_ 1024   // conv blocks:   M*DE/1024
#define NX_ 4096   // xstats blocks: M
__launch_bounds__(256)
__global__ void prep_k(const float* __restrict__ conn, u16* __restrict__ Lm,
                       const float* __restrict__ e, u16* __restrict__ e_bf,
                       const float* __restrict__ X, float* __restrict__ stats,
                       const float* __restrict__ bq, const float* __restrict__ bk,
                       const float* __restrict__ bv, float* __restrict__ qkvb)
{
    __shared__ float rs[4], rq[4];
    const int bid = blockIdx.x;
    const int tid = threadIdx.x;
    if (bid < NL_) {
        const size_t i = ((size_t)bid * 256 + tid) * 8;
        f32x4 a = *reinterpret_cast<const f32x4*>(conn + i);
        f32x4 b = *reinterpret_cast<const f32x4*>(conn + i + 4);
        u16x8 o;
        #pragma unroll
        for (int j = 0; j < 4; ++j) {
            o[j]     = f2bf(__log2f(fminf(fmaxf(a[j], 0.f), 1.f) + 1e-6f));
            o[j + 4] = f2bf(__log2f(fminf(fmaxf(b[j], 0.f), 1.f) + 1e-6f));
        }
        *reinterpret_cast<u16x8*>(Lm + i) = o;
    } else if (bid < NL_ + NC_) {
        const int i = ((bid - NL_) * 256 + tid) * 4;
        f32x4 v = *reinterpret_cast<const f32x4*>(e + i);
        u16x4 o;
        #pragma unroll
        for (int j = 0; j < 4; ++j) o[j] = f2bf(v[j]);
        *reinterpret_cast<u16x4*>(e_bf + i) = o;
    } else if (bid < NL_ + NC_ + NX_) {
        const int row = bid - NL_ - NC_;
        f32x4 v4 = *reinterpret_cast<const f32x4*>(X + (size_t)row * D_ + tid * 4);
        float s = 0.f, sq = 0.f;
        #pragma unroll
        for (int j = 0; j < 4; ++j) { s += v4[j]; sq += v4[j] * v4[j]; }
        #pragma unroll
        for (int off = 32; off; off >>= 1) {
            s  += __shfl_xor(s, off);
            sq += __shfl_xor(sq, off);
        }
        const int w = tid >> 6;
        if ((tid & 63) == 0) { rs[w] = s; rq[w] = sq; }
        __syncthreads();
        if (tid == 0) {
            s  = rs[0] + rs[1] + rs[2] + rs[3];
            sq = rq[0] + rq[1] + rq[2] + rq[3];
            float mean = s * (1.0f / D_);
            float var  = sq * (1.0f / D_) - mean * mean;
            stats[row * 2]     = mean;
            stats[row * 2 + 1] = rsqrtf(fmaxf(var, 0.f) + 1e-5f);
        }
    } else {
        const int i = (bid - NL_ - NC_ - NX_) * 256 + tid;
        qkvb[i] = i < 1024 ? bq[i] : (i < 2048 ? bk[i - 1024] : bv[i - 2048]);
    }
}

// per-row LayerNorm stats (standalone, for xnew)
template<typename TX>
__launch_bounds__(256)
__global__ void xstats_k(const TX* __restrict__ X, float* __restrict__ stats)
{
    const int row = blockIdx.x;
    const int tid = threadIdx.x;
    const TX* xr = X + (size_t)row * D_ + tid * 4;
    float s = 0.f, sq = 0.f;
    if constexpr (sizeof(TX) == 4) {
        f32x4 v4 = *reinterpret_cast<const f32x4*>(xr);
        #pragma unroll
        for (int j = 0; j < 4; ++j) { s += v4[j]; sq += v4[j] * v4[j]; }
    } else {
        u16x4 v4 = *reinterpret_cast<const u16x4*>(xr);
        #pragma unroll
        for (int j = 0; j < 4; ++j) { float v = bf2f(v4[j]); s += v; sq += v * v; }
    }
    #pragma unroll
    for (int off = 32; off; off >>= 1) {
        s  += __shfl_xor(s, off);
        sq += __shfl_xor(sq, off);
    }
    __shared__ float rs[4], rq[4];
    const int w = tid >> 6;
    if ((tid & 63) == 0) { rs[w] = s; rq[w] = sq; }
    __syncthreads();
    if (tid == 0) {
        s  = rs[0] + rs[1] + rs[2] + rs[3];
        sq = rq[0] + rq[1] + rq[2] + rq[3];
        float mean = s * (1.0f / D_);
        float var  = sq * (1.0f / D_) - mean * mean;
        stats[row * 2]     = mean;
        stats[row * 2 + 1] = rsqrtf(fmaxf(var, 0.f) + 1e-5f);
    }
}

// ---------------------------------------------------------------------------
// bf16 MFMA GEMM, counted-vmcnt pipelined: C = epi(A @ Wt^T + bias (+res))
// BM=128, BN in {128,64}; 4 waves; double-buffered LDS. (r12 version)
// EPI: 0 = none, 1 = exact-erf GELU, 2 = add residual
// ---------------------------------------------------------------------------
template<int EPI, int BN, typename TC, typename TRES>
__launch_bounds__(256)
__global__ void gemm_k(const u16* __restrict__ A, const u16* __restrict__ Wt,
                       const float* __restrict__ bias, const TRES* __restrict__ res,
                       TC* __restrict__ C, int M, int N, int K)
{
    constexpr int NB = BN / 32;
    constexpr int IB = BN / 32;
    __shared__ u16 As[2][128 * 64];
    __shared__ u16 Bs[2][BN * 64];

    const int tid  = threadIdx.x;
    const int lane = tid & 63;
    const int w    = tid >> 6;
    const int wm   = (w >> 1) * 64, wn = (w & 1) * (BN / 2);
    const int m0   = blockIdx.y * 128, n0 = blockIdx.x * BN;
    const int l15  = lane & 15, l4 = lane >> 4;
    const int rStage = lane >> 3;

    int rrA[4], ccA[4];
    #pragma unroll
    for (int i = 0; i < 4; ++i) {
        rrA[i] = w * 32 + i * 8 + rStage;
        ccA[i] = (lane & 7) ^ (rrA[i] & 7);
    }
    int rrB[IB], ccB[IB];
    #pragma unroll
    for (int i = 0; i < IB; ++i) {
        rrB[i] = w * (BN / 4) + i * 8 + rStage;
        ccB[i] = (lane & 7) ^ (rrB[i] & 7);
    }

    auto stage = [&](int kt, int dd) {
        const int k0 = kt * 64;
        #pragma unroll
        for (int i = 0; i < 4; ++i)
            gload16(A + (size_t)(m0 + rrA[i]) * K + k0 + ccA[i] * 8, &As[dd][w * 2048 + i * 512]);
        #pragma unroll
        for (int i = 0; i < IB; ++i)
            gload16(Wt + (size_t)(n0 + rrB[i]) * K + k0 + ccB[i] * 8, &Bs[dd][w * (BN * 16) + i * 512]);
    };

    f32x4 acc[4][NB] = {};
    const int NT = K / 64;

    stage(0, 0);

    for (int t = 0; t < NT; ++t) {
        const int d = t & 1;
        barrier_raw();
        if (t + 1 < NT) {
            stage(t + 1, d ^ 1);
            if constexpr (BN == 128) asm volatile("s_waitcnt vmcnt(8)" ::: "memory");
            else                     asm volatile("s_waitcnt vmcnt(6)" ::: "memory");
        } else {
            asm volatile("s_waitcnt vmcnt(0)" ::: "memory");
        }
        barrier_raw();
        __builtin_amdgcn_sched_barrier(0);

        #pragma unroll
        for (int kk = 0; kk < 2; ++kk) {
            bf16x8 a[4], b[NB];
            #pragma unroll
            for (int mb = 0; mb < 4; ++mb) {
                int r  = wm + mb * 16 + l15;
                int ph = (kk * 4 + l4) ^ (r & 7);
                a[mb] = *reinterpret_cast<const bf16x8*>(&As[d][r * 64 + ph * 8]);
            }
            #pragma unroll
            for (int nb = 0; nb < NB; ++nb) {
                int r  = wn + nb * 16 + l15;
                int ph = (kk * 4 + l4) ^ (r & 7);
                b[nb] = *reinterpret_cast<const bf16x8*>(&Bs[d][r * 64 + ph * 8]);
            }
            #pragma unroll
            for (int mb = 0; mb < 4; ++mb)
                #pragma unroll
                for (int nb = 0; nb < NB; ++nb)
                    acc[mb][nb] = __builtin_amdgcn_mfma_f32_16x16x32_bf16(a[mb], b[nb], acc[mb][nb], 0, 0, 0);
        }
    }

    #pragma unroll
    for (int nb = 0; nb < NB; ++nb) {
        int col = n0 + wn + nb * 16 + l15;
        float bv = bias[col];
        #pragma unroll
        for (int mb = 0; mb < 4; ++mb) {
            #pragma unroll
            for (int i = 0; i < 4; ++i) {
                int row = m0 + wm + mb * 16 + l4 * 4 + i;
                float v = acc[mb][nb][i] + bv;
                if (EPI == 1) v = gelu_erf(v);
                if (EPI == 2) v += ldv(res + (size_t)row * N + col);
                stv(C + (size_t)row * N + col, v);
            }
        }
    }
}

// ---------------------------------------------------------------------------
// Fused film-g2 + LayerNorm + FiLM (r14 version, verbatim).
// ---------------------------------------------------------------------------
template<typename TX>
__launch_bounds__(256)
__global__ void gemmfilm_k(const u16* __restrict__ A, const u16* __restrict__ Wt,
                           const float* __restrict__ b2, const TX* __restrict__ X,
                           const float* __restrict__ stats,
                           const float* __restrict__ lng, const float* __restrict__ lnb,
                           u16* __restrict__ Y)
{
    constexpr int Kc = D2_;
    __shared__ u16 As[2][128 * 64];
    __shared__ u16 Bs[2][128 * 64];

    const int tid  = threadIdx.x;
    const int lane = tid & 63;
    const int w    = tid >> 6;
    const int wm   = (w >> 1) * 64, wn = (w & 1) * 32;
    const int m0   = blockIdx.y * 128, n0 = blockIdx.x * 64;
    const int l15  = lane & 15, l4 = lane >> 4;
    const int rStage = lane >> 3;

    int rrA[4], ccA[4];
    #pragma unroll
    for (int i = 0; i < 4; ++i) {
        rrA[i] = w * 32 + i * 8 + rStage;
        ccA[i] = (lane & 7) ^ (rrA[i] & 7);
    }
    int ccB[4], grB[4];
    #pragma unroll
    for (int i = 0; i < 4; ++i) {
        int lr = w * 16 + (i & 1) * 8 + rStage;
        grB[i]  = (i < 2 ? n0 : D_ + n0) + lr;
        ccB[i]  = (lane & 7) ^ (lr & 7);
    }

    auto stage = [&](int kt, int dd) {
        const int k0 = kt * 64;
        #pragma unroll
        for (int i = 0; i < 4; ++i)
            gload16(A + (size_t)(m0 + rrA[i]) * Kc + k0 + ccA[i] * 8, &As[dd][w * 2048 + i * 512]);
        #pragma unroll
        for (int i = 0; i < 4; ++i)
            gload16(Wt + (size_t)grB[i] * Kc + k0 + ccB[i] * 8,
                    &Bs[dd][((i < 2 ? 0 : 64) + w * 16 + (i & 1) * 8) * 64]);
    };

    f32x4 accG[4][2] = {}, accB2[4][2] = {};
    const int NT = Kc / 64;

    stage(0, 0);

    for (int t = 0; t < NT; ++t) {
        const int d = t & 1;
        barrier_raw();
        if (t + 1 < NT) {
            stage(t + 1, d ^ 1);
            asm volatile("s_waitcnt vmcnt(8)" ::: "memory");
        } else {
            asm volatile("s_waitcnt vmcnt(0)" ::: "memory");
        }
        barrier_raw();
        __builtin_amdgcn_sched_barrier(0);

        #pragma unroll
        for (int kk = 0; kk < 2; ++kk) {
            bf16x8 a[4], bg[2], bb[2];
            #pragma unroll
            for (int mb = 0; mb < 4; ++mb) {
                int r  = wm + mb * 16 + l15;
                int ph = (kk * 4 + l4) ^ (r & 7);
                a[mb] = *reinterpret_cast<const bf16x8*>(&As[d][r * 64 + ph * 8]);
            }
            #pragma unroll
            for (int nb = 0; nb < 2; ++nb) {
                int r  = wn + nb * 16 + l15;
                int ph = (kk * 4 + l4) ^ (r & 7);
                bg[nb] = *reinterpret_cast<const bf16x8*>(&Bs[d][r * 64 + ph * 8]);
                bb[nb] = *reinterpret_cast<const bf16x8*>(&Bs[d][(64 + r) * 64 + ph * 8]);
            }
            #pragma unroll
            for (int mb = 0; mb < 4; ++mb)
                #pragma unroll
                for (int nb = 0; nb < 2; ++nb) {
                    accG[mb][nb]  = __builtin_amdgcn_mfma_f32_16x16x32_bf16(a[mb], bg[nb], accG[mb][nb], 0, 0, 0);
                    accB2[mb][nb] = __builtin_amdgcn_mfma_f32_16x16x32_bf16(a[mb], bb[nb], accB2[mb][nb], 0, 0, 0);
                }
        }
    }

    #pragma unroll
    for (int nb = 0; nb < 2; ++nb) {
        int col = n0 + wn + nb * 16 + l15;
        float gb_ = b2[col], bb_ = b2[D_ + col];
        float lg = lng[col], lb = lnb[col];
        #pragma unroll
        for (int mb = 0; mb < 4; ++mb) {
            #pragma unroll
            for (int i = 0; i < 4; ++i) {
                int row = m0 + wm + mb * 16 + l4 * 4 + i;
                float mean = stats[row * 2], rstd = stats[row * 2 + 1];
                float xv = ldv(X + (size_t)row * D_ + col);
                float gamma = accG[mb][nb][i] + gb_;
                float beta  = accB2[mb][nb][i] + bb_;
                float v = ((xv - mean) * rstd * lg + lb) * (1.0f + gamma) + beta;
                Y[(size_t)row * D_ + col] = f2bf(v);
            }
        }
    }
}

// ---------------------------------------------------------------------------
// Flash attention, counted-vmcnt double-buffered pipeline (T4 applied to attn).
// K/V/Lm double-buffered; Ps wave-private (64x72), q-groups processed
// sequentially per tile; V fragments tr-read once per tile, reused.
// ---------------------------------------------------------------------------
__launch_bounds__(256)
__global__ void attn_k(const u16* __restrict__ Q, const u16* __restrict__ K,
                       const u16* __restrict__ Vv, const u16* __restrict__ Lm,
                       u16* __restrict__ O, int ld)
{
    __shared__ u16 Ks[2][64 * 64];    // 16 KB
    __shared__ u16 Vs[2][64 * 64];    // 16 KB
    __shared__ u16 Lms[2][128 * 64];  // 32 KB
    __shared__ u16 Ps[64 * 72];       // 9 KB, wave-private rows

    const int blk = blockIdx.x;
    const int qt  = blk & 15;
    const int h   = (blk >> 4) & 15;
    const int b   = blk >> 8;
    const int q0  = qt * 128;
    const int tid = threadIdx.x, lane = tid & 63, w = tid >> 6;
    const int l15 = lane & 15, l4 = lane >> 4;
    const size_t bV = (size_t)b * V_;

    // Q frags (B-operand), two 16-row groups, pre-scaled by 1/8 (exact)
    bf16x8 qa[2][2];
    #pragma unroll
    for (int g = 0; g < 2; ++g) {
        const u16* qp = Q + (bV + q0 + w * 32 + g * 16 + l15) * ld + h * 64;
        u16x8 r0 = *reinterpret_cast<const u16x8*>(qp + l4 * 8);
        u16x8 r1 = *reinterpret_cast<const u16x8*>(qp + 32 + l4 * 8);
        u16x8 s0, s1;
        #pragma unroll
        for (int j = 0; j < 8; ++j) {
            s0[j] = f2bf(bf2f(r0[j]) * 0.125f);
            s1[j] = f2bf(bf2f(r1[j]) * 0.125f);
        }
        union { u16x8 u; bf16x8 h; } c0, c1;
        c0.u = s0; c1.u = s1;
        qa[g][0] = c0.h; qa[g][1] = c1.h;
    }

    const int rStage = (lane >> 3);
    const int cSw    = ((lane & 7) ^ rStage) * 8;
    const int vK     = ((lane >> 5) << 2) + ((lane & 7) >> 1);
    const int vDk    = ((lane >> 3) & 3) * 16 + (lane & 1) * 8;
    const u32 vaddr  = (u32)(uintptr_t)&Vs[0][0] + (l4 << 10) + (l15 << 3);

    int lmOff[4];
    #pragma unroll
    for (int kb = 0; kb < 4; ++kb)
        lmOff[kb] = ((((kb << 1) | (l4 >> 1)) ^ (l15 & 7)) << 3);

    auto stage = [&](int kt, int dd) {
        const int k0 = kt * 64;
        #pragma unroll
        for (int i = 0; i < 2; ++i) {
            int r  = i * 32 + w * 8 + rStage;
            int kv = i * 32 + w * 8 + vK;
            gload16(K  + (bV + k0 + r)  * ld + h * 64 + cSw, &Ks[dd][i * 2048 + w * 512]);
            gload16(Vv + (bV + k0 + kv) * ld + h * 64 + vDk, &Vs[dd][i * 2048 + w * 512]);
        }
        #pragma unroll
        for (int i = 0; i < 4; ++i) {
            int r = i * 32 + w * 8 + rStage;
            gload16(Lm + (bV + q0 + r) * (size_t)V_ + k0 + cSw, &Lms[dd][i * 2048 + w * 512]);
        }
    };

    const float LOG2E = 1.44269504088896f;
    float lrp[2] = {0.f, 0.f};
    f32x4 o4[2][4] = {};
    const int NT = V_ / 64;

    stage(0, 0);   // prologue

    for (int kt = 0; kt < NT; ++kt) {
        const int d = kt & 1;
        barrier_raw();                    // all waves done reading buf d^1
        if (kt + 1 < NT) {
            stage(kt + 1, d ^ 1);
            asm volatile("s_waitcnt vmcnt(8)" ::: "memory");   // tile kt resident
        } else {
            asm volatile("s_waitcnt vmcnt(0)" ::: "memory");
        }
        barrier_raw();                    // tile kt visible to all waves
        __builtin_amdgcn_sched_barrier(0);

        // V B-fragments: tr-read ONCE per tile into registers
        union VU { u32x4 u; bf16x8 h; };
        VU vb[2][4];
        #pragma unroll
        for (int c2 = 0; c2 < 2; ++c2) {
            u32 a0 = vaddr + d * 8192 + c2 * 4096;
            u32x2 t0, t1, t2, t3, t4, t5, t6, t7;
            asm volatile("ds_read_b64_tr_b16 %0, %1"            : "=v"(t0) : "v"(a0));
            asm volatile("ds_read_b64_tr_b16 %0, %1 offset:512" : "=v"(t1) : "v"(a0));
            asm volatile("ds_read_b64_tr_b16 %0, %1 offset:128" : "=v"(t2) : "v"(a0));
            asm volatile("ds_read_b64_tr_b16 %0, %1 offset:640" : "=v"(t3) : "v"(a0));
            asm volatile("ds_read_b64_tr_b16 %0, %1 offset:256" : "=v"(t4) : "v"(a0));
            asm volatile("ds_read_b64_tr_b16 %0, %1 offset:768" : "=v"(t5) : "v"(a0));
            asm volatile("ds_read_b64_tr_b16 %0, %1 offset:384" : "=v"(t6) : "v"(a0));
            asm volatile("ds_read_b64_tr_b16 %0, %1 offset:896" : "=v"(t7) : "v"(a0));
            asm volatile("s_waitcnt lgkmcnt(0)" ::: "memory");
            __builtin_amdgcn_sched_barrier(0);
            vb[c2][0].u = (u32x4){t0.x, t0.y, t1.x, t1.y};
            vb[c2][1].u = (u32x4){t2.x, t2.y, t3.x, t3.y};
            vb[c2][2].u = (u32x4){t4.x, t4.y, t5.x, t5.y};
            vb[c2][3].u = (u32x4){t6.x, t6.y, t7.x, t7.y};
        }

        // per group (sequential; Ps rows are wave-private, reused across groups)
        #pragma unroll
        for (int g = 0; g < 2; ++g) {
            f32x4 s[4];
            #pragma unroll
            for (int kb = 0; kb < 4; ++kb) {
                int row = (kb * 16 + l15) * 64;
                bf16x8 k0f = *reinterpret_cast<const bf16x8*>(&Ks[d][row + ((l4 ^ (l15 & 7)) * 8)]);
                bf16x8 k1f = *reinterpret_cast<const bf16x8*>(&Ks[d][row + (((l4 + 4) ^ (l15 & 7)) * 8)]);
                f32x4 z = {};
                z = __builtin_amdgcn_mfma_f32_16x16x32_bf16(k0f, qa[g][0], z, 0, 0, 0);
                z = __builtin_amdgcn_mfma_f32_16x16x32_bf16(k1f, qa[g][1], z, 0, 0, 0);
                s[kb] = z;
            }
            const int lmRow = w * 32 + g * 16 + l15;
            const u16* lmBase = &Lms[d][lmRow * 64 + (l4 & 1) * 4];
            u16* psW = &Ps[(w * 16 + l15) * 72 + l4 * 4];
            #pragma unroll
            for (int kb = 0; kb < 4; ++kb) {
                u16x4 lm4 = *reinterpret_cast<const u16x4*>(lmBase + lmOff[kb]);
                float p0, p1, p2, p3;
                float t0 = fmaf(s[kb][0], LOG2E, bf2f(lm4[0]));
                float t1 = fmaf(s[kb][1], LOG2E, bf2f(lm4[1]));
                float t2 = fmaf(s[kb][2], LOG2E, bf2f(lm4[2]));
                float t3 = fmaf(s[kb][3], LOG2E, bf2f(lm4[3]));
                asm("v_exp_f32 %0, %1" : "=v"(p0) : "v"(t0));
                asm("v_exp_f32 %0, %1" : "=v"(p1) : "v"(t1));
                asm("v_exp_f32 %0, %1" : "=v"(p2) : "v"(t2));
                asm("v_exp_f32 %0, %1" : "=v"(p3) : "v"(t3));
                lrp[g] += (p0 + p1) + (p2 + p3);
                u32 d0, d1;
                asm("v_cvt_pk_bf16_f32 %0, %1, %2" : "=v"(d0) : "v"(p0), "v"(p1));
                asm("v_cvt_pk_bf16_f32 %0, %1, %2" : "=v"(d1) : "v"(p2), "v"(p3));
                u32x2 dd = {d0, d1};
                *reinterpret_cast<u32x2*>(psW + kb * 16) = dd;
            }
            const u16* pr = &Ps[(w * 16 + l15) * 72];
            bf16x8 pa0 = *reinterpret_cast<const bf16x8*>(pr + l4 * 8);
            bf16x8 pa1 = *reinterpret_cast<const bf16x8*>(pr + 32 + l4 * 8);
            #pragma unroll
            for (int nb = 0; nb < 4; ++nb) {
                o4[g][nb] = __builtin_amdgcn_mfma_f32_16x16x32_bf16(pa0, vb[0][nb].h, o4[g][nb], 0, 0, 0);
                o4[g][nb] = __builtin_amdgcn_mfma_f32_16x16x32_bf16(pa1, vb[1][nb].h, o4[g][nb], 0, 0, 0);
            }
        }
    }

    // row-sums: reduce across l4 groups, redistribute, normalize, store
    #pragma unroll
    for (int g = 0; g < 2; ++g) {
        float v = lrp[g];
        v += __shfl_xor(v, 16);
        v += __shfl_xor(v, 32);
        #pragma unroll
        for (int i = 0; i < 4; ++i) {
            float lw = __shfl(v, (lane & 48) | ((l4 << 2) + i));
            float rcp = 1.0f / (lw + 1e-8f);
            int q = q0 + w * 32 + g * 16 + l4 * 4 + i;
            u16* op = O + (bV + q) * D_ + h * 64;
            #pragma unroll
            for (int nb = 0; nb < 4; ++nb)
                op[nb * 16 + l15] = f2bf(o4[g][nb][i] * rcp);
        }
    }
}

// ---------------------------------------------------------------------------
extern "C" void kernel_launch(void* const* d_in, const int* in_sizes, int n_in,
                              void* d_out, int out_size, void* d_ws, size_t ws_size,
                              hipStream_t stream)
{
    (void)in_sizes; (void)n_in; (void)out_size; (void)ws_size;
    const float* x    = (const float*)d_in[0];
    const float* e    = (const float*)d_in[1];
    const float* conn = (const float*)d_in[2];
    const float* ln1g = (const float*)d_in[3];
    const float* ln1b = (const float*)d_in[4];
    const float* f1w1 = (const float*)d_in[5];
    const float* f1b1 = (const float*)d_in[6];
    const float* f1w2 = (const float*)d_in[7];
    const float* f1b2 = (const float*)d_in[8];
    const float* wq   = (const float*)d_in[9];
    const float* bq   = (const float*)d_in[10];
    const float* wk   = (const float*)d_in[11];
    const float* bk   = (const float*)d_in[12];
    const float* wv   = (const float*)d_in[13];
    const float* bv   = (const float*)d_in[14];
    const float* wp   = (const float*)d_in[15];
    const float* bp   = (const float*)d_in[16];
    const float* ln2g = (const float*)d_in[17];
    const float* ln2b = (const float*)d_in[18];
    const float* f2w1 = (const float*)d_in[19];
    const float* f2b1 = (const float*)d_in[20];
    const float* f2w2 = (const float*)d_in[21];
    const float* f2b2 = (const float*)d_in[22];
    const float* ffw1 = (const float*)d_in[23];
    const float* ffb1 = (const float*)d_in[24];
    const float* ffw2 = (const float*)d_in[25];
    const float* ffb2 = (const float*)d_in[26];
    float* out = (float*)d_out;

    // workspace schedule (MB offsets, peak 72 MB == proven-safe, r14 layout)
    char* ws = (char*)d_ws;
    const size_t MB = 1u << 20;
    u16*   Lm    = (u16*)(ws + 0);        // 0-16   log2-mask (live -> attn)
    u16*   e_bf  = (u16*)(ws + 16 * MB);  // 16-18  (live -> film2 gemm1)
    u16*   h     = (u16*)(ws + 18 * MB);  // 18-34
    u16*   wt2   = (u16*)(ws + 34 * MB);  // 34-36  small weight slot
    float* stats = (float*)(ws + 35 * MB);// 35-36  LN row stats (32 KB)
    u16*   wt8   = (u16*)(ws + 36 * MB);  // 36-44  f1w2t / f2w2t
    u16*   y     = (u16*)(ws + 60 * MB);  // 60-68
    u16*   wqkvt = (u16*)(ws + 18 * MB);  // 18-24  (h dead)
    u16*   qkv   = (u16*)(ws + 24 * MB);  // 24-48  fused QKV [4096][3072]
    float* qkvb  = (float*)(ws + 71 * MB);// 71-72
    u16*   o     = (u16*)(ws + 48 * MB);  // 48-56
    u16*   xnew  = (u16*)(ws + 64 * MB);  // 64-72  (y dead by then)
    u16*   h2    = (u16*)(ws + 18 * MB);  // 18-34
    u16*   y2    = (u16*)(ws + 0);        // 0-8    (Lm dead)
    u16*   ffw1t = (u16*)(ws + 8 * MB);   // 8-16
    u16*   t     = (u16*)(ws + 16 * MB);  // 16-48
    u16*   ffw2t = (u16*)(ws + 48 * MB);  // 48-56

    dim3 blk(256), tblk(32, 8);
    #define CONVT(W, WT, K, N) convT_k<<<dim3((N)/32, (K)/32), tblk, 0, stream>>>(W, WT, K, N)

    // fused prologue: lmask + e->bf16 + LN stats(x) + qkv bias concat
    prep_k<<<NL_ + NC_ + NX_ + D3_/256, blk, 0, stream>>>(conn, Lm, e, e_bf, x, stats, bq, bk, bv, qkvb);

    // FiLM 1: g1 GEMM, then fused g2+LN+FiLM
    CONVT(f1w1, wt2, DE_, D2_);
    gemm_k<1, 64, u16, u16><<<dim3(D2_/64, M_/128), blk, 0, stream>>>(e_bf, wt2, f1b1, (const u16*)nullptr, h, M_, D2_, DE_);
    CONVT(f1w2, wt8, D2_, D2_);
    gemmfilm_k<float><<<dim3(D_/64, M_/128), blk, 0, stream>>>(h, wt8, f1b2, x, stats, ln1g, ln1b, y);
    // fused QKV (batched transposes + BN=128 pipelined GEMM)
    convT3_k<<<dim3(D_/32, D_/32, 3), tblk, 0, stream>>>(wq, wk, wv, wqkvt);
    gemm_k<0, 128, u16, u16><<<dim3(D3_/128, M_/128), blk, 0, stream>>>(y, wqkvt, qkvb, (const u16*)nullptr, qkv, M_, D3_, D_);
    // attention (QBLK=128, pipelined)
    attn_k<<<B_*H_*(V_/128), blk, 0, stream>>>(qkv, qkv + 1024, qkv + 2048, Lm, o, D3_);
    // projection + residual (res = x, f32)
    CONVT(wp, wt2, D_, D_);
    gemm_k<2, 64, u16, float><<<dim3(D_/64, M_/128), blk, 0, stream>>>(o, wt2, bp, x, xnew, M_, D_, D_);
    // FiLM 2: g1 GEMM, then fused g2+LN+FiLM (stats from xnew)
    CONVT(f2w1, wt2, DE_, D2_);
    gemm_k<1, 64, u16, u16><<<dim3(D2_/64, M_/128), blk, 0, stream>>>(e_bf, wt2, f2b1, (const u16*)nullptr, h2, M_, D2_, DE_);
    xstats_k<u16><<<M_, blk, 0, stream>>>(xnew, stats);
    CONVT(f2w2, wt8, D2_, D2_);
    gemmfilm_k<u16><<<dim3(D_/64, M_/128), blk, 0, stream>>>(h2, wt8, f2b2, xnew, stats, ln2g, ln2b, y2);
    // FFN + residual -> out (f32)
    CONVT(ffw1, ffw1t, D_, DFF_);
    gemm_k<1, 128, u16, u16><<<dim3(DFF_/128, M_/128), blk, 0, stream>>>(y2, ffw1t, ffb1, (const u16*)nullptr, t, M_, DFF_, D_);
    CONVT(ffw2, ffw2t, DFF_, D_);
    gemm_k<2, 64, float, u16><<<dim3(D_/64, M_/128), blk, 0, stream>>>(t, ffw2t, ffb2, xnew, out, M_, D_, DFF_);
    #undef CONVT
}

// Round 16
// 374.533 us; speedup vs baseline: 1.1072x; 1.0107x over previous
//
#include <hip/hip_runtime.h>
#include <math.h>
#include <stdint.h>

// Problem constants (B,V,D,H,DE,DFF fixed by the reference)
#define B_   2
#define V_   2048
#define D_   1024
#define H_   16
#define DK_  64
#define DE_  256
#define DFF_ 4096
#define M_   (B_*V_)     // 4096 tokens
#define D2_  (2*D_)      // 2048
#define D3_  (3*D_)      // 3072 (fused QKV width)

typedef unsigned short u16;
typedef unsigned int   u32;
typedef __bf16 bf16x8 __attribute__((ext_vector_type(8)));
typedef u16    u16x8  __attribute__((ext_vector_type(8)));
typedef u16    u16x4  __attribute__((ext_vector_type(4)));
typedef float  f32x4  __attribute__((ext_vector_type(4)));
typedef u32    u32x2  __attribute__((ext_vector_type(2)));
typedef u32    u32x4  __attribute__((ext_vector_type(4)));

__device__ __forceinline__ float bf2f(u16 u) {
    union { unsigned int i; float f; } z; z.i = ((unsigned int)u) << 16; return z.f;
}
__device__ __forceinline__ u16 f2bf(float f) {
    union { float f; unsigned int i; } z; z.f = f;
    unsigned int x = z.i;
    return (u16)((x + 0x7fffu + ((x >> 16) & 1u)) >> 16);  // RNE
}
__device__ __forceinline__ float gelu_erf(float v) {
    return 0.5f * v * (1.0f + erff(v * 0.70710678118654752f));
}
__device__ __forceinline__ float ldv(const float* p) { return *p; }
__device__ __forceinline__ float ldv(const u16* p)   { return bf2f(*p); }
__device__ __forceinline__ void  stv(float* p, float v) { *p = v; }
__device__ __forceinline__ void  stv(u16* p,   float v) { *p = f2bf(v); }

// async global->LDS, 16B per lane; LDS dest = wave-uniform base + lane*16
__device__ __forceinline__ void gload16(const u16* g, u16* lds)
{
    __builtin_amdgcn_global_load_lds(
        (const __attribute__((address_space(1))) void*)g,
        (__attribute__((address_space(3))) void*)(uintptr_t)lds,
        16, 0, 0);
}

// raw workgroup barrier WITHOUT the compiler's implicit vmcnt(0) drain.
__device__ __forceinline__ void barrier_raw()
{
    asm volatile("" ::: "memory");
    __builtin_amdgcn_s_barrier();
    asm volatile("" ::: "memory");
}

// ---------------------------------------------------------------------------
// Weight convert+transpose: Wt[N][K] bf16 <- W[K][N] f32 (32x32 LDS tiles)
// ---------------------------------------------------------------------------
__global__ void convT_k(const float* __restrict__ W, u16* __restrict__ Wt, int K, int N)
{
    __shared__ float tile[32][33];
    const int n0 = blockIdx.x * 32, k0 = blockIdx.y * 32;
    const int tx = threadIdx.x, ty = threadIdx.y;   // 32 x 8
    #pragma unroll
    for (int j = 0; j < 4; ++j)
        tile[ty * 4 + j][tx] = W[(size_t)(k0 + ty * 4 + j) * N + n0 + tx];
    __syncthreads();
    #pragma unroll
    for (int j = 0; j < 4; ++j)
        Wt[(size_t)(n0 + ty * 4 + j) * K + k0 + tx] = f2bf(tile[tx][ty * 4 + j]);
}

// batched 1024x1024 transposes (wq,wk,wv) selected by blockIdx.z
__global__ void convT3_k(const float* __restrict__ W0, const float* __restrict__ W1,
                         const float* __restrict__ W2, u16* __restrict__ Wt)
{
    __shared__ float tile[32][33];
    const float* W = blockIdx.z == 0 ? W0 : (blockIdx.z == 1 ? W1 : W2);
    u16* dst = Wt + (size_t)blockIdx.z * D_ * D_;
    const int n0 = blockIdx.x * 32, k0 = blockIdx.y * 32;
    const int tx = threadIdx.x, ty = threadIdx.y;
    #pragma unroll
    for (int j = 0; j < 4; ++j)
        tile[ty * 4 + j][tx] = W[(size_t)(k0 + ty * 4 + j) * D_ + n0 + tx];
    __syncthreads();
    #pragma unroll
    for (int j = 0; j < 4; ++j)
        dst[(size_t)(n0 + ty * 4 + j) * D_ + k0 + tx] = f2bf(tile[tx][ty * 4 + j]);
}

// ---------------------------------------------------------------------------
// prep: fused prologue (lmask + e->bf16 + LN stats of x + qkv bias concat)
// ---------------------------------------------------------------------------
#define NL_ 4096   // lmask blocks:  B*V*V/2048
#define NC_ 1024   // conv blocks:   M*DE/1024
#define NX_ 4096   // xstats blocks: M
__launch_bounds__(256)
__global__ void prep_k(const float* __restrict__ conn, u16* __restrict__ Lm,
                       const float* __restrict__ e, u16* __restrict__ e_bf,
                       const float* __restrict__ X, float* __restrict__ stats,
                       const float* __restrict__ bq, const float* __restrict__ bk,
                       const float* __restrict__ bv, float* __restrict__ qkvb)
{
    __shared__ float rs[4], rq[4];
    const int bid = blockIdx.x;
    const int tid = threadIdx.x;
    if (bid < NL_) {
        const size_t i = ((size_t)bid * 256 + tid) * 8;
        f32x4 a = *reinterpret_cast<const f32x4*>(conn + i);
        f32x4 b = *reinterpret_cast<const f32x4*>(conn + i + 4);
        u16x8 o;
        #pragma unroll
        for (int j = 0; j < 4; ++j) {
            o[j]     = f2bf(__log2f(fminf(fmaxf(a[j], 0.f), 1.f) + 1e-6f));
            o[j + 4] = f2bf(__log2f(fminf(fmaxf(b[j], 0.f), 1.f) + 1e-6f));
        }
        *reinterpret_cast<u16x8*>(Lm + i) = o;
    } else if (bid < NL_ + NC_) {
        const int i = ((bid - NL_) * 256 + tid) * 4;
        f32x4 v = *reinterpret_cast<const f32x4*>(e + i);
        u16x4 o;
        #pragma unroll
        for (int j = 0; j < 4; ++j) o[j] = f2bf(v[j]);
        *reinterpret_cast<u16x4*>(e_bf + i) = o;
    } else if (bid < NL_ + NC_ + NX_) {
        const int row = bid - NL_ - NC_;
        f32x4 v4 = *reinterpret_cast<const f32x4*>(X + (size_t)row * D_ + tid * 4);
        float s = 0.f, sq = 0.f;
        #pragma unroll
        for (int j = 0; j < 4; ++j) { s += v4[j]; sq += v4[j] * v4[j]; }
        #pragma unroll
        for (int off = 32; off; off >>= 1) {
            s  += __shfl_xor(s, off);
            sq += __shfl_xor(sq, off);
        }
        const int w = tid >> 6;
        if ((tid & 63) == 0) { rs[w] = s; rq[w] = sq; }
        __syncthreads();
        if (tid == 0) {
            s  = rs[0] + rs[1] + rs[2] + rs[3];
            sq = rq[0] + rq[1] + rq[2] + rq[3];
            float mean = s * (1.0f / D_);
            float var  = sq * (1.0f / D_) - mean * mean;
            stats[row * 2]     = mean;
            stats[row * 2 + 1] = rsqrtf(fmaxf(var, 0.f) + 1e-5f);
        }
    } else {
        const int i = (bid - NL_ - NC_ - NX_) * 256 + tid;
        qkvb[i] = i < 1024 ? bq[i] : (i < 2048 ? bk[i - 1024] : bv[i - 2048]);
    }
}

// per-row LayerNorm stats (standalone, for xnew)
template<typename TX>
__launch_bounds__(256)
__global__ void xstats_k(const TX* __restrict__ X, float* __restrict__ stats)
{
    const int row = blockIdx.x;
    const int tid = threadIdx.x;
    const TX* xr = X + (size_t)row * D_ + tid * 4;
    float s = 0.f, sq = 0.f;
    if constexpr (sizeof(TX) == 4) {
        f32x4 v4 = *reinterpret_cast<const f32x4*>(xr);
        #pragma unroll
        for (int j = 0; j < 4; ++j) { s += v4[j]; sq += v4[j] * v4[j]; }
    } else {
        u16x4 v4 = *reinterpret_cast<const u16x4*>(xr);
        #pragma unroll
        for (int j = 0; j < 4; ++j) { float v = bf2f(v4[j]); s += v; sq += v * v; }
    }
    #pragma unroll
    for (int off = 32; off; off >>= 1) {
        s  += __shfl_xor(s, off);
        sq += __shfl_xor(sq, off);
    }
    __shared__ float rs[4], rq[4];
    const int w = tid >> 6;
    if ((tid & 63) == 0) { rs[w] = s; rq[w] = sq; }
    __syncthreads();
    if (tid == 0) {
        s  = rs[0] + rs[1] + rs[2] + rs[3];
        sq = rq[0] + rq[1] + rq[2] + rq[3];
        float mean = s * (1.0f / D_);
        float var  = sq * (1.0f / D_) - mean * mean;
        stats[row * 2]     = mean;
        stats[row * 2 + 1] = rsqrtf(fmaxf(var, 0.f) + 1e-5f);
    }
}

// ---------------------------------------------------------------------------
// bf16 MFMA GEMM, counted-vmcnt pipelined: C = epi(A @ Wt^T + bias (+res))
// BM=128, BN in {128,64}; 4 waves; double-buffered LDS.
// EPI: 0 = none, 1 = exact-erf GELU, 2 = add residual
// ---------------------------------------------------------------------------
template<int EPI, int BN, typename TC, typename TRES>
__launch_bounds__(256)
__global__ void gemm_k(const u16* __restrict__ A, const u16* __restrict__ Wt,
                       const float* __restrict__ bias, const TRES* __restrict__ res,
                       TC* __restrict__ C, int M, int N, int K)
{
    constexpr int NB = BN / 32;
    constexpr int IB = BN / 32;
    __shared__ u16 As[2][128 * 64];
    __shared__ u16 Bs[2][BN * 64];

    const int tid  = threadIdx.x;
    const int lane = tid & 63;
    const int w    = tid >> 6;
    const int wm   = (w >> 1) * 64, wn = (w & 1) * (BN / 2);
    const int m0   = blockIdx.y * 128, n0 = blockIdx.x * BN;
    const int l15  = lane & 15, l4 = lane >> 4;
    const int rStage = lane >> 3;

    int rrA[4], ccA[4];
    #pragma unroll
    for (int i = 0; i < 4; ++i) {
        rrA[i] = w * 32 + i * 8 + rStage;
        ccA[i] = (lane & 7) ^ (rrA[i] & 7);
    }
    int rrB[IB], ccB[IB];
    #pragma unroll
    for (int i = 0; i < IB; ++i) {
        rrB[i] = w * (BN / 4) + i * 8 + rStage;
        ccB[i] = (lane & 7) ^ (rrB[i] & 7);
    }

    auto stage = [&](int kt, int dd) {
        const int k0 = kt * 64;
        #pragma unroll
        for (int i = 0; i < 4; ++i)
            gload16(A + (size_t)(m0 + rrA[i]) * K + k0 + ccA[i] * 8, &As[dd][w * 2048 + i * 512]);
        #pragma unroll
        for (int i = 0; i < IB; ++i)
            gload16(Wt + (size_t)(n0 + rrB[i]) * K + k0 + ccB[i] * 8, &Bs[dd][w * (BN * 16) + i * 512]);
    };

    f32x4 acc[4][NB] = {};
    const int NT = K / 64;

    stage(0, 0);

    for (int t = 0; t < NT; ++t) {
        const int d = t & 1;
        barrier_raw();
        if (t + 1 < NT) {
            stage(t + 1, d ^ 1);
            if constexpr (BN == 128) asm volatile("s_waitcnt vmcnt(8)" ::: "memory");
            else                     asm volatile("s_waitcnt vmcnt(6)" ::: "memory");
        } else {
            asm volatile("s_waitcnt vmcnt(0)" ::: "memory");
        }
        barrier_raw();
        __builtin_amdgcn_sched_barrier(0);

        #pragma unroll
        for (int kk = 0; kk < 2; ++kk) {
            bf16x8 a[4], b[NB];
            #pragma unroll
            for (int mb = 0; mb < 4; ++mb) {
                int r  = wm + mb * 16 + l15;
                int ph = (kk * 4 + l4) ^ (r & 7);
                a[mb] = *reinterpret_cast<const bf16x8*>(&As[d][r * 64 + ph * 8]);
            }
            #pragma unroll
            for (int nb = 0; nb < NB; ++nb) {
                int r  = wn + nb * 16 + l15;
                int ph = (kk * 4 + l4) ^ (r & 7);
                b[nb] = *reinterpret_cast<const bf16x8*>(&Bs[d][r * 64 + ph * 8]);
            }
            #pragma unroll
            for (int mb = 0; mb < 4; ++mb)
                #pragma unroll
                for (int nb = 0; nb < NB; ++nb)
                    acc[mb][nb] = __builtin_amdgcn_mfma_f32_16x16x32_bf16(a[mb], b[nb], acc[mb][nb], 0, 0, 0);
        }
    }

    #pragma unroll
    for (int nb = 0; nb < NB; ++nb) {
        int col = n0 + wn + nb * 16 + l15;
        float bv = bias[col];
        #pragma unroll
        for (int mb = 0; mb < 4; ++mb) {
            #pragma unroll
            for (int i = 0; i < 4; ++i) {
                int row = m0 + wm + mb * 16 + l4 * 4 + i;
                float v = acc[mb][nb][i] + bv;
                if (EPI == 1) v = gelu_erf(v);
                if (EPI == 2) v += ldv(res + (size_t)row * N + col);
                stv(C + (size_t)row * N + col, v);
            }
        }
    }
}

// ---------------------------------------------------------------------------
// Fused film-g2 + LayerNorm + FiLM (r14 version, verbatim).
// ---------------------------------------------------------------------------
template<typename TX>
__launch_bounds__(256)
__global__ void gemmfilm_k(const u16* __restrict__ A, const u16* __restrict__ Wt,
                           const float* __restrict__ b2, const TX* __restrict__ X,
                           const float* __restrict__ stats,
                           const float* __restrict__ lng, const float* __restrict__ lnb,
                           u16* __restrict__ Y)
{
    constexpr int Kc = D2_;
    __shared__ u16 As[2][128 * 64];
    __shared__ u16 Bs[2][128 * 64];

    const int tid  = threadIdx.x;
    const int lane = tid & 63;
    const int w    = tid >> 6;
    const int wm   = (w >> 1) * 64, wn = (w & 1) * 32;
    const int m0   = blockIdx.y * 128, n0 = blockIdx.x * 64;
    const int l15  = lane & 15, l4 = lane >> 4;
    const int rStage = lane >> 3;

    int rrA[4], ccA[4];
    #pragma unroll
    for (int i = 0; i < 4; ++i) {
        rrA[i] = w * 32 + i * 8 + rStage;
        ccA[i] = (lane & 7) ^ (rrA[i] & 7);
    }
    int ccB[4], grB[4];
    #pragma unroll
    for (int i = 0; i < 4; ++i) {
        int lr = w * 16 + (i & 1) * 8 + rStage;
        grB[i]  = (i < 2 ? n0 : D_ + n0) + lr;
        ccB[i]  = (lane & 7) ^ (lr & 7);
    }

    auto stage = [&](int kt, int dd) {
        const int k0 = kt * 64;
        #pragma unroll
        for (int i = 0; i < 4; ++i)
            gload16(A + (size_t)(m0 + rrA[i]) * Kc + k0 + ccA[i] * 8, &As[dd][w * 2048 + i * 512]);
        #pragma unroll
        for (int i = 0; i < 4; ++i)
            gload16(Wt + (size_t)grB[i] * Kc + k0 + ccB[i] * 8,
                    &Bs[dd][((i < 2 ? 0 : 64) + w * 16 + (i & 1) * 8) * 64]);
    };

    f32x4 accG[4][2] = {}, accB2[4][2] = {};
    const int NT = Kc / 64;

    stage(0, 0);

    for (int t = 0; t < NT; ++t) {
        const int d = t & 1;
        barrier_raw();
        if (t + 1 < NT) {
            stage(t + 1, d ^ 1);
            asm volatile("s_waitcnt vmcnt(8)" ::: "memory");
        } else {
            asm volatile("s_waitcnt vmcnt(0)" ::: "memory");
        }
        barrier_raw();
        __builtin_amdgcn_sched_barrier(0);

        #pragma unroll
        for (int kk = 0; kk < 2; ++kk) {
            bf16x8 a[4], bg[2], bb[2];
            #pragma unroll
            for (int mb = 0; mb < 4; ++mb) {
                int r  = wm + mb * 16 + l15;
                int ph = (kk * 4 + l4) ^ (r & 7);
                a[mb] = *reinterpret_cast<const bf16x8*>(&As[d][r * 64 + ph * 8]);
            }
            #pragma unroll
            for (int nb = 0; nb < 2; ++nb) {
                int r  = wn + nb * 16 + l15;
                int ph = (kk * 4 + l4) ^ (r & 7);
                bg[nb] = *reinterpret_cast<const bf16x8*>(&Bs[d][r * 64 + ph * 8]);
                bb[nb] = *reinterpret_cast<const bf16x8*>(&Bs[d][(64 + r) * 64 + ph * 8]);
            }
            #pragma unroll
            for (int mb = 0; mb < 4; ++mb)
                #pragma unroll
                for (int nb = 0; nb < 2; ++nb) {
                    accG[mb][nb]  = __builtin_amdgcn_mfma_f32_16x16x32_bf16(a[mb], bg[nb], accG[mb][nb], 0, 0, 0);
                    accB2[mb][nb] = __builtin_amdgcn_mfma_f32_16x16x32_bf16(a[mb], bb[nb], accB2[mb][nb], 0, 0, 0);
                }
        }
    }

    #pragma unroll
    for (int nb = 0; nb < 2; ++nb) {
        int col = n0 + wn + nb * 16 + l15;
        float gb_ = b2[col], bb_ = b2[D_ + col];
        float lg = lng[col], lb = lnb[col];
        #pragma unroll
        for (int mb = 0; mb < 4; ++mb) {
            #pragma unroll
            for (int i = 0; i < 4; ++i) {
                int row = m0 + wm + mb * 16 + l4 * 4 + i;
                float mean = stats[row * 2], rstd = stats[row * 2 + 1];
                float xv = ldv(X + (size_t)row * D_ + col);
                float gamma = accG[mb][nb][i] + gb_;
                float beta  = accB2[mb][nb][i] + bb_;
                float v = ((xv - mean) * rstd * lg + lb) * (1.0f + gamma) + beta;
                Y[(size_t)row * D_ + col] = f2bf(v);
            }
        }
    }
}

// ---------------------------------------------------------------------------
// Flash attention (r12/r14 proven version, verbatim: single-buffered tiles,
// interleaved q-groups, Ps 128x72).
// ---------------------------------------------------------------------------
__launch_bounds__(256)
__global__ void attn_k(const u16* __restrict__ Q, const u16* __restrict__ K,
                       const u16* __restrict__ Vv, const u16* __restrict__ Lm,
                       u16* __restrict__ O, int ld)
{
    __shared__ u16 Ks[64 * 64];
    __shared__ u16 Vs[64 * 64];
    __shared__ u16 Lms[128 * 64];
    __shared__ u16 Ps[128 * 72];

    const int blk = blockIdx.x;
    const int qt  = blk & 15;
    const int h   = (blk >> 4) & 15;
    const int b   = blk >> 8;
    const int q0  = qt * 128;
    const int tid = threadIdx.x, lane = tid & 63, w = tid >> 6;
    const int l15 = lane & 15, l4 = lane >> 4;
    const size_t bV = (size_t)b * V_;

    bf16x8 qa[2][2];
    #pragma unroll
    for (int g = 0; g < 2; ++g) {
        const u16* qp = Q + (bV + q0 + w * 32 + g * 16 + l15) * ld + h * 64;
        u16x8 r0 = *reinterpret_cast<const u16x8*>(qp + l4 * 8);
        u16x8 r1 = *reinterpret_cast<const u16x8*>(qp + 32 + l4 * 8);
        u16x8 s0, s1;
        #pragma unroll
        for (int j = 0; j < 8; ++j) {
            s0[j] = f2bf(bf2f(r0[j]) * 0.125f);
            s1[j] = f2bf(bf2f(r1[j]) * 0.125f);
        }
        union { u16x8 u; bf16x8 h; } c0, c1;
        c0.u = s0; c1.u = s1;
        qa[g][0] = c0.h; qa[g][1] = c1.h;
    }

    const int rStage = (lane >> 3);
    const int cSw    = ((lane & 7) ^ rStage) * 8;
    const int vK     = ((lane >> 5) << 2) + ((lane & 7) >> 1);
    const int vDk    = ((lane >> 3) & 3) * 16 + (lane & 1) * 8;
    const u32 vaddr  = (u32)(uintptr_t)&Vs[0] + (l4 << 10) + (l15 << 3);

    int lmOff[4];
    #pragma unroll
    for (int kb = 0; kb < 4; ++kb)
        lmOff[kb] = ((((kb << 1) | (l4 >> 1)) ^ (l15 & 7)) << 3);

    const float LOG2E = 1.44269504088896f;
    float lrp[2] = {0.f, 0.f};
    f32x4 o4[2][4] = {};

    for (int kt = 0; kt < V_ / 64; ++kt) {
        const int k0 = kt * 64;
        if (kt) __syncthreads();
        #pragma unroll
        for (int i = 0; i < 2; ++i) {
            int r  = i * 32 + w * 8 + rStage;
            int kv = i * 32 + w * 8 + vK;
            gload16(K  + (bV + k0 + r)  * ld + h * 64 + cSw, &Ks[i * 2048 + w * 512]);
            gload16(Vv + (bV + k0 + kv) * ld + h * 64 + vDk, &Vs[i * 2048 + w * 512]);
        }
        #pragma unroll
        for (int i = 0; i < 4; ++i) {
            int r = i * 32 + w * 8 + rStage;
            gload16(Lm + (bV + q0 + r) * (size_t)V_ + k0 + cSw, &Lms[i * 2048 + w * 512]);
        }
        __syncthreads();

        #pragma unroll
        for (int g = 0; g < 2; ++g) {
            f32x4 s[4];
            #pragma unroll
            for (int kb = 0; kb < 4; ++kb) {
                int row = (kb * 16 + l15) * 64;
                bf16x8 k0f = *reinterpret_cast<const bf16x8*>(&Ks[row + ((l4 ^ (l15 & 7)) * 8)]);
                bf16x8 k1f = *reinterpret_cast<const bf16x8*>(&Ks[row + (((l4 + 4) ^ (l15 & 7)) * 8)]);
                f32x4 z = {};
                z = __builtin_amdgcn_mfma_f32_16x16x32_bf16(k0f, qa[g][0], z, 0, 0, 0);
                z = __builtin_amdgcn_mfma_f32_16x16x32_bf16(k1f, qa[g][1], z, 0, 0, 0);
                s[kb] = z;
            }
            const int lmRow = w * 32 + g * 16 + l15;
            const u16* lmBase = &Lms[lmRow * 64 + (l4 & 1) * 4];
            u16* psW = &Ps[lmRow * 72 + l4 * 4];
            #pragma unroll
            for (int kb = 0; kb < 4; ++kb) {
                u16x4 lm4 = *reinterpret_cast<const u16x4*>(lmBase + lmOff[kb]);
                float p0, p1, p2, p3;
                float t0 = fmaf(s[kb][0], LOG2E, bf2f(lm4[0]));
                float t1 = fmaf(s[kb][1], LOG2E, bf2f(lm4[1]));
                float t2 = fmaf(s[kb][2], LOG2E, bf2f(lm4[2]));
                float t3 = fmaf(s[kb][3], LOG2E, bf2f(lm4[3]));
                asm("v_exp_f32 %0, %1" : "=v"(p0) : "v"(t0));
                asm("v_exp_f32 %0, %1" : "=v"(p1) : "v"(t1));
                asm("v_exp_f32 %0, %1" : "=v"(p2) : "v"(t2));
                asm("v_exp_f32 %0, %1" : "=v"(p3) : "v"(t3));
                lrp[g] += (p0 + p1) + (p2 + p3);
                u32 d0, d1;
                asm("v_cvt_pk_bf16_f32 %0, %1, %2" : "=v"(d0) : "v"(p0), "v"(p1));
                asm("v_cvt_pk_bf16_f32 %0, %1, %2" : "=v"(d1) : "v"(p2), "v"(p3));
                u32x2 dd = {d0, d1};
                *reinterpret_cast<u32x2*>(psW + kb * 16) = dd;
            }
        }

        union VU { u32x4 u; bf16x8 h; };
        VU vb[2][4];
        #pragma unroll
        for (int c2 = 0; c2 < 2; ++c2) {
            u32 a0 = vaddr + c2 * 4096;
            u32x2 t0, t1, t2, t3, t4, t5, t6, t7;
            asm volatile("ds_read_b64_tr_b16 %0, %1"            : "=v"(t0) : "v"(a0));
            asm volatile("ds_read_b64_tr_b16 %0, %1 offset:512" : "=v"(t1) : "v"(a0));
            asm volatile("ds_read_b64_tr_b16 %0, %1 offset:128" : "=v"(t2) : "v"(a0));
            asm volatile("ds_read_b64_tr_b16 %0, %1 offset:640" : "=v"(t3) : "v"(a0));
            asm volatile("ds_read_b64_tr_b16 %0, %1 offset:256" : "=v"(t4) : "v"(a0));
            asm volatile("ds_read_b64_tr_b16 %0, %1 offset:768" : "=v"(t5) : "v"(a0));
            asm volatile("ds_read_b64_tr_b16 %0, %1 offset:384" : "=v"(t6) : "v"(a0));
            asm volatile("ds_read_b64_tr_b16 %0, %1 offset:896" : "=v"(t7) : "v"(a0));
            asm volatile("s_waitcnt lgkmcnt(0)" ::: "memory");
            __builtin_amdgcn_sched_barrier(0);
            vb[c2][0].u = (u32x4){t0.x, t0.y, t1.x, t1.y};
            vb[c2][1].u = (u32x4){t2.x, t2.y, t3.x, t3.y};
            vb[c2][2].u = (u32x4){t4.x, t4.y, t5.x, t5.y};
            vb[c2][3].u = (u32x4){t6.x, t6.y, t7.x, t7.y};
        }
        #pragma unroll
        for (int g = 0; g < 2; ++g) {
            const u16* pr = &Ps[(w * 32 + g * 16 + l15) * 72];
            bf16x8 pa0 = *reinterpret_cast<const bf16x8*>(pr + l4 * 8);
            bf16x8 pa1 = *reinterpret_cast<const bf16x8*>(pr + 32 + l4 * 8);
            #pragma unroll
            for (int nb = 0; nb < 4; ++nb) {
                o4[g][nb] = __builtin_amdgcn_mfma_f32_16x16x32_bf16(pa0, vb[0][nb].h, o4[g][nb], 0, 0, 0);
                o4[g][nb] = __builtin_amdgcn_mfma_f32_16x16x32_bf16(pa1, vb[1][nb].h, o4[g][nb], 0, 0, 0);
            }
        }
    }

    #pragma unroll
    for (int g = 0; g < 2; ++g) {
        float v = lrp[g];
        v += __shfl_xor(v, 16);
        v += __shfl_xor(v, 32);
        #pragma unroll
        for (int i = 0; i < 4; ++i) {
            float lw = __shfl(v, (lane & 48) | ((l4 << 2) + i));
            float rcp = 1.0f / (lw + 1e-8f);
            int q = q0 + w * 32 + g * 16 + l4 * 4 + i;
            u16* op = O + (bV + q) * D_ + h * 64;
            #pragma unroll
            for (int nb = 0; nb < 4; ++nb)
                op[nb * 16 + l15] = f2bf(o4[g][nb][i] * rcp);
        }
    }
}

// ---------------------------------------------------------------------------
extern "C" void kernel_launch(void* const* d_in, const int* in_sizes, int n_in,
                              void* d_out, int out_size, void* d_ws, size_t ws_size,
                              hipStream_t stream)
{
    (void)in_sizes; (void)n_in; (void)out_size; (void)ws_size;
    const float* x    = (const float*)d_in[0];
    const float* e    = (const float*)d_in[1];
    const float* conn = (const float*)d_in[2];
    const float* ln1g = (const float*)d_in[3];
    const float* ln1b = (const float*)d_in[4];
    const float* f1w1 = (const float*)d_in[5];
    const float* f1b1 = (const float*)d_in[6];
    const float* f1w2 = (const float*)d_in[7];
    const float* f1b2 = (const float*)d_in[8];
    const float* wq   = (const float*)d_in[9];
    const float* bq   = (const float*)d_in[10];
    const float* wk   = (const float*)d_in[11];
    const float* bk   = (const float*)d_in[12];
    const float* wv   = (const float*)d_in[13];
    const float* bv   = (const float*)d_in[14];
    const float* wp   = (const float*)d_in[15];
    const float* bp   = (const float*)d_in[16];
    const float* ln2g = (const float*)d_in[17];
    const float* ln2b = (const float*)d_in[18];
    const float* f2w1 = (const float*)d_in[19];
    const float* f2b1 = (const float*)d_in[20];
    const float* f2w2 = (const float*)d_in[21];
    const float* f2b2 = (const float*)d_in[22];
    const float* ffw1 = (const float*)d_in[23];
    const float* ffb1 = (const float*)d_in[24];
    const float* ffw2 = (const float*)d_in[25];
    const float* ffb2 = (const float*)d_in[26];
    float* out = (float*)d_out;

    // workspace schedule (MB offsets, peak 72 MB == proven-safe, r14 layout)
    char* ws = (char*)d_ws;
    const size_t MB = 1u << 20;
    u16*   Lm    = (u16*)(ws + 0);        // 0-16   log2-mask (live -> attn)
    u16*   e_bf  = (u16*)(ws + 16 * MB);  // 16-18  (live -> film2 gemm1)
    u16*   h     = (u16*)(ws + 18 * MB);  // 18-34
    u16*   wt2   = (u16*)(ws + 34 * MB);  // 34-36  small weight slot
    float* stats = (float*)(ws + 35 * MB);// 35-36  LN row stats (32 KB)
    u16*   wt8   = (u16*)(ws + 36 * MB);  // 36-44  f1w2t / f2w2t
    u16*   y     = (u16*)(ws + 60 * MB);  // 60-68
    u16*   wqkvt = (u16*)(ws + 18 * MB);  // 18-24  (h dead)
    u16*   qkv   = (u16*)(ws + 24 * MB);  // 24-48  fused QKV [4096][3072]
    float* qkvb  = (float*)(ws + 71 * MB);// 71-72
    u16*   o     = (u16*)(ws + 48 * MB);  // 48-56
    u16*   xnew  = (u16*)(ws + 64 * MB);  // 64-72  (y dead by then)
    u16*   h2    = (u16*)(ws + 18 * MB);  // 18-34
    u16*   y2    = (u16*)(ws + 0);        // 0-8    (Lm dead)
    u16*   ffw1t = (u16*)(ws + 8 * MB);   // 8-16
    u16*   t     = (u16*)(ws + 16 * MB);  // 16-48
    u16*   ffw2t = (u16*)(ws + 48 * MB);  // 48-56

    dim3 blk(256), tblk(32, 8);
    #define CONVT(W, WT, K, N) convT_k<<<dim3((N)/32, (K)/32), tblk, 0, stream>>>(W, WT, K, N)

    // fused prologue: lmask + e->bf16 + LN stats(x) + qkv bias concat
    prep_k<<<NL_ + NC_ + NX_ + D3_/256, blk, 0, stream>>>(conn, Lm, e, e_bf, x, stats, bq, bk, bv, qkvb);

    // FiLM 1: g1 GEMM, then fused g2+LN+FiLM
    CONVT(f1w1, wt2, DE_, D2_);
    gemm_k<1, 64, u16, u16><<<dim3(D2_/64, M_/128), blk, 0, stream>>>(e_bf, wt2, f1b1, (const u16*)nullptr, h, M_, D2_, DE_);
    CONVT(f1w2, wt8, D2_, D2_);
    gemmfilm_k<float><<<dim3(D_/64, M_/128), blk, 0, stream>>>(h, wt8, f1b2, x, stats, ln1g, ln1b, y);
    // fused QKV (batched transposes + BN=128 pipelined GEMM)
    convT3_k<<<dim3(D_/32, D_/32, 3), tblk, 0, stream>>>(wq, wk, wv, wqkvt);
    gemm_k<0, 128, u16, u16><<<dim3(D3_/128, M_/128), blk, 0, stream>>>(y, wqkvt, qkvb, (const u16*)nullptr, qkv, M_, D3_, D_);
    // attention (QBLK=128)
    attn_k<<<B_*H_*(V_/128), blk, 0, stream>>>(qkv, qkv + 1024, qkv + 2048, Lm, o, D3_);
    // projection + residual (res = x, f32)
    CONVT(wp, wt2, D_, D_);
    gemm_k<2, 64, u16, float><<<dim3(D_/64, M_/128), blk, 0, stream>>>(o, wt2, bp, x, xnew, M_, D_, D_);
    // FiLM 2: g1 GEMM, then fused g2+LN+FiLM (stats from xnew)
    CONVT(f2w1, wt2, DE_, D2_);
    gemm_k<1, 64, u16, u16><<<dim3(D2_/64, M_/128), blk, 0, stream>>>(e_bf, wt2, f2b1, (const u16*)nullptr, h2, M_, D2_, DE_);
    xstats_k<u16><<<M_, blk, 0, stream>>>(xnew, stats);
    CONVT(f2w2, wt8, D2_, D2_);
    gemmfilm_k<u16><<<dim3(D_/64, M_/128), blk, 0, stream>>>(h2, wt8, f2b2, xnew, stats, ln2g, ln2b, y2);
    // FFN + residual -> out (f32)
    CONVT(ffw1, ffw1t, D_, DFF_);
    gemm_k<1, 128, u16, u16><<<dim3(DFF_/128, M_/128), blk, 0, stream>>>(y2, ffw1t, ffb1, (const u16*)nullptr, t, M_, DFF_, D_);
    CONVT(ffw2, ffw2t, DFF_, D_);
    gemm_k<2, 64, float, u16><<<dim3(D_/64, M_/128), blk, 0, stream>>>(t, ffw2t, ffb2, xnew, out, M_, D_, DFF_);
    #undef CONVT
}

// Round 17
// 373.011 us; speedup vs baseline: 1.1118x; 1.0041x over previous
//
#include <hip/hip_runtime.h>
#include <math.h>
#include <stdint.h>

// Problem constants (B,V,D,H,DE,DFF fixed by the reference)
#define B_   2
#define V_   2048
#define D_   1024
#define H_   16
#define DK_  64
#define DE_  256
#define DFF_ 4096
#define M_   (B_*V_)     // 4096 tokens
#define D2_  (2*D_)      // 2048
#define D3_  (3*D_)      // 3072 (fused QKV width)

typedef unsigned short u16;
typedef unsigned int   u32;
typedef __bf16 bf16x8 __attribute__((ext_vector_type(8)));
typedef u16    u16x8  __attribute__((ext_vector_type(8)));
typedef u16    u16x4  __attribute__((ext_vector_type(4)));
typedef float  f32x4  __attribute__((ext_vector_type(4)));
typedef u32    u32x2  __attribute__((ext_vector_type(2)));
typedef u32    u32x4  __attribute__((ext_vector_type(4)));

__device__ __forceinline__ float bf2f(u16 u) {
    union { unsigned int i; float f; } z; z.i = ((unsigned int)u) << 16; return z.f;
}
__device__ __forceinline__ u16 f2bf(float f) {
    union { float f; unsigned int i; } z; z.f = f;
    unsigned int x = z.i;
    return (u16)((x + 0x7fffu + ((x >> 16) & 1u)) >> 16);  // RNE
}
__device__ __forceinline__ float gelu_erf(float v) {
    return 0.5f * v * (1.0f + erff(v * 0.70710678118654752f));
}
__device__ __forceinline__ float ldv(const float* p) { return *p; }
__device__ __forceinline__ float ldv(const u16* p)   { return bf2f(*p); }
__device__ __forceinline__ void  stv(float* p, float v) { *p = v; }
__device__ __forceinline__ void  stv(u16* p,   float v) { *p = f2bf(v); }

// async global->LDS, 16B per lane; LDS dest = wave-uniform base + lane*16
__device__ __forceinline__ void gload16(const u16* g, u16* lds)
{
    __builtin_amdgcn_global_load_lds(
        (const __attribute__((address_space(1))) void*)g,
        (__attribute__((address_space(3))) void*)(uintptr_t)lds,
        16, 0, 0);
}

// raw workgroup barrier WITHOUT the compiler's implicit vmcnt(0) drain.
__device__ __forceinline__ void barrier_raw()
{
    asm volatile("" ::: "memory");
    __builtin_amdgcn_s_barrier();
    asm volatile("" ::: "memory");
}

// XCD-aware bijective block swizzle (requires nwg % 8 == 0): hardware assigns
// raw ids round-robin to XCDs; this gives each XCD a CONTIGUOUS logical range.
__device__ __forceinline__ int xcd_swz(int lin, int nwg)
{
    return (lin & 7) * (nwg >> 3) + (lin >> 3);
}

// ---------------------------------------------------------------------------
// Weight convert+transpose: Wt[N][K] bf16 <- W[K][N] f32 (32x32 LDS tiles)
// ---------------------------------------------------------------------------
__global__ void convT_k(const float* __restrict__ W, u16* __restrict__ Wt, int K, int N)
{
    __shared__ float tile[32][33];
    const int n0 = blockIdx.x * 32, k0 = blockIdx.y * 32;
    const int tx = threadIdx.x, ty = threadIdx.y;   // 32 x 8
    #pragma unroll
    for (int j = 0; j < 4; ++j)
        tile[ty * 4 + j][tx] = W[(size_t)(k0 + ty * 4 + j) * N + n0 + tx];
    __syncthreads();
    #pragma unroll
    for (int j = 0; j < 4; ++j)
        Wt[(size_t)(n0 + ty * 4 + j) * K + k0 + tx] = f2bf(tile[tx][ty * 4 + j]);
}

// batched 1024x1024 transposes (wq,wk,wv) selected by blockIdx.z
__global__ void convT3_k(const float* __restrict__ W0, const float* __restrict__ W1,
                         const float* __restrict__ W2, u16* __restrict__ Wt)
{
    __shared__ float tile[32][33];
    const float* W = blockIdx.z == 0 ? W0 : (blockIdx.z == 1 ? W1 : W2);
    u16* dst = Wt + (size_t)blockIdx.z * D_ * D_;
    const int n0 = blockIdx.x * 32, k0 = blockIdx.y * 32;
    const int tx = threadIdx.x, ty = threadIdx.y;
    #pragma unroll
    for (int j = 0; j < 4; ++j)
        tile[ty * 4 + j][tx] = W[(size_t)(k0 + ty * 4 + j) * D_ + n0 + tx];
    __syncthreads();
    #pragma unroll
    for (int j = 0; j < 4; ++j)
        dst[(size_t)(n0 + ty * 4 + j) * D_ + k0 + tx] = f2bf(tile[tx][ty * 4 + j]);
}

// ---------------------------------------------------------------------------
// prep: fused prologue (lmask + e->bf16 + LN stats of x + qkv bias concat)
// ---------------------------------------------------------------------------
#define NL_ 4096   // lmask blocks:  B*V*V/2048
#define NC_ 1024   // conv blocks:   M*DE/1024
#define NX_ 4096   // xstats blocks: M
__launch_bounds__(256)
__global__ void prep_k(const float* __restrict__ conn, u16* __restrict__ Lm,
                       const float* __restrict__ e, u16* __restrict__ e_bf,
                       const float* __restrict__ X, float* __restrict__ stats,
                       const float* __restrict__ bq, const float* __restrict__ bk,
                       const float* __restrict__ bv, float* __restrict__ qkvb)
{
    __shared__ float rs[4], rq[4];
    const int bid = blockIdx.x;
    const int tid = threadIdx.x;
    if (bid < NL_) {
        const size_t i = ((size_t)bid * 256 + tid) * 8;
        f32x4 a = *reinterpret_cast<const f32x4*>(conn + i);
        f32x4 b = *reinterpret_cast<const f32x4*>(conn + i + 4);
        u16x8 o;
        #pragma unroll
        for (int j = 0; j < 4; ++j) {
            o[j]     = f2bf(__log2f(fminf(fmaxf(a[j], 0.f), 1.f) + 1e-6f));
            o[j + 4] = f2bf(__log2f(fminf(fmaxf(b[j], 0.f), 1.f) + 1e-6f));
        }
        *reinterpret_cast<u16x8*>(Lm + i) = o;
    } else if (bid < NL_ + NC_) {
        const int i = ((bid - NL_) * 256 + tid) * 4;
        f32x4 v = *reinterpret_cast<const f32x4*>(e + i);
        u16x4 o;
        #pragma unroll
        for (int j = 0; j < 4; ++j) o[j] = f2bf(v[j]);
        *reinterpret_cast<u16x4*>(e_bf + i) = o;
    } else if (bid < NL_ + NC_ + NX_) {
        const int row = bid - NL_ - NC_;
        f32x4 v4 = *reinterpret_cast<const f32x4*>(X + (size_t)row * D_ + tid * 4);
        float s = 0.f, sq = 0.f;
        #pragma unroll
        for (int j = 0; j < 4; ++j) { s += v4[j]; sq += v4[j] * v4[j]; }
        #pragma unroll
        for (int off = 32; off; off >>= 1) {
            s  += __shfl_xor(s, off);
            sq += __shfl_xor(sq, off);
        }
        const int w = tid >> 6;
        if ((tid & 63) == 0) { rs[w] = s; rq[w] = sq; }
        __syncthreads();
        if (tid == 0) {
            s  = rs[0] + rs[1] + rs[2] + rs[3];
            sq = rq[0] + rq[1] + rq[2] + rq[3];
            float mean = s * (1.0f / D_);
            float var  = sq * (1.0f / D_) - mean * mean;
            stats[row * 2]     = mean;
            stats[row * 2 + 1] = rsqrtf(fmaxf(var, 0.f) + 1e-5f);
        }
    } else {
        const int i = (bid - NL_ - NC_ - NX_) * 256 + tid;
        qkvb[i] = i < 1024 ? bq[i] : (i < 2048 ? bk[i - 1024] : bv[i - 2048]);
    }
}

// per-row LayerNorm stats (standalone, for xnew)
template<typename TX>
__launch_bounds__(256)
__global__ void xstats_k(const TX* __restrict__ X, float* __restrict__ stats)
{
    const int row = blockIdx.x;
    const int tid = threadIdx.x;
    const TX* xr = X + (size_t)row * D_ + tid * 4;
    float s = 0.f, sq = 0.f;
    if constexpr (sizeof(TX) == 4) {
        f32x4 v4 = *reinterpret_cast<const f32x4*>(xr);
        #pragma unroll
        for (int j = 0; j < 4; ++j) { s += v4[j]; sq += v4[j] * v4[j]; }
    } else {
        u16x4 v4 = *reinterpret_cast<const u16x4*>(xr);
        #pragma unroll
        for (int j = 0; j < 4; ++j) { float v = bf2f(v4[j]); s += v; sq += v * v; }
    }
    #pragma unroll
    for (int off = 32; off; off >>= 1) {
        s  += __shfl_xor(s, off);
        sq += __shfl_xor(sq, off);
    }
    __shared__ float rs[4], rq[4];
    const int w = tid >> 6;
    if ((tid & 63) == 0) { rs[w] = s; rq[w] = sq; }
    __syncthreads();
    if (tid == 0) {
        s  = rs[0] + rs[1] + rs[2] + rs[3];
        sq = rq[0] + rq[1] + rq[2] + rq[3];
        float mean = s * (1.0f / D_);
        float var  = sq * (1.0f / D_) - mean * mean;
        stats[row * 2]     = mean;
        stats[row * 2 + 1] = rsqrtf(fmaxf(var, 0.f) + 1e-5f);
    }
}

// ---------------------------------------------------------------------------
// bf16 MFMA GEMM, counted-vmcnt pipelined, XCD-swizzled grid.
// BM=128, BN in {128,64}; 4 waves; double-buffered LDS.
// EPI: 0 = none, 1 = exact-erf GELU, 2 = add residual
// ---------------------------------------------------------------------------
template<int EPI, int BN, typename TC, typename TRES>
__launch_bounds__(256)
__global__ void gemm_k(const u16* __restrict__ A, const u16* __restrict__ Wt,
                       const float* __restrict__ bias, const TRES* __restrict__ res,
                       TC* __restrict__ C, int M, int N, int K)
{
    constexpr int NB = BN / 32;
    constexpr int IB = BN / 32;
    __shared__ u16 As[2][128 * 64];
    __shared__ u16 Bs[2][BN * 64];

    const int tid  = threadIdx.x;
    const int lane = tid & 63;
    const int w    = tid >> 6;
    const int wm   = (w >> 1) * 64, wn = (w & 1) * (BN / 2);
    const int nwg  = gridDim.x * gridDim.y;
    const int lin  = xcd_swz(blockIdx.y * gridDim.x + blockIdx.x, nwg);
    const int m0   = (lin / gridDim.x) * 128, n0 = (lin % gridDim.x) * BN;
    const int l15  = lane & 15, l4 = lane >> 4;
    const int rStage = lane >> 3;

    int rrA[4], ccA[4];
    #pragma unroll
    for (int i = 0; i < 4; ++i) {
        rrA[i] = w * 32 + i * 8 + rStage;
        ccA[i] = (lane & 7) ^ (rrA[i] & 7);
    }
    int rrB[IB], ccB[IB];
    #pragma unroll
    for (int i = 0; i < IB; ++i) {
        rrB[i] = w * (BN / 4) + i * 8 + rStage;
        ccB[i] = (lane & 7) ^ (rrB[i] & 7);
    }

    auto stage = [&](int kt, int dd) {
        const int k0 = kt * 64;
        #pragma unroll
        for (int i = 0; i < 4; ++i)
            gload16(A + (size_t)(m0 + rrA[i]) * K + k0 + ccA[i] * 8, &As[dd][w * 2048 + i * 512]);
        #pragma unroll
        for (int i = 0; i < IB; ++i)
            gload16(Wt + (size_t)(n0 + rrB[i]) * K + k0 + ccB[i] * 8, &Bs[dd][w * (BN * 16) + i * 512]);
    };

    f32x4 acc[4][NB] = {};
    const int NT = K / 64;

    stage(0, 0);

    for (int t = 0; t < NT; ++t) {
        const int d = t & 1;
        barrier_raw();
        if (t + 1 < NT) {
            stage(t + 1, d ^ 1);
            if constexpr (BN == 128) asm volatile("s_waitcnt vmcnt(8)" ::: "memory");
            else                     asm volatile("s_waitcnt vmcnt(6)" ::: "memory");
        } else {
            asm volatile("s_waitcnt vmcnt(0)" ::: "memory");
        }
        barrier_raw();
        __builtin_amdgcn_sched_barrier(0);

        #pragma unroll
        for (int kk = 0; kk < 2; ++kk) {
            bf16x8 a[4], b[NB];
            #pragma unroll
            for (int mb = 0; mb < 4; ++mb) {
                int r  = wm + mb * 16 + l15;
                int ph = (kk * 4 + l4) ^ (r & 7);
                a[mb] = *reinterpret_cast<const bf16x8*>(&As[d][r * 64 + ph * 8]);
            }
            #pragma unroll
            for (int nb = 0; nb < NB; ++nb) {
                int r  = wn + nb * 16 + l15;
                int ph = (kk * 4 + l4) ^ (r & 7);
                b[nb] = *reinterpret_cast<const bf16x8*>(&Bs[d][r * 64 + ph * 8]);
            }
            #pragma unroll
            for (int mb = 0; mb < 4; ++mb)
                #pragma unroll
                for (int nb = 0; nb < NB; ++nb)
                    acc[mb][nb] = __builtin_amdgcn_mfma_f32_16x16x32_bf16(a[mb], b[nb], acc[mb][nb], 0, 0, 0);
        }
    }

    #pragma unroll
    for (int nb = 0; nb < NB; ++nb) {
        int col = n0 + wn + nb * 16 + l15;
        float bv = bias[col];
        #pragma unroll
        for (int mb = 0; mb < 4; ++mb) {
            #pragma unroll
            for (int i = 0; i < 4; ++i) {
                int row = m0 + wm + mb * 16 + l4 * 4 + i;
                float v = acc[mb][nb][i] + bv;
                if (EPI == 1) v = gelu_erf(v);
                if (EPI == 2) v += ldv(res + (size_t)row * N + col);
                stv(C + (size_t)row * N + col, v);
            }
        }
    }
}

// ---------------------------------------------------------------------------
// Fused film-g2 + LayerNorm + FiLM, XCD-swizzled grid.
// ---------------------------------------------------------------------------
template<typename TX>
__launch_bounds__(256)
__global__ void gemmfilm_k(const u16* __restrict__ A, const u16* __restrict__ Wt,
                           const float* __restrict__ b2, const TX* __restrict__ X,
                           const float* __restrict__ stats,
                           const float* __restrict__ lng, const float* __restrict__ lnb,
                           u16* __restrict__ Y)
{
    constexpr int Kc = D2_;
    __shared__ u16 As[2][128 * 64];
    __shared__ u16 Bs[2][128 * 64];

    const int tid  = threadIdx.x;
    const int lane = tid & 63;
    const int w    = tid >> 6;
    const int wm   = (w >> 1) * 64, wn = (w & 1) * 32;
    const int nwg  = gridDim.x * gridDim.y;
    const int lin  = xcd_swz(blockIdx.y * gridDim.x + blockIdx.x, nwg);
    const int m0   = (lin / gridDim.x) * 128, n0 = (lin % gridDim.x) * 64;
    const int l15  = lane & 15, l4 = lane >> 4;
    const int rStage = lane >> 3;

    int rrA[4], ccA[4];
    #pragma unroll
    for (int i = 0; i < 4; ++i) {
        rrA[i] = w * 32 + i * 8 + rStage;
        ccA[i] = (lane & 7) ^ (rrA[i] & 7);
    }
    int ccB[4], grB[4];
    #pragma unroll
    for (int i = 0; i < 4; ++i) {
        int lr = w * 16 + (i & 1) * 8 + rStage;
        grB[i]  = (i < 2 ? n0 : D_ + n0) + lr;
        ccB[i]  = (lane & 7) ^ (lr & 7);
    }

    auto stage = [&](int kt, int dd) {
        const int k0 = kt * 64;
        #pragma unroll
        for (int i = 0; i < 4; ++i)
            gload16(A + (size_t)(m0 + rrA[i]) * Kc + k0 + ccA[i] * 8, &As[dd][w * 2048 + i * 512]);
        #pragma unroll
        for (int i = 0; i < 4; ++i)
            gload16(Wt + (size_t)grB[i] * Kc + k0 + ccB[i] * 8,
                    &Bs[dd][((i < 2 ? 0 : 64) + w * 16 + (i & 1) * 8) * 64]);
    };

    f32x4 accG[4][2] = {}, accB2[4][2] = {};
    const int NT = Kc / 64;

    stage(0, 0);

    for (int t = 0; t < NT; ++t) {
        const int d = t & 1;
        barrier_raw();
        if (t + 1 < NT) {
            stage(t + 1, d ^ 1);
            asm volatile("s_waitcnt vmcnt(8)" ::: "memory");
        } else {
            asm volatile("s_waitcnt vmcnt(0)" ::: "memory");
        }
        barrier_raw();
        __builtin_amdgcn_sched_barrier(0);

        #pragma unroll
        for (int kk = 0; kk < 2; ++kk) {
            bf16x8 a[4], bg[2], bb[2];
            #pragma unroll
            for (int mb = 0; mb < 4; ++mb) {
                int r  = wm + mb * 16 + l15;
                int ph = (kk * 4 + l4) ^ (r & 7);
                a[mb] = *reinterpret_cast<const bf16x8*>(&As[d][r * 64 + ph * 8]);
            }
            #pragma unroll
            for (int nb = 0; nb < 2; ++nb) {
                int r  = wn + nb * 16 + l15;
                int ph = (kk * 4 + l4) ^ (r & 7);
                bg[nb] = *reinterpret_cast<const bf16x8*>(&Bs[d][r * 64 + ph * 8]);
                bb[nb] = *reinterpret_cast<const bf16x8*>(&Bs[d][(64 + r) * 64 + ph * 8]);
            }
            #pragma unroll
            for (int mb = 0; mb < 4; ++mb)
                #pragma unroll
                for (int nb = 0; nb < 2; ++nb) {
                    accG[mb][nb]  = __builtin_amdgcn_mfma_f32_16x16x32_bf16(a[mb], bg[nb], accG[mb][nb], 0, 0, 0);
                    accB2[mb][nb] = __builtin_amdgcn_mfma_f32_16x16x32_bf16(a[mb], bb[nb], accB2[mb][nb], 0, 0, 0);
                }
        }
    }

    #pragma unroll
    for (int nb = 0; nb < 2; ++nb) {
        int col = n0 + wn + nb * 16 + l15;
        float gb_ = b2[col], bb_ = b2[D_ + col];
        float lg = lng[col], lb = lnb[col];
        #pragma unroll
        for (int mb = 0; mb < 4; ++mb) {
            #pragma unroll
            for (int i = 0; i < 4; ++i) {
                int row = m0 + wm + mb * 16 + l4 * 4 + i;
                float mean = stats[row * 2], rstd = stats[row * 2 + 1];
                float xv = ldv(X + (size_t)row * D_ + col);
                float gamma = accG[mb][nb][i] + gb_;
                float beta  = accB2[mb][nb][i] + bb_;
                float v = ((xv - mean) * rstd * lg + lb) * (1.0f + gamma) + beta;
                Y[(size_t)row * D_ + col] = f2bf(v);
            }
        }
    }
}

// ---------------------------------------------------------------------------
// Flash attention (r12/r14 proven version), XCD-swizzled block id: each XCD
// gets 4 complete heads -> K/V panels (2 MB) stay resident in its L2.
// ---------------------------------------------------------------------------
__launch_bounds__(256)
__global__ void attn_k(const u16* __restrict__ Q, const u16* __restrict__ K,
                       const u16* __restrict__ Vv, const u16* __restrict__ Lm,
                       u16* __restrict__ O, int ld)
{
    __shared__ u16 Ks[64 * 64];
    __shared__ u16 Vs[64 * 64];
    __shared__ u16 Lms[128 * 64];
    __shared__ u16 Ps[128 * 72];

    const int blk = xcd_swz(blockIdx.x, gridDim.x);
    const int qt  = blk & 15;
    const int h   = (blk >> 4) & 15;
    const int b   = blk >> 8;
    const int q0  = qt * 128;
    const int tid = threadIdx.x, lane = tid & 63, w = tid >> 6;
    const int l15 = lane & 15, l4 = lane >> 4;
    const size_t bV = (size_t)b * V_;

    bf16x8 qa[2][2];
    #pragma unroll
    for (int g = 0; g < 2; ++g) {
        const u16* qp = Q + (bV + q0 + w * 32 + g * 16 + l15) * ld + h * 64;
        u16x8 r0 = *reinterpret_cast<const u16x8*>(qp + l4 * 8);
        u16x8 r1 = *reinterpret_cast<const u16x8*>(qp + 32 + l4 * 8);
        u16x8 s0, s1;
        #pragma unroll
        for (int j = 0; j < 8; ++j) {
            s0[j] = f2bf(bf2f(r0[j]) * 0.125f);
            s1[j] = f2bf(bf2f(r1[j]) * 0.125f);
        }
        union { u16x8 u; bf16x8 h; } c0, c1;
        c0.u = s0; c1.u = s1;
        qa[g][0] = c0.h; qa[g][1] = c1.h;
    }

    const int rStage = (lane >> 3);
    const int cSw    = ((lane & 7) ^ rStage) * 8;
    const int vK     = ((lane >> 5) << 2) + ((lane & 7) >> 1);
    const int vDk    = ((lane >> 3) & 3) * 16 + (lane & 1) * 8;
    const u32 vaddr  = (u32)(uintptr_t)&Vs[0] + (l4 << 10) + (l15 << 3);

    int lmOff[4];
    #pragma unroll
    for (int kb = 0; kb < 4; ++kb)
        lmOff[kb] = ((((kb << 1) | (l4 >> 1)) ^ (l15 & 7)) << 3);

    const float LOG2E = 1.44269504088896f;
    float lrp[2] = {0.f, 0.f};
    f32x4 o4[2][4] = {};

    for (int kt = 0; kt < V_ / 64; ++kt) {
        const int k0 = kt * 64;
        if (kt) __syncthreads();
        #pragma unroll
        for (int i = 0; i < 2; ++i) {
            int r  = i * 32 + w * 8 + rStage;
            int kv = i * 32 + w * 8 + vK;
            gload16(K  + (bV + k0 + r)  * ld + h * 64 + cSw, &Ks[i * 2048 + w * 512]);
            gload16(Vv + (bV + k0 + kv) * ld + h * 64 + vDk, &Vs[i * 2048 + w * 512]);
        }
        #pragma unroll
        for (int i = 0; i < 4; ++i) {
            int r = i * 32 + w * 8 + rStage;
            gload16(Lm + (bV + q0 + r) * (size_t)V_ + k0 + cSw, &Lms[i * 2048 + w * 512]);
        }
        __syncthreads();

        #pragma unroll
        for (int g = 0; g < 2; ++g) {
            f32x4 s[4];
            #pragma unroll
            for (int kb = 0; kb < 4; ++kb) {
                int row = (kb * 16 + l15) * 64;
                bf16x8 k0f = *reinterpret_cast<const bf16x8*>(&Ks[row + ((l4 ^ (l15 & 7)) * 8)]);
                bf16x8 k1f = *reinterpret_cast<const bf16x8*>(&Ks[row + (((l4 + 4) ^ (l15 & 7)) * 8)]);
                f32x4 z = {};
                z = __builtin_amdgcn_mfma_f32_16x16x32_bf16(k0f, qa[g][0], z, 0, 0, 0);
                z = __builtin_amdgcn_mfma_f32_16x16x32_bf16(k1f, qa[g][1], z, 0, 0, 0);
                s[kb] = z;
            }
            const int lmRow = w * 32 + g * 16 + l15;
            const u16* lmBase = &Lms[lmRow * 64 + (l4 & 1) * 4];
            u16* psW = &Ps[lmRow * 72 + l4 * 4];
            #pragma unroll
            for (int kb = 0; kb < 4; ++kb) {
                u16x4 lm4 = *reinterpret_cast<const u16x4*>(lmBase + lmOff[kb]);
                float p0, p1, p2, p3;
                float t0 = fmaf(s[kb][0], LOG2E, bf2f(lm4[0]));
                float t1 = fmaf(s[kb][1], LOG2E, bf2f(lm4[1]));
                float t2 = fmaf(s[kb][2], LOG2E, bf2f(lm4[2]));
                float t3 = fmaf(s[kb][3], LOG2E, bf2f(lm4[3]));
                asm("v_exp_f32 %0, %1" : "=v"(p0) : "v"(t0));
                asm("v_exp_f32 %0, %1" : "=v"(p1) : "v"(t1));
                asm("v_exp_f32 %0, %1" : "=v"(p2) : "v"(t2));
                asm("v_exp_f32 %0, %1" : "=v"(p3) : "v"(t3));
                lrp[g] += (p0 + p1) + (p2 + p3);
                u32 d0, d1;
                asm("v_cvt_pk_bf16_f32 %0, %1, %2" : "=v"(d0) : "v"(p0), "v"(p1));
                asm("v_cvt_pk_bf16_f32 %0, %1, %2" : "=v"(d1) : "v"(p2), "v"(p3));
                u32x2 dd = {d0, d1};
                *reinterpret_cast<u32x2*>(psW + kb * 16) = dd;
            }
        }

        union VU { u32x4 u; bf16x8 h; };
        VU vb[2][4];
        #pragma unroll
        for (int c2 = 0; c2 < 2; ++c2) {
            u32 a0 = vaddr + c2 * 4096;
            u32x2 t0, t1, t2, t3, t4, t5, t6, t7;
            asm volatile("ds_read_b64_tr_b16 %0, %1"            : "=v"(t0) : "v"(a0));
            asm volatile("ds_read_b64_tr_b16 %0, %1 offset:512" : "=v"(t1) : "v"(a0));
            asm volatile("ds_read_b64_tr_b16 %0, %1 offset:128" : "=v"(t2) : "v"(a0));
            asm volatile("ds_read_b64_tr_b16 %0, %1 offset:640" : "=v"(t3) : "v"(a0));
            asm volatile("ds_read_b64_tr_b16 %0, %1 offset:256" : "=v"(t4) : "v"(a0));
            asm volatile("ds_read_b64_tr_b16 %0, %1 offset:768" : "=v"(t5) : "v"(a0));
            asm volatile("ds_read_b64_tr_b16 %0, %1 offset:384" : "=v"(t6) : "v"(a0));
            asm volatile("ds_read_b64_tr_b16 %0, %1 offset:896" : "=v"(t7) : "v"(a0));
            asm volatile("s_waitcnt lgkmcnt(0)" ::: "memory");
            __builtin_amdgcn_sched_barrier(0);
            vb[c2][0].u = (u32x4){t0.x, t0.y, t1.x, t1.y};
            vb[c2][1].u = (u32x4){t2.x, t2.y, t3.x, t3.y};
            vb[c2][2].u = (u32x4){t4.x, t4.y, t5.x, t5.y};
            vb[c2][3].u = (u32x4){t6.x, t6.y, t7.x, t7.y};
        }
        #pragma unroll
        for (int g = 0; g < 2; ++g) {
            const u16* pr = &Ps[(w * 32 + g * 16 + l15) * 72];
            bf16x8 pa0 = *reinterpret_cast<const bf16x8*>(pr + l4 * 8);
            bf16x8 pa1 = *reinterpret_cast<const bf16x8*>(pr + 32 + l4 * 8);
            #pragma unroll
            for (int nb = 0; nb < 4; ++nb) {
                o4[g][nb] = __builtin_amdgcn_mfma_f32_16x16x32_bf16(pa0, vb[0][nb].h, o4[g][nb], 0, 0, 0);
                o4[g][nb] = __builtin_amdgcn_mfma_f32_16x16x32_bf16(pa1, vb[1][nb].h, o4[g][nb], 0, 0, 0);
            }
        }
    }

    #pragma unroll
    for (int g = 0; g < 2; ++g) {
        float v = lrp[g];
        v += __shfl_xor(v, 16);
        v += __shfl_xor(v, 32);
        #pragma unroll
        for (int i = 0; i < 4; ++i) {
            float lw = __shfl(v, (lane & 48) | ((l4 << 2) + i));
            float rcp = 1.0f / (lw + 1e-8f);
            int q = q0 + w * 32 + g * 16 + l4 * 4 + i;
            u16* op = O + (bV + q) * D_ + h * 64;
            #pragma unroll
            for (int nb = 0; nb < 4; ++nb)
                op[nb * 16 + l15] = f2bf(o4[g][nb][i] * rcp);
        }
    }
}

// ---------------------------------------------------------------------------
extern "C" void kernel_launch(void* const* d_in, const int* in_sizes, int n_in,
                              void* d_out, int out_size, void* d_ws, size_t ws_size,
                              hipStream_t stream)
{
    (void)in_sizes; (void)n_in; (void)out_size; (void)ws_size;
    const float* x    = (const float*)d_in[0];
    const float* e    = (const float*)d_in[1];
    const float* conn = (const float*)d_in[2];
    const float* ln1g = (const float*)d_in[3];
    const float* ln1b = (const float*)d_in[4];
    const float* f1w1 = (const float*)d_in[5];
    const float* f1b1 = (const float*)d_in[6];
    const float* f1w2 = (const float*)d_in[7];
    const float* f1b2 = (const float*)d_in[8];
    const float* wq   = (const float*)d_in[9];
    const float* bq   = (const float*)d_in[10];
    const float* wk   = (const float*)d_in[11];
    const float* bk   = (const float*)d_in[12];
    const float* wv   = (const float*)d_in[13];
    const float* bv   = (const float*)d_in[14];
    const float* wp   = (const float*)d_in[15];
    const float* bp   = (const float*)d_in[16];
    const float* ln2g = (const float*)d_in[17];
    const float* ln2b = (const float*)d_in[18];
    const float* f2w1 = (const float*)d_in[19];
    const float* f2b1 = (const float*)d_in[20];
    const float* f2w2 = (const float*)d_in[21];
    const float* f2b2 = (const float*)d_in[22];
    const float* ffw1 = (const float*)d_in[23];
    const float* ffb1 = (const float*)d_in[24];
    const float* ffw2 = (const float*)d_in[25];
    const float* ffb2 = (const float*)d_in[26];
    float* out = (float*)d_out;

    // workspace schedule (MB offsets, peak 72 MB == proven-safe, r14 layout)
    char* ws = (char*)d_ws;
    const size_t MB = 1u << 20;
    u16*   Lm    = (u16*)(ws + 0);        // 0-16   log2-mask (live -> attn)
    u16*   e_bf  = (u16*)(ws + 16 * MB);  // 16-18  (live -> film2 gemm1)
    u16*   h     = (u16*)(ws + 18 * MB);  // 18-34
    u16*   wt2   = (u16*)(ws + 34 * MB);  // 34-36  small weight slot
    float* stats = (float*)(ws + 35 * MB);// 35-36  LN row stats (32 KB)
    u16*   wt8   = (u16*)(ws + 36 * MB);  // 36-44  f1w2t / f2w2t
    u16*   y     = (u16*)(ws + 60 * MB);  // 60-68
    u16*   wqkvt = (u16*)(ws + 18 * MB);  // 18-24  (h dead)
    u16*   qkv   = (u16*)(ws + 24 * MB);  // 24-48  fused QKV [4096][3072]
    float* qkvb  = (float*)(ws + 71 * MB);// 71-72
    u16*   o     = (u16*)(ws + 48 * MB);  // 48-56
    u16*   xnew  = (u16*)(ws + 64 * MB);  // 64-72  (y dead by then)
    u16*   h2    = (u16*)(ws + 18 * MB);  // 18-34
    u16*   y2    = (u16*)(ws + 0);        // 0-8    (Lm dead)
    u16*   ffw1t = (u16*)(ws + 8 * MB);   // 8-16
    u16*   t     = (u16*)(ws + 16 * MB);  // 16-48
    u16*   ffw2t = (u16*)(ws + 48 * MB);  // 48-56

    dim3 blk(256), tblk(32, 8);
    #define CONVT(W, WT, K, N) convT_k<<<dim3((N)/32, (K)/32), tblk, 0, stream>>>(W, WT, K, N)

    // fused prologue: lmask + e->bf16 + LN stats(x) + qkv bias concat
    prep_k<<<NL_ + NC_ + NX_ + D3_/256, blk, 0, stream>>>(conn, Lm, e, e_bf, x, stats, bq, bk, bv, qkvb);

    // FiLM 1: g1 GEMM, then fused g2+LN+FiLM
    CONVT(f1w1, wt2, DE_, D2_);
    gemm_k<1, 64, u16, u16><<<dim3(D2_/64, M_/128), blk, 0, stream>>>(e_bf, wt2, f1b1, (const u16*)nullptr, h, M_, D2_, DE_);
    CONVT(f1w2, wt8, D2_, D2_);
    gemmfilm_k<float><<<dim3(D_/64, M_/128), blk, 0, stream>>>(h, wt8, f1b2, x, stats, ln1g, ln1b, y);
    // fused QKV (batched transposes + BN=128 pipelined GEMM)
    convT3_k<<<dim3(D_/32, D_/32, 3), tblk, 0, stream>>>(wq, wk, wv, wqkvt);
    gemm_k<0, 128, u16, u16><<<dim3(D3_/128, M_/128), blk, 0, stream>>>(y, wqkvt, qkvb, (const u16*)nullptr, qkv, M_, D3_, D_);
    // attention (QBLK=128, XCD-swizzled)
    attn_k<<<B_*H_*(V_/128), blk, 0, stream>>>(qkv, qkv + 1024, qkv + 2048, Lm, o, D3_);
    // projection + residual (res = x, f32)
    CONVT(wp, wt2, D_, D_);
    gemm_k<2, 64, u16, float><<<dim3(D_/64, M_/128), blk, 0, stream>>>(o, wt2, bp, x, xnew, M_, D_, D_);
    // FiLM 2: g1 GEMM, then fused g2+LN+FiLM (stats from xnew)
    CONVT(f2w1, wt2, DE_, D2_);
    gemm_k<1, 64, u16, u16><<<dim3(D2_/64, M_/128), blk, 0, stream>>>(e_bf, wt2, f2b1, (const u16*)nullptr, h2, M_, D2_, DE_);
    xstats_k<u16><<<M_, blk, 0, stream>>>(xnew, stats);
    CONVT(f2w2, wt8, D2_, D2_);
    gemmfilm_k<u16><<<dim3(D_/64, M_/128), blk, 0, stream>>>(h2, wt8, f2b2, xnew, stats, ln2g, ln2b, y2);
    // FFN + residual -> out (f32)
    CONVT(ffw1, ffw1t, D_, DFF_);
    gemm_k<1, 128, u16, u16><<<dim3(DFF_/128, M_/128), blk, 0, stream>>>(y2, ffw1t, ffb1, (const u16*)nullptr, t, M_, DFF_, D_);
    CONVT(ffw2, ffw2t, DFF_, D_);
    gemm_k<2, 64, float, u16><<<dim3(D_/64, M_/128), blk, 0, stream>>>(t, ffw2t, ffb2, xnew, out, M_, D_, DFF_);
    #undef CONVT
}

// Round 18
// 372.970 us; speedup vs baseline: 1.1119x; 1.0001x over previous
//
#include <hip/hip_runtime.h>
#include <math.h>
#include <stdint.h>

// Problem constants (B,V,D,H,DE,DFF fixed by the reference)
#define B_   2
#define V_   2048
#define D_   1024
#define H_   16
#define DK_  64
#define DE_  256
#define DFF_ 4096
#define M_   (B_*V_)     // 4096 tokens
#define D2_  (2*D_)      // 2048
#define D3_  (3*D_)      // 3072 (fused QKV width)

typedef unsigned short u16;
typedef unsigned int   u32;
typedef __bf16 bf16x8 __attribute__((ext_vector_type(8)));
typedef u16    u16x8  __attribute__((ext_vector_type(8)));
typedef u16    u16x4  __attribute__((ext_vector_type(4)));
typedef float  f32x4  __attribute__((ext_vector_type(4)));
typedef u32    u32x2  __attribute__((ext_vector_type(2)));
typedef u32    u32x4  __attribute__((ext_vector_type(4)));

__device__ __forceinline__ float bf2f(u16 u) {
    union { unsigned int i; float f; } z; z.i = ((unsigned int)u) << 16; return z.f;
}
__device__ __forceinline__ u16 f2bf(float f) {
    union { float f; unsigned int i; } z; z.f = f;
    unsigned int x = z.i;
    return (u16)((x + 0x7fffu + ((x >> 16) & 1u)) >> 16);  // RNE
}
__device__ __forceinline__ float gelu_erf(float v) {
    return 0.5f * v * (1.0f + erff(v * 0.70710678118654752f));
}
__device__ __forceinline__ float ldv(const float* p) { return *p; }
__device__ __forceinline__ float ldv(const u16* p)   { return bf2f(*p); }
__device__ __forceinline__ void  stv(float* p, float v) { *p = v; }
__device__ __forceinline__ void  stv(u16* p,   float v) { *p = f2bf(v); }

// async global->LDS, 16B per lane; LDS dest = wave-uniform base + lane*16
__device__ __forceinline__ void gload16(const void* g, void* lds)
{
    __builtin_amdgcn_global_load_lds(
        (const __attribute__((address_space(1))) void*)g,
        (__attribute__((address_space(3))) void*)(uintptr_t)lds,
        16, 0, 0);
}

// raw workgroup barrier WITHOUT the compiler's implicit vmcnt(0) drain.
__device__ __forceinline__ void barrier_raw()
{
    asm volatile("" ::: "memory");
    __builtin_amdgcn_s_barrier();
    asm volatile("" ::: "memory");
}

// XCD-aware bijective block swizzle (requires nwg % 8 == 0)
__device__ __forceinline__ int xcd_swz(int lin, int nwg)
{
    return (lin & 7) * (nwg >> 3) + (lin >> 3);
}

// ---------------------------------------------------------------------------
// Weight convert+transpose: Wt[N][K] bf16 <- W[K][N] f32 (32x32 LDS tiles)
// ---------------------------------------------------------------------------
__global__ void convT_k(const float* __restrict__ W, u16* __restrict__ Wt, int K, int N)
{
    __shared__ float tile[32][33];
    const int n0 = blockIdx.x * 32, k0 = blockIdx.y * 32;
    const int tx = threadIdx.x, ty = threadIdx.y;   // 32 x 8
    #pragma unroll
    for (int j = 0; j < 4; ++j)
        tile[ty * 4 + j][tx] = W[(size_t)(k0 + ty * 4 + j) * N + n0 + tx];
    __syncthreads();
    #pragma unroll
    for (int j = 0; j < 4; ++j)
        Wt[(size_t)(n0 + ty * 4 + j) * K + k0 + tx] = f2bf(tile[tx][ty * 4 + j]);
}

// batched 1024x1024 transposes (wq,wk,wv) selected by blockIdx.z
__global__ void convT3_k(const float* __restrict__ W0, const float* __restrict__ W1,
                         const float* __restrict__ W2, u16* __restrict__ Wt)
{
    __shared__ float tile[32][33];
    const float* W = blockIdx.z == 0 ? W0 : (blockIdx.z == 1 ? W1 : W2);
    u16* dst = Wt + (size_t)blockIdx.z * D_ * D_;
    const int n0 = blockIdx.x * 32, k0 = blockIdx.y * 32;
    const int tx = threadIdx.x, ty = threadIdx.y;
    #pragma unroll
    for (int j = 0; j < 4; ++j)
        tile[ty * 4 + j][tx] = W[(size_t)(k0 + ty * 4 + j) * D_ + n0 + tx];
    __syncthreads();
    #pragma unroll
    for (int j = 0; j < 4; ++j)
        dst[(size_t)(n0 + ty * 4 + j) * D_ + k0 + tx] = f2bf(tile[tx][ty * 4 + j]);
}

// ---------------------------------------------------------------------------
// prep: fused prologue (e->bf16 + LN stats of x + qkv bias concat)
// ---------------------------------------------------------------------------
#define NC_ 1024   // conv blocks:   M*DE/1024
#define NX_ 4096   // xstats blocks: M
__launch_bounds__(256)
__global__ void prep_k(const float* __restrict__ e, u16* __restrict__ e_bf,
                       const float* __restrict__ X, float* __restrict__ stats,
                       const float* __restrict__ bq, const float* __restrict__ bk,
                       const float* __restrict__ bv, float* __restrict__ qkvb)
{
    __shared__ float rs[4], rq[4];
    const int bid = blockIdx.x;
    const int tid = threadIdx.x;
    if (bid < NC_) {
        const int i = (bid * 256 + tid) * 4;
        f32x4 v = *reinterpret_cast<const f32x4*>(e + i);
        u16x4 o;
        #pragma unroll
        for (int j = 0; j < 4; ++j) o[j] = f2bf(v[j]);
        *reinterpret_cast<u16x4*>(e_bf + i) = o;
    } else if (bid < NC_ + NX_) {
        const int row = bid - NC_;
        f32x4 v4 = *reinterpret_cast<const f32x4*>(X + (size_t)row * D_ + tid * 4);
        float s = 0.f, sq = 0.f;
        #pragma unroll
        for (int j = 0; j < 4; ++j) { s += v4[j]; sq += v4[j] * v4[j]; }
        #pragma unroll
        for (int off = 32; off; off >>= 1) {
            s  += __shfl_xor(s, off);
            sq += __shfl_xor(sq, off);
        }
        const int w = tid >> 6;
        if ((tid & 63) == 0) { rs[w] = s; rq[w] = sq; }
        __syncthreads();
        if (tid == 0) {
            s  = rs[0] + rs[1] + rs[2] + rs[3];
            sq = rq[0] + rq[1] + rq[2] + rq[3];
            float mean = s * (1.0f / D_);
            float var  = sq * (1.0f / D_) - mean * mean;
            stats[row * 2]     = mean;
            stats[row * 2 + 1] = rsqrtf(fmaxf(var, 0.f) + 1e-5f);
        }
    } else {
        const int i = (bid - NC_ - NX_) * 256 + tid;
        qkvb[i] = i < 1024 ? bq[i] : (i < 2048 ? bk[i - 1024] : bv[i - 2048]);
    }
}

// per-row LayerNorm stats (standalone, for xnew)
template<typename TX>
__launch_bounds__(256)
__global__ void xstats_k(const TX* __restrict__ X, float* __restrict__ stats)
{
    const int row = blockIdx.x;
    const int tid = threadIdx.x;
    const TX* xr = X + (size_t)row * D_ + tid * 4;
    float s = 0.f, sq = 0.f;
    if constexpr (sizeof(TX) == 4) {
        f32x4 v4 = *reinterpret_cast<const f32x4*>(xr);
        #pragma unroll
        for (int j = 0; j < 4; ++j) { s += v4[j]; sq += v4[j] * v4[j]; }
    } else {
        u16x4 v4 = *reinterpret_cast<const u16x4*>(xr);
        #pragma unroll
        for (int j = 0; j < 4; ++j) { float v = bf2f(v4[j]); s += v; sq += v * v; }
    }
    #pragma unroll
    for (int off = 32; off; off >>= 1) {
        s  += __shfl_xor(s, off);
        sq += __shfl_xor(sq, off);
    }
    __shared__ float rs[4], rq[4];
    const int w = tid >> 6;
    if ((tid & 63) == 0) { rs[w] = s; rq[w] = sq; }
    __syncthreads();
    if (tid == 0) {
        s  = rs[0] + rs[1] + rs[2] + rs[3];
        sq = rq[0] + rq[1] + rq[2] + rq[3];
        float mean = s * (1.0f / D_);
        float var  = sq * (1.0f / D_) - mean * mean;
        stats[row * 2]     = mean;
        stats[row * 2 + 1] = rsqrtf(fmaxf(var, 0.f) + 1e-5f);
    }
}

// ---------------------------------------------------------------------------
// bf16 MFMA GEMM, counted-vmcnt pipelined, XCD-swizzled grid. (r17 verbatim)
// ---------------------------------------------------------------------------
template<int EPI, int BN, typename TC, typename TRES>
__launch_bounds__(256)
__global__ void gemm_k(const u16* __restrict__ A, const u16* __restrict__ Wt,
                       const float* __restrict__ bias, const TRES* __restrict__ res,
                       TC* __restrict__ C, int M, int N, int K)
{
    constexpr int NB = BN / 32;
    constexpr int IB = BN / 32;
    __shared__ u16 As[2][128 * 64];
    __shared__ u16 Bs[2][BN * 64];

    const int tid  = threadIdx.x;
    const int lane = tid & 63;
    const int w    = tid >> 6;
    const int wm   = (w >> 1) * 64, wn = (w & 1) * (BN / 2);
    const int nwg  = gridDim.x * gridDim.y;
    const int lin  = xcd_swz(blockIdx.y * gridDim.x + blockIdx.x, nwg);
    const int m0   = (lin / gridDim.x) * 128, n0 = (lin % gridDim.x) * BN;
    const int l15  = lane & 15, l4 = lane >> 4;
    const int rStage = lane >> 3;

    int rrA[4], ccA[4];
    #pragma unroll
    for (int i = 0; i < 4; ++i) {
        rrA[i] = w * 32 + i * 8 + rStage;
        ccA[i] = (lane & 7) ^ (rrA[i] & 7);
    }
    int rrB[IB], ccB[IB];
    #pragma unroll
    for (int i = 0; i < IB; ++i) {
        rrB[i] = w * (BN / 4) + i * 8 + rStage;
        ccB[i] = (lane & 7) ^ (rrB[i] & 7);
    }

    auto stage = [&](int kt, int dd) {
        const int k0 = kt * 64;
        #pragma unroll
        for (int i = 0; i < 4; ++i)
            gload16(A + (size_t)(m0 + rrA[i]) * K + k0 + ccA[i] * 8, &As[dd][w * 2048 + i * 512]);
        #pragma unroll
        for (int i = 0; i < IB; ++i)
            gload16(Wt + (size_t)(n0 + rrB[i]) * K + k0 + ccB[i] * 8, &Bs[dd][w * (BN * 16) + i * 512]);
    };

    f32x4 acc[4][NB] = {};
    const int NT = K / 64;

    stage(0, 0);

    for (int t = 0; t < NT; ++t) {
        const int d = t & 1;
        barrier_raw();
        if (t + 1 < NT) {
            stage(t + 1, d ^ 1);
            if constexpr (BN == 128) asm volatile("s_waitcnt vmcnt(8)" ::: "memory");
            else                     asm volatile("s_waitcnt vmcnt(6)" ::: "memory");
        } else {
            asm volatile("s_waitcnt vmcnt(0)" ::: "memory");
        }
        barrier_raw();
        __builtin_amdgcn_sched_barrier(0);

        #pragma unroll
        for (int kk = 0; kk < 2; ++kk) {
            bf16x8 a[4], b[NB];
            #pragma unroll
            for (int mb = 0; mb < 4; ++mb) {
                int r  = wm + mb * 16 + l15;
                int ph = (kk * 4 + l4) ^ (r & 7);
                a[mb] = *reinterpret_cast<const bf16x8*>(&As[d][r * 64 + ph * 8]);
            }
            #pragma unroll
            for (int nb = 0; nb < NB; ++nb) {
                int r  = wn + nb * 16 + l15;
                int ph = (kk * 4 + l4) ^ (r & 7);
                b[nb] = *reinterpret_cast<const bf16x8*>(&Bs[d][r * 64 + ph * 8]);
            }
            #pragma unroll
            for (int mb = 0; mb < 4; ++mb)
                #pragma unroll
                for (int nb = 0; nb < NB; ++nb)
                    acc[mb][nb] = __builtin_amdgcn_mfma_f32_16x16x32_bf16(a[mb], b[nb], acc[mb][nb], 0, 0, 0);
        }
    }

    #pragma unroll
    for (int nb = 0; nb < NB; ++nb) {
        int col = n0 + wn + nb * 16 + l15;
        float bv = bias[col];
        #pragma unroll
        for (int mb = 0; mb < 4; ++mb) {
            #pragma unroll
            for (int i = 0; i < 4; ++i) {
                int row = m0 + wm + mb * 16 + l4 * 4 + i;
                float v = acc[mb][nb][i] + bv;
                if (EPI == 1) v = gelu_erf(v);
                if (EPI == 2) v += ldv(res + (size_t)row * N + col);
                stv(C + (size_t)row * N + col, v);
            }
        }
    }
}

// ---------------------------------------------------------------------------
// Fused film-g2 + LayerNorm + FiLM, XCD-swizzled grid. (r17 verbatim)
// ---------------------------------------------------------------------------
template<typename TX>
__launch_bounds__(256)
__global__ void gemmfilm_k(const u16* __restrict__ A, const u16* __restrict__ Wt,
                           const float* __restrict__ b2, const TX* __restrict__ X,
                           const float* __restrict__ stats,
                           const float* __restrict__ lng, const float* __restrict__ lnb,
                           u16* __restrict__ Y)
{
    constexpr int Kc = D2_;
    __shared__ u16 As[2][128 * 64];
    __shared__ u16 Bs[2][128 * 64];

    const int tid  = threadIdx.x;
    const int lane = tid & 63;
    const int w    = tid >> 6;
    const int wm   = (w >> 1) * 64, wn = (w & 1) * 32;
    const int nwg  = gridDim.x * gridDim.y;
    const int lin  = xcd_swz(blockIdx.y * gridDim.x + blockIdx.x, nwg);
    const int m0   = (lin / gridDim.x) * 128, n0 = (lin % gridDim.x) * 64;
    const int l15  = lane & 15, l4 = lane >> 4;
    const int rStage = lane >> 3;

    int rrA[4], ccA[4];
    #pragma unroll
    for (int i = 0; i < 4; ++i) {
        rrA[i] = w * 32 + i * 8 + rStage;
        ccA[i] = (lane & 7) ^ (rrA[i] & 7);
    }
    int ccB[4], grB[4];
    #pragma unroll
    for (int i = 0; i < 4; ++i) {
        int lr = w * 16 + (i & 1) * 8 + rStage;
        grB[i]  = (i < 2 ? n0 : D_ + n0) + lr;
        ccB[i]  = (lane & 7) ^ (lr & 7);
    }

    auto stage = [&](int kt, int dd) {
        const int k0 = kt * 64;
        #pragma unroll
        for (int i = 0; i < 4; ++i)
            gload16(A + (size_t)(m0 + rrA[i]) * Kc + k0 + ccA[i] * 8, &As[dd][w * 2048 + i * 512]);
        #pragma unroll
        for (int i = 0; i < 4; ++i)
            gload16(Wt + (size_t)grB[i] * Kc + k0 + ccB[i] * 8,
                    &Bs[dd][((i < 2 ? 0 : 64) + w * 16 + (i & 1) * 8) * 64]);
    };

    f32x4 accG[4][2] = {}, accB2[4][2] = {};
    const int NT = Kc / 64;

    stage(0, 0);

    for (int t = 0; t < NT; ++t) {
        const int d = t & 1;
        barrier_raw();
        if (t + 1 < NT) {
            stage(t + 1, d ^ 1);
            asm volatile("s_waitcnt vmcnt(8)" ::: "memory");
        } else {
            asm volatile("s_waitcnt vmcnt(0)" ::: "memory");
        }
        barrier_raw();
        __builtin_amdgcn_sched_barrier(0);

        #pragma unroll
        for (int kk = 0; kk < 2; ++kk) {
            bf16x8 a[4], bg[2], bb[2];
            #pragma unroll
            for (int mb = 0; mb < 4; ++mb) {
                int r  = wm + mb * 16 + l15;
                int ph = (kk * 4 + l4) ^ (r & 7);
                a[mb] = *reinterpret_cast<const bf16x8*>(&As[d][r * 64 + ph * 8]);
            }
            #pragma unroll
            for (int nb = 0; nb < 2; ++nb) {
                int r  = wn + nb * 16 + l15;
                int ph = (kk * 4 + l4) ^ (r & 7);
                bg[nb] = *reinterpret_cast<const bf16x8*>(&Bs[d][r * 64 + ph * 8]);
                bb[nb] = *reinterpret_cast<const bf16x8*>(&Bs[d][(64 + r) * 64 + ph * 8]);
            }
            #pragma unroll
            for (int mb = 0; mb < 4; ++mb)
                #pragma unroll
                for (int nb = 0; nb < 2; ++nb) {
                    accG[mb][nb]  = __builtin_amdgcn_mfma_f32_16x16x32_bf16(a[mb], bg[nb], accG[mb][nb], 0, 0, 0);
                    accB2[mb][nb] = __builtin_amdgcn_mfma_f32_16x16x32_bf16(a[mb], bb[nb], accB2[mb][nb], 0, 0, 0);
                }
        }
    }

    #pragma unroll
    for (int nb = 0; nb < 2; ++nb) {
        int col = n0 + wn + nb * 16 + l15;
        float gb_ = b2[col], bb_ = b2[D_ + col];
        float lg = lng[col], lb = lnb[col];
        #pragma unroll
        for (int mb = 0; mb < 4; ++mb) {
            #pragma unroll
            for (int i = 0; i < 4; ++i) {
                int row = m0 + wm + mb * 16 + l4 * 4 + i;
                float mean = stats[row * 2], rstd = stats[row * 2 + 1];
                float xv = ldv(X + (size_t)row * D_ + col);
                float gamma = accG[mb][nb][i] + gb_;
                float beta  = accB2[mb][nb][i] + bb_;
                float v = ((xv - mean) * rstd * lg + lb) * (1.0f + gamma) + beta;
                Y[(size_t)row * D_ + col] = f2bf(v);
            }
        }
    }
}

// ---------------------------------------------------------------------------
// Flash attention, XCD-swizzled, direct f32 conn (no log-mask):
// P = exp2(S*log2e) * (conn + 1e-6)  [exact: exp(S+log(c+1e-6)) = exp(S)*(c+1e-6)]
// conn tile staged f32 with 16-chunk XOR swizzle (both-sides).
// ---------------------------------------------------------------------------
__launch_bounds__(256)
__global__ void attn_k(const u16* __restrict__ Q, const u16* __restrict__ K,
                       const u16* __restrict__ Vv, const float* __restrict__ Cn,
                       u16* __restrict__ O, int ld)
{
    __shared__ u16   Ks[64 * 64];    // 8 KB
    __shared__ u16   Vs[64 * 64];    // 8 KB
    __shared__ float Cs[128 * 64];   // 32 KB, [q][k] f32, 16B-chunk XOR by (row&15)
    __shared__ u16   Ps[128 * 72];   // 18 KB

    const int blk = xcd_swz(blockIdx.x, gridDim.x);
    const int qt  = blk & 15;
    const int h   = (blk >> 4) & 15;
    const int b   = blk >> 8;
    const int q0  = qt * 128;
    const int tid = threadIdx.x, lane = tid & 63, w = tid >> 6;
    const int l15 = lane & 15, l4 = lane >> 4;
    const size_t bV = (size_t)b * V_;

    // Q frags (B-operand), two 16-row groups, pre-scaled by 1/8 (exact)
    bf16x8 qa[2][2];
    #pragma unroll
    for (int g = 0; g < 2; ++g) {
        const u16* qp = Q + (bV + q0 + w * 32 + g * 16 + l15) * ld + h * 64;
        u16x8 r0 = *reinterpret_cast<const u16x8*>(qp + l4 * 8);
        u16x8 r1 = *reinterpret_cast<const u16x8*>(qp + 32 + l4 * 8);
        u16x8 s0, s1;
        #pragma unroll
        for (int j = 0; j < 8; ++j) {
            s0[j] = f2bf(bf2f(r0[j]) * 0.125f);
            s1[j] = f2bf(bf2f(r1[j]) * 0.125f);
        }
        union { u16x8 u; bf16x8 h; } c0, c1;
        c0.u = s0; c1.u = s1;
        qa[g][0] = c0.h; qa[g][1] = c1.h;
    }

    const int rStage = (lane >> 3);
    const int cSw    = ((lane & 7) ^ rStage) * 8;                // K pre-swizzled chunk
    const int vK     = ((lane >> 5) << 2) + ((lane & 7) >> 1);
    const int vDk    = ((lane >> 3) & 3) * 16 + (lane & 1) * 8;
    const u32 vaddr  = (u32)(uintptr_t)&Vs[0] + (l4 << 10) + (l15 << 3);

    // conn staging: 8 issues/wave, 4 rows each; source chunk pre-swizzled by row&15
    const int cnRow4 = (lane >> 4);                              // row within 4-row group
    const int cnChnk = lane & 15;                                // physical 16B chunk (4 f32)

    const float LOG2E = 1.44269504088896f;
    float lrp[2] = {0.f, 0.f};
    f32x4 o4[2][4] = {};

    for (int kt = 0; kt < V_ / 64; ++kt) {
        const int k0 = kt * 64;
        if (kt) __syncthreads();
        #pragma unroll
        for (int i = 0; i < 2; ++i) {
            int r  = i * 32 + w * 8 + rStage;
            int kv = i * 32 + w * 8 + vK;
            gload16(K  + (bV + k0 + r)  * ld + h * 64 + cSw, &Ks[i * 2048 + w * 512]);
            gload16(Vv + (bV + k0 + kv) * ld + h * 64 + vDk, &Vs[i * 2048 + w * 512]);
        }
        #pragma unroll
        for (int i = 0; i < 8; ++i) {
            int row = w * 32 + i * 4 + cnRow4;                   // 0..127
            int sc  = cnChnk ^ (row & 15);                       // source chunk (4 f32)
            gload16(Cn + (bV + q0 + row) * (size_t)V_ + k0 + sc * 4,
                    &Cs[(w * 32 + i * 4) * 64]);
        }
        __syncthreads();   // drains vmcnt(0): tiles resident

        #pragma unroll
        for (int g = 0; g < 2; ++g) {
            f32x4 s[4];
            #pragma unroll
            for (int kb = 0; kb < 4; ++kb) {
                int row = (kb * 16 + l15) * 64;
                bf16x8 k0f = *reinterpret_cast<const bf16x8*>(&Ks[row + ((l4 ^ (l15 & 7)) * 8)]);
                bf16x8 k1f = *reinterpret_cast<const bf16x8*>(&Ks[row + (((l4 + 4) ^ (l15 & 7)) * 8)]);
                f32x4 z = {};
                z = __builtin_amdgcn_mfma_f32_16x16x32_bf16(k0f, qa[g][0], z, 0, 0, 0);
                z = __builtin_amdgcn_mfma_f32_16x16x32_bf16(k1f, qa[g][1], z, 0, 0, 0);
                s[kb] = z;
            }
            const int qRow = w * 32 + g * 16 + l15;              // row&15 == l15
            const float* cBase = &Cs[qRow * 64];
            u16* psW = &Ps[qRow * 72 + l4 * 4];
            #pragma unroll
            for (int kb = 0; kb < 4; ++kb) {
                f32x4 c4 = *reinterpret_cast<const f32x4*>(cBase + (((kb * 4 + l4) ^ l15) * 4));
                float p0, p1, p2, p3;
                float t0 = s[kb][0] * LOG2E;
                float t1 = s[kb][1] * LOG2E;
                float t2 = s[kb][2] * LOG2E;
                float t3 = s[kb][3] * LOG2E;
                asm("v_exp_f32 %0, %1" : "=v"(p0) : "v"(t0));
                asm("v_exp_f32 %0, %1" : "=v"(p1) : "v"(t1));
                asm("v_exp_f32 %0, %1" : "=v"(p2) : "v"(t2));
                asm("v_exp_f32 %0, %1" : "=v"(p3) : "v"(t3));
                p0 *= c4[0] + 1e-6f;
                p1 *= c4[1] + 1e-6f;
                p2 *= c4[2] + 1e-6f;
                p3 *= c4[3] + 1e-6f;
                lrp[g] += (p0 + p1) + (p2 + p3);
                u32 d0, d1;
                asm("v_cvt_pk_bf16_f32 %0, %1, %2" : "=v"(d0) : "v"(p0), "v"(p1));
                asm("v_cvt_pk_bf16_f32 %0, %1, %2" : "=v"(d1) : "v"(p2), "v"(p3));
                u32x2 dd = {d0, d1};
                *reinterpret_cast<u32x2*>(psW + kb * 16) = dd;
            }
        }

        union VU { u32x4 u; bf16x8 h; };
        VU vb[2][4];
        #pragma unroll
        for (int c2 = 0; c2 < 2; ++c2) {
            u32 a0 = vaddr + c2 * 4096;
            u32x2 t0, t1, t2, t3, t4, t5, t6, t7;
            asm volatile("ds_read_b64_tr_b16 %0, %1"            : "=v"(t0) : "v"(a0));
            asm volatile("ds_read_b64_tr_b16 %0, %1 offset:512" : "=v"(t1) : "v"(a0));
            asm volatile("ds_read_b64_tr_b16 %0, %1 offset:128" : "=v"(t2) : "v"(a0));
            asm volatile("ds_read_b64_tr_b16 %0, %1 offset:640" : "=v"(t3) : "v"(a0));
            asm volatile("ds_read_b64_tr_b16 %0, %1 offset:256" : "=v"(t4) : "v"(a0));
            asm volatile("ds_read_b64_tr_b16 %0, %1 offset:768" : "=v"(t5) : "v"(a0));
            asm volatile("ds_read_b64_tr_b16 %0, %1 offset:384" : "=v"(t6) : "v"(a0));
            asm volatile("ds_read_b64_tr_b16 %0, %1 offset:896" : "=v"(t7) : "v"(a0));
            asm volatile("s_waitcnt lgkmcnt(0)" ::: "memory");
            __builtin_amdgcn_sched_barrier(0);
            vb[c2][0].u = (u32x4){t0.x, t0.y, t1.x, t1.y};
            vb[c2][1].u = (u32x4){t2.x, t2.y, t3.x, t3.y};
            vb[c2][2].u = (u32x4){t4.x, t4.y, t5.x, t5.y};
            vb[c2][3].u = (u32x4){t6.x, t6.y, t7.x, t7.y};
        }
        #pragma unroll
        for (int g = 0; g < 2; ++g) {
            const u16* pr = &Ps[(w * 32 + g * 16 + l15) * 72];
            bf16x8 pa0 = *reinterpret_cast<const bf16x8*>(pr + l4 * 8);
            bf16x8 pa1 = *reinterpret_cast<const bf16x8*>(pr + 32 + l4 * 8);
            #pragma unroll
            for (int nb = 0; nb < 4; ++nb) {
                o4[g][nb] = __builtin_amdgcn_mfma_f32_16x16x32_bf16(pa0, vb[0][nb].h, o4[g][nb], 0, 0, 0);
                o4[g][nb] = __builtin_amdgcn_mfma_f32_16x16x32_bf16(pa1, vb[1][nb].h, o4[g][nb], 0, 0, 0);
            }
        }
    }

    #pragma unroll
    for (int g = 0; g < 2; ++g) {
        float v = lrp[g];
        v += __shfl_xor(v, 16);
        v += __shfl_xor(v, 32);
        #pragma unroll
        for (int i = 0; i < 4; ++i) {
            float lw = __shfl(v, (lane & 48) | ((l4 << 2) + i));
            float rcp = 1.0f / (lw + 1e-8f);
            int q = q0 + w * 32 + g * 16 + l4 * 4 + i;
            u16* op = O + (bV + q) * D_ + h * 64;
            #pragma unroll
            for (int nb = 0; nb < 4; ++nb)
                op[nb * 16 + l15] = f2bf(o4[g][nb][i] * rcp);
        }
    }
}

// ---------------------------------------------------------------------------
extern "C" void kernel_launch(void* const* d_in, const int* in_sizes, int n_in,
                              void* d_out, int out_size, void* d_ws, size_t ws_size,
                              hipStream_t stream)
{
    (void)in_sizes; (void)n_in; (void)out_size; (void)ws_size;
    const float* x    = (const float*)d_in[0];
    const float* e    = (const float*)d_in[1];
    const float* conn = (const float*)d_in[2];
    const float* ln1g = (const float*)d_in[3];
    const float* ln1b = (const float*)d_in[4];
    const float* f1w1 = (const float*)d_in[5];
    const float* f1b1 = (const float*)d_in[6];
    const float* f1w2 = (const float*)d_in[7];
    const float* f1b2 = (const float*)d_in[8];
    const float* wq   = (const float*)d_in[9];
    const float* bq   = (const float*)d_in[10];
    const float* wk   = (const float*)d_in[11];
    const float* bk   = (const float*)d_in[12];
    const float* wv   = (const float*)d_in[13];
    const float* bv   = (const float*)d_in[14];
    const float* wp   = (const float*)d_in[15];
    const float* bp   = (const float*)d_in[16];
    const float* ln2g = (const float*)d_in[17];
    const float* ln2b = (const float*)d_in[18];
    const float* f2w1 = (const float*)d_in[19];
    const float* f2b1 = (const float*)d_in[20];
    const float* f2w2 = (const float*)d_in[21];
    const float* f2b2 = (const float*)d_in[22];
    const float* ffw1 = (const float*)d_in[23];
    const float* ffb1 = (const float*)d_in[24];
    const float* ffw2 = (const float*)d_in[25];
    const float* ffb2 = (const float*)d_in[26];
    float* out = (float*)d_out;

    // workspace schedule (MB offsets, peak 72 MB == proven-safe; Lm removed)
    char* ws = (char*)d_ws;
    const size_t MB = 1u << 20;
    u16*   e_bf  = (u16*)(ws + 16 * MB);  // 16-18  (live -> film2 gemm1)
    u16*   h     = (u16*)(ws + 18 * MB);  // 18-34
    u16*   wt2   = (u16*)(ws + 34 * MB);  // 34-36  small weight slot
    float* stats = (float*)(ws + 35 * MB);// 35-36  LN row stats (32 KB)
    u16*   wt8   = (u16*)(ws + 36 * MB);  // 36-44  f1w2t / f2w2t
    u16*   y     = (u16*)(ws + 60 * MB);  // 60-68
    u16*   wqkvt = (u16*)(ws + 18 * MB);  // 18-24  (h dead)
    u16*   qkv   = (u16*)(ws + 24 * MB);  // 24-48  fused QKV [4096][3072]
    float* qkvb  = (float*)(ws + 71 * MB);// 71-72
    u16*   o     = (u16*)(ws + 48 * MB);  // 48-56
    u16*   xnew  = (u16*)(ws + 64 * MB);  // 64-72  (y dead by then)
    u16*   h2    = (u16*)(ws + 18 * MB);  // 18-34
    u16*   y2    = (u16*)(ws + 0);        // 0-8
    u16*   ffw1t = (u16*)(ws + 8 * MB);   // 8-16
    u16*   t     = (u16*)(ws + 16 * MB);  // 16-48
    u16*   ffw2t = (u16*)(ws + 48 * MB);  // 48-56

    dim3 blk(256), tblk(32, 8);
    #define CONVT(W, WT, K, N) convT_k<<<dim3((N)/32, (K)/32), tblk, 0, stream>>>(W, WT, K, N)

    // fused prologue: e->bf16 + LN stats(x) + qkv bias concat
    prep_k<<<NC_ + NX_ + D3_/256, blk, 0, stream>>>(e, e_bf, x, stats, bq, bk, bv, qkvb);

    // FiLM 1: g1 GEMM, then fused g2+LN+FiLM
    CONVT(f1w1, wt2, DE_, D2_);
    gemm_k<1, 64, u16, u16><<<dim3(D2_/64, M_/128), blk, 0, stream>>>(e_bf, wt2, f1b1, (const u16*)nullptr, h, M_, D2_, DE_);
    CONVT(f1w2, wt8, D2_, D2_);
    gemmfilm_k<float><<<dim3(D_/64, M_/128), blk, 0, stream>>>(h, wt8, f1b2, x, stats, ln1g, ln1b, y);
    // fused QKV (batched transposes + BN=128 pipelined GEMM)
    convT3_k<<<dim3(D_/32, D_/32, 3), tblk, 0, stream>>>(wq, wk, wv, wqkvt);
    gemm_k<0, 128, u16, u16><<<dim3(D3_/128, M_/128), blk, 0, stream>>>(y, wqkvt, qkvb, (const u16*)nullptr, qkv, M_, D3_, D_);
    // attention (QBLK=128, XCD-swizzled, direct f32 conn)
    attn_k<<<B_*H_*(V_/128), blk, 0, stream>>>(qkv, qkv + 1024, qkv + 2048, conn, o, D3_);
    // projection + residual (res = x, f32)
    CONVT(wp, wt2, D_, D_);
    gemm_k<2, 64, u16, float><<<dim3(D_/64, M_/128), blk, 0, stream>>>(o, wt2, bp, x, xnew, M_, D_, D_);
    // FiLM 2: g1 GEMM, then fused g2+LN+FiLM (stats from xnew)
    CONVT(f2w1, wt2, DE_, D2_);
    gemm_k<1, 64, u16, u16><<<dim3(D2_/64, M_/128), blk, 0, stream>>>(e_bf, wt2, f2b1, (const u16*)nullptr, h2, M_, D2_, DE_);
    xstats_k<u16><<<M_, blk, 0, stream>>>(xnew, stats);
    CONVT(f2w2, wt8, D2_, D2_);
    gemmfilm_k<u16><<<dim3(D_/64, M_/128), blk, 0, stream>>>(h2, wt8, f2b2, xnew, stats, ln2g, ln2b, y2);
    // FFN + residual -> out (f32)
    CONVT(ffw1, ffw1t, D_, DFF_);
    gemm_k<1, 128, u16, u16><<<dim3(DFF_/128, M_/128), blk, 0, stream>>>(y2, ffw1t, ffb1, (const u16*)nullptr, t, M_, DFF_, D_);
    CONVT(ffw2, ffw2t, DFF_, D_);
    gemm_k<2, 64, float, u16><<<dim3(D_/64, M_/128), blk, 0, stream>>>(t, ffw2t, ffb2, xnew, out, M_, D_, DFF_);
    #undef CONVT
}